// Round 5
// baseline (429.649 us; speedup 1.0000x reference)
//
#include <hip/hip_runtime.h>
#include <hip/hip_bf16.h>
#include <math.h>

#define H 128
#define W 128
#define HW (H*W)
#define BATCH 2

typedef __attribute__((ext_vector_type(8))) short          bf16x8;
typedef __attribute__((ext_vector_type(4))) float          f32x4;
typedef __attribute__((ext_vector_type(8))) unsigned short u16x8;

__device__ __forceinline__ float sigmoidf_(float x){ return 1.0f/(1.0f + expf(-x)); }

__device__ __forceinline__ unsigned short f2bf(float f) {
    __hip_bfloat16 h = __float2bfloat16(f);          // RTNE, compiler may pair into cvt_pk
    return __builtin_bit_cast(unsigned short, h);
}

// ---------------------------------------------------------------------------
// Transpose x [B][64][HW] -> xt [B][HW][64]
// ---------------------------------------------------------------------------
__global__ __launch_bounds__(256) void transpose_x64(
    const float* __restrict__ x, float* __restrict__ xt)
{
    __shared__ float tile[64][65];
    int blk = blockIdx.x;               // 512 = 2 b * 256 pix-tiles
    int b  = blk >> 8;
    int p0 = (blk & 255) * 64;
    int tr = threadIdx.x >> 6;
    int tc = threadIdx.x & 63;
    #pragma unroll
    for (int r = 0; r < 16; r++) {
        int c = r * 4 + tr;
        tile[c][tc] = x[((size_t)b * 64 + c) * HW + p0 + tc];
    }
    __syncthreads();
    #pragma unroll
    for (int r = 0; r < 16; r++) {
        int p = r * 4 + tr;
        xt[((size_t)b * HW + p0 + p) * 64 + tc] = tile[tc][p];
    }
}

// ---------------------------------------------------------------------------
// Deform-conv weights: wc [64][CIN][9] fp32 -> wtp [64][NCH*96] bf16,
// k' = ch*96 + n*8 + cl  (n 0..8 real, 9..11 zero-pad)
// ---------------------------------------------------------------------------
template<int CIN>
__global__ __launch_bounds__(256) void transpose_wpad(
    const float* __restrict__ wc, unsigned short* __restrict__ wtp)
{
    constexpr int NCH = CIN / 8;
    int t = blockIdx.x * 256 + threadIdx.x;
    if (t >= 64 * NCH * 96) return;
    int oc = t / (NCH * 96);
    int r  = t - oc * (NCH * 96);
    int ch = r / 96;
    int q  = r - ch * 96;
    int n  = q >> 3, cl = q & 7;
    float v = (n < 9) ? wc[((size_t)oc * CIN + ch * 8 + cl) * 9 + n] : 0.f;
    wtp[t] = f2bf(v);
}

// ---------------------------------------------------------------------------
// Offset/mask conv weights: wp [18][CIN][9], wm [9][CIN][9]
//   -> wt [(c*9+n)*32 + oc], oc 0..26
// ---------------------------------------------------------------------------
template<int CIN>
__global__ __launch_bounds__(256) void transpose_woff(
    const float* __restrict__ wp, const float* __restrict__ wm,
    float* __restrict__ wt)
{
    int t = blockIdx.x * 256 + threadIdx.x;
    if (t >= 27 * CIN * 9) return;
    int oc  = t / (CIN * 9);
    int rem = t - oc * (CIN * 9);
    int c = rem / 9, n = rem - (rem / 9) * 9;
    float v = (oc < 18) ? wp[((size_t)oc * CIN + c) * 9 + n]
                        : wm[((size_t)(oc - 18) * CIN + c) * 9 + n];
    wt[(size_t)(c * 9 + n) * 32 + oc] = v;
}

// ---------------------------------------------------------------------------
// Offset/mask 3x3 conv from channel-major xt [B][HW][CIN]; thread = 1 pixel,
// all 27 oc, 1/4 channel slice. part: [split][B][27][HW]
// ---------------------------------------------------------------------------
template<int CIN>
__global__ __launch_bounds__(256) void conv_off_part(
    const float* __restrict__ xt,
    const float* __restrict__ wt,
    float* __restrict__ part)
{
    constexpr int CPS = CIN / 4;
    int bid   = blockIdx.x;
    int split = bid & 3;
    int tile  = bid >> 2;
    int t   = tile * 256 + threadIdx.x;
    int b   = t >> 14;
    int pix = t & (HW - 1);
    int i = pix >> 7, j = pix & (W - 1);

    const float* nbase[9];
    float msk[9];
    #pragma unroll
    for (int r = 0; r < 9; r++) {
        int ii = i + r / 3 - 1;
        int jj = j + r % 3 - 1;
        bool v = (ii >= 0 && ii < H && jj >= 0 && jj < W);
        nbase[r] = xt + ((size_t)b * HW + (v ? (ii * W + jj) : 0)) * CIN;
        msk[r]   = v ? 1.f : 0.f;
    }

    float acc[27];
    #pragma unroll
    for (int o = 0; o < 27; o++) acc[o] = 0.f;

    for (int cb = 0; cb < CPS; cb += 4) {
        int c0 = split * CPS + cb;
        float4 nb[9];
        #pragma unroll
        for (int r = 0; r < 9; r++)
            nb[r] = *reinterpret_cast<const float4*>(nbase[r] + c0);
        #pragma unroll
        for (int n = 0; n < 9; n++) {
            float mn = msk[n];
            #pragma unroll
            for (int cl = 0; cl < 4; cl++) {
                float xv = ((const float*)&nb[n])[cl] * mn;
                const float* wcn = wt + ((size_t)(c0 + cl) * 9 + n) * 32;
                #pragma unroll
                for (int o = 0; o < 27; o++)
                    acc[o] = fmaf(wcn[o], xv, acc[o]);
            }
        }
    }

    float* pb = part + (((size_t)split * BATCH + b) * 27) * HW + pix;
    #pragma unroll
    for (int o = 0; o < 27; o++) pb[(size_t)o * HW] = acc[o];
}

// ---------------------------------------------------------------------------
// Reduce 4 channel-split partials, add bias, sigmoid mask channels.
// ---------------------------------------------------------------------------
__global__ __launch_bounds__(256) void conv_off_reduce(
    const float* __restrict__ part, const float* __restrict__ bp,
    const float* __restrict__ bm, float* __restrict__ out)
{
    int t4 = blockIdx.x * 256 + threadIdx.x;
    if (t4 >= BATCH * 27 * HW / 4) return;
    int t   = t4 * 4;
    int b   = t / (27 * HW);
    int rem = t - b * 27 * HW;
    int oc  = rem / HW;
    int pix = rem - oc * HW;

    float4 s = make_float4(0.f, 0.f, 0.f, 0.f);
    #pragma unroll
    for (int sp = 0; sp < 4; sp++) {
        float4 v = *reinterpret_cast<const float4*>(
            part + (((size_t)sp * BATCH + b) * 27 + oc) * HW + pix);
        s.x += v.x; s.y += v.y; s.z += v.z; s.w += v.w;
    }
    if (oc < 18) {
        float bv = bp[oc];
        s.x += bv; s.y += bv; s.z += bv; s.w += bv;
    } else {
        float bv = bm[oc - 18];
        s.x = sigmoidf_(s.x + bv); s.y = sigmoidf_(s.y + bv);
        s.z = sigmoidf_(s.z + bv); s.w = sigmoidf_(s.w + bv);
    }
    *reinterpret_cast<float4*>(out + ((size_t)b * 27 + oc) * HW + pix) = s;
}

// ---------------------------------------------------------------------------
// Bilinear metadata for one (pixel, tap): 4 element-offsets (idx*CIN) + wts
// ---------------------------------------------------------------------------
__device__ __forceinline__ void bilin_meta(
    const float* __restrict__ ob, int i, int j, int n, int cin,
    int* mi, float* mw)
{
    float px = ob[(size_t)n * HW]       + (float)(n / 3 - 1) + (float)(i + 1);
    float py = ob[(size_t)(9 + n) * HW] + (float)(n % 3 - 1) + (float)(j + 1);
    float mk = ob[(size_t)(18 + n) * HW];
    float fx = floorf(px), fy = floorf(py);
    const float lim = 129.0f;                 // Hp-1 = Wp-1
    int qltx = (int)fminf(fmaxf(fx, 0.f), lim);
    int qlty = (int)fminf(fmaxf(fy, 0.f), lim);
    int qrbx = (int)fminf(fmaxf(fx + 1.f, 0.f), lim);
    int qrby = (int)fminf(fmaxf(fy + 1.f, 0.f), lim);
    float pxc = fminf(fmaxf(px, 0.f), lim);
    float pyc = fminf(fmaxf(py, 0.f), lim);
    float gxl = 1.f + ((float)qltx - pxc);
    float gxr = 1.f - ((float)qrbx - pxc);
    float gyl = 1.f + ((float)qlty - pyc);
    float gyr = 1.f - ((float)qrby - pyc);
    int   xs[4] = {qltx, qrbx, qltx, qrbx};
    int   ys[4] = {qlty, qrby, qrby, qlty};
    float gs[4] = {gxl * gyl, gxr * gyr, gxl * gyr, gxr * gyl};
    #pragma unroll
    for (int q = 0; q < 4; q++) {
        int qx = xs[q], qy = ys[q];
        bool valid = (qx >= 1 && qx <= H && qy >= 1 && qy <= W);
        mi[q] = (valid ? ((qx - 1) * W + (qy - 1)) : 0) * cin;
        mw[q] = valid ? gs[q] * mk : 0.f;
    }
}

// ---------------------------------------------------------------------------
// Deformable sampling + main conv via MFMA, split-K over 2 block-splits.
// Block: 64 oc x 32 pix, 256 threads (4 waves). Each thread samples one
// (pixel p=tid&31, tap n0=tid>>5); wave 0 also handles tap 8. Meta in regs.
// Weights read straight from L2 (block-invariant). LDS: sbuf only (13.3 KB).
// Next chunk's gathers are issued BEFORE the current chunk's MFMA.
// outp: [2][B][64][HW] fp32 partials (summed by sum2).
// ---------------------------------------------------------------------------
template<int CIN>
__global__ __launch_bounds__(256, 6) void deform_mfma(
    const float* __restrict__ xt,           // [B][HW][CIN]
    const float* __restrict__ off,          // [B][27][HW]
    const unsigned short* __restrict__ wtp, // [64][NCH*96] bf16
    float* __restrict__ outp)               // [2][B][64][HW]
{
    constexpr int NCH = CIN / 8;
    constexpr int HCH = NCH / 2;
    constexpr int SROW = 104;
    __shared__ __align__(16) unsigned short sbuf[2][32][SROW];

    int tid   = threadIdx.x;
    int bid   = blockIdx.x;
    int split = bid & 1;
    int pix0  = (bid >> 1) * 32;
    int b     = pix0 >> 14;
    int base  = pix0 & (HW - 1);
    int i     = base >> 7;
    int j0    = base & 127;

    int p  = tid & 31;
    int n0 = tid >> 5;                      // 0..7
    const float* ob = off + (size_t)b * 27 * HW + (i << 7) + (j0 + p);

    int mi[4];  float mw[4];
    bilin_meta(ob, i, j0 + p, n0, CIN, mi, mw);
    bool tap8 = (tid < 32);
    int mi8[4]; float mw8[4];
    if (tap8) bilin_meta(ob, i, j0 + p, 8, CIN, mi8, mw8);

    // zero the pad k-slots (72..95) of both buffers
    if (tid < 192) {
        int bi = tid / 96, r2 = tid - bi * 96;
        int row = r2 / 3, sg = r2 - (r2 / 3) * 3;
        u16x8 z = {0,0,0,0,0,0,0,0};
        *reinterpret_cast<u16x8*>(&sbuf[bi][row][72 + sg * 8]) = z;
    }

    const float* xtb = xt + (size_t)b * HW * CIN;
    int ch0 = split * HCH;

    float vac[8], vac8[8];
    auto gather = [&](int ch) {
        const float* cb = xtb + ch * 8;
        #pragma unroll
        for (int e = 0; e < 8; e++) vac[e] = 0.f;
        #pragma unroll
        for (int q = 0; q < 4; q++) {
            const float4* sp = reinterpret_cast<const float4*>(cb + mi[q]);
            float4 lo = sp[0], hi = sp[1];
            float wq = mw[q];
            vac[0] = fmaf(lo.x, wq, vac[0]); vac[1] = fmaf(lo.y, wq, vac[1]);
            vac[2] = fmaf(lo.z, wq, vac[2]); vac[3] = fmaf(lo.w, wq, vac[3]);
            vac[4] = fmaf(hi.x, wq, vac[4]); vac[5] = fmaf(hi.y, wq, vac[5]);
            vac[6] = fmaf(hi.z, wq, vac[6]); vac[7] = fmaf(hi.w, wq, vac[7]);
        }
        if (tap8) {
            #pragma unroll
            for (int e = 0; e < 8; e++) vac8[e] = 0.f;
            #pragma unroll
            for (int q = 0; q < 4; q++) {
                const float4* sp = reinterpret_cast<const float4*>(cb + mi8[q]);
                float4 lo = sp[0], hi = sp[1];
                float wq = mw8[q];
                vac8[0] = fmaf(lo.x, wq, vac8[0]); vac8[1] = fmaf(lo.y, wq, vac8[1]);
                vac8[2] = fmaf(lo.z, wq, vac8[2]); vac8[3] = fmaf(lo.w, wq, vac8[3]);
                vac8[4] = fmaf(hi.x, wq, vac8[4]); vac8[5] = fmaf(hi.y, wq, vac8[5]);
                vac8[6] = fmaf(hi.z, wq, vac8[6]); vac8[7] = fmaf(hi.w, wq, vac8[7]);
            }
        }
    };
    auto commit = [&](int bi) {
        u16x8 o;
        #pragma unroll
        for (int e = 0; e < 8; e++) o[e] = f2bf(vac[e]);
        *reinterpret_cast<u16x8*>(&sbuf[bi][p][n0 * 8]) = o;
        if (tap8) {
            u16x8 o8;
            #pragma unroll
            for (int e = 0; e < 8; e++) o8[e] = f2bf(vac8[e]);
            *reinterpret_cast<u16x8*>(&sbuf[bi][p][64]) = o8;
        }
    };

    // prologue
    gather(ch0);
    commit(0);
    __syncthreads();

    int lane = tid & 63, wv = tid >> 6;     // 4 waves
    int ocq = wv & 1, pq = wv >> 1;         // pq 0..1 (16-pix halves)
    int lr = lane & 15, lg = lane >> 4;
    int srow = pq * 16 + lr;
    int wrow = ocq * 32 + lr;
    const unsigned short* wb0 = wtp + (size_t)wrow * (NCH * 96) + lg * 8;
    const unsigned short* wb1 = wb0 + (size_t)16 * (NCH * 96);

    f32x4 acc0 = {0.f, 0.f, 0.f, 0.f};
    f32x4 acc1 = {0.f, 0.f, 0.f, 0.f};

    for (int cc = 0; cc < HCH; cc++) {
        int ch  = ch0 + cc;
        int cur = cc & 1;
        if (cc + 1 < HCH) gather(ch + 1);       // issue gathers early
        #pragma unroll
        for (int ks = 0; ks < 3; ks++) {
            bf16x8 bfr = *reinterpret_cast<const bf16x8*>(&sbuf[cur][srow][ks * 32 + lg * 8]);
            bf16x8 a0  = *reinterpret_cast<const bf16x8*>(wb0 + (size_t)ch * 96 + ks * 32);
            bf16x8 a1  = *reinterpret_cast<const bf16x8*>(wb1 + (size_t)ch * 96 + ks * 32);
            acc0 = __builtin_amdgcn_mfma_f32_16x16x32_bf16(a0, bfr, acc0, 0, 0, 0);
            acc1 = __builtin_amdgcn_mfma_f32_16x16x32_bf16(a1, bfr, acc1, 0, 0, 0);
        }
        if (cc + 1 < HCH) commit(cur ^ 1);
        __syncthreads();
    }

    float* op = outp + (size_t)split * (BATCH * 64 * HW);
    int pixo = base + pq * 16 + lr;
    float* ob0 = op + ((size_t)b * 64 + ocq * 32 + lg * 4) * HW + pixo;
    #pragma unroll
    for (int r = 0; r < 4; r++) ob0[(size_t)r * HW] = acc0[r];
    float* ob1 = op + ((size_t)b * 64 + ocq * 32 + 16 + lg * 4) * HW + pixo;
    #pragma unroll
    for (int r = 0; r < 4; r++) ob1[(size_t)r * HW] = acc1[r];
}

// ---------------------------------------------------------------------------
// Sum the two split-K partials (o may alias a).
// ---------------------------------------------------------------------------
__global__ __launch_bounds__(256) void sum2(
    const float* __restrict__ a, const float* __restrict__ bsrc,
    float* __restrict__ o)
{
    int t = blockIdx.x * 256 + threadIdx.x;
    if (t >= BATCH * 64 * HW / 4) return;
    float4 va = reinterpret_cast<const float4*>(a)[t];
    float4 vb = reinterpret_cast<const float4*>(bsrc)[t];
    va.x += vb.x; va.y += vb.y; va.z += vb.z; va.w += vb.w;
    reinterpret_cast<float4*>(o)[t] = va;
}

// ---------------------------------------------------------------------------
// Group-norm statistics. One block per (b, group).
// ---------------------------------------------------------------------------
__global__ __launch_bounds__(256) void gn_stats(
    const float* __restrict__ buf, float* __restrict__ stats)
{
    int bg = blockIdx.x;
    const float4* v = reinterpret_cast<const float4*>(buf + (size_t)bg * 4 * HW);
    float sum = 0.f, ssq = 0.f;
    for (int idx = threadIdx.x; idx < 4 * HW / 4; idx += 256) {
        float4 x = v[idx];
        sum += x.x + x.y + x.z + x.w;
        ssq += x.x * x.x + x.y * x.y + x.z * x.z + x.w * x.w;
    }
    #pragma unroll
    for (int d = 32; d > 0; d >>= 1) {
        sum += __shfl_down(sum, d);
        ssq += __shfl_down(ssq, d);
    }
    __shared__ float ws1[4], ws2[4];
    int wid = threadIdx.x >> 6;
    if ((threadIdx.x & 63) == 0) { ws1[wid] = sum; ws2[wid] = ssq; }
    __syncthreads();
    if (threadIdx.x == 0) {
        float S = ws1[0] + ws1[1] + ws1[2] + ws1[3];
        float Q = ws2[0] + ws2[1] + ws2[2] + ws2[3];
        float mean = S * (1.0f / (4.0f * HW));
        float var  = Q * (1.0f / (4.0f * HW)) - mean * mean;
        stats[bg]      = mean;
        stats[32 + bg] = rsqrtf(var + 1e-5f);
    }
}

// ---------------------------------------------------------------------------
// GN(+relu) on the fly -> channel mean & max maps only (no c1 materialized).
// ---------------------------------------------------------------------------
__global__ __launch_bounds__(256) void gn_meanmax(
    const float* __restrict__ dc, const float* __restrict__ stats,
    const float* __restrict__ gamma, const float* __restrict__ beta,
    float* __restrict__ cm, float* __restrict__ cx)
{
    int t = blockIdx.x * 256 + threadIdx.x;
    if (t >= BATCH * HW) return;
    int b = t >> 14;
    int pix = t & (HW - 1);
    float msum = 0.f, mmax = -INFINITY;
    #pragma unroll 8
    for (int c = 0; c < 64; c++) {
        int g = c >> 2;
        float mean = stats[b * 16 + g];
        float rstd = stats[32 + b * 16 + g];
        size_t idx = ((size_t)b * 64 + c) * HW + pix;
        float v = (dc[idx] - mean) * rstd * gamma[c] + beta[c];
        v = fmaxf(v, 0.f);
        msum += v;
        mmax = fmaxf(mmax, v);
    }
    cm[t] = msum * (1.0f / 64.0f);
    cx[t] = mmax;
}

// ---------------------------------------------------------------------------
// 1-ch 3x3 convs over cm/cx + sigmoid -> av, mv maps.
// ---------------------------------------------------------------------------
__global__ __launch_bounds__(256) void attn_sig(
    const float* __restrict__ cm, const float* __restrict__ cx,
    const float* __restrict__ wa, const float* __restrict__ ba,
    const float* __restrict__ wb, const float* __restrict__ bb,
    float* __restrict__ avb, float* __restrict__ mvb)
{
    int t = blockIdx.x * 256 + threadIdx.x;
    if (t >= BATCH * HW) return;
    int b = t >> 14;
    int pix = t & (HW - 1);
    int i = pix >> 7, j = pix & (W - 1);
    float sa = ba[0], sb = bb[0];
    #pragma unroll
    for (int di = 0; di < 3; di++) {
        int ii = i + di - 1;
        if (ii < 0 || ii >= H) continue;
        #pragma unroll
        for (int dj = 0; dj < 3; dj++) {
            int jj = j + dj - 1;
            if (jj < 0 || jj >= W) continue;
            int q = (b << 14) + (ii << 7) + jj;
            sa = fmaf(cm[q], wa[di * 3 + dj], sa);
            sb = fmaf(cx[q], wb[di * 3 + dj], sb);
        }
    }
    avb[t] = sigmoidf_(sa);
    mvb[t] = sigmoidf_(sb);
}

// ---------------------------------------------------------------------------
// Fused GN+relu + attention-scale + concat + transpose:
// catt[b][pix][0:64] = av*GN(dc), catt[b][pix][64:128] = mv*GN(dc)
// Coalesced both sides via LDS tile.
// ---------------------------------------------------------------------------
__global__ __launch_bounds__(256) void attn_cat_t(
    const float* __restrict__ dc, const float* __restrict__ stats,
    const float* __restrict__ gamma, const float* __restrict__ beta,
    const float* __restrict__ avb, const float* __restrict__ mvb,
    float* __restrict__ catt)
{
    __shared__ float tile[64][65];
    __shared__ float avs[64], mvs[64];
    int blk = blockIdx.x;               // 512
    int b  = blk >> 8;
    int p0 = (blk & 255) * 64;
    int tr = threadIdx.x >> 6;
    int tc = threadIdx.x & 63;
    if (threadIdx.x < 64)       avs[threadIdx.x] = avb[(size_t)b * HW + p0 + threadIdx.x];
    else if (threadIdx.x < 128) mvs[threadIdx.x - 64] = mvb[(size_t)b * HW + p0 + threadIdx.x - 64];
    #pragma unroll
    for (int r = 0; r < 16; r++) {
        int c = r * 4 + tr;
        float mean = stats[b * 16 + (c >> 2)];
        float rstd = stats[32 + b * 16 + (c >> 2)];
        float v = dc[((size_t)b * 64 + c) * HW + p0 + tc];
        tile[c][tc] = fmaxf((v - mean) * rstd * gamma[c] + beta[c], 0.f);
    }
    __syncthreads();
    #pragma unroll
    for (int r = 0; r < 16; r++) {
        int p = r * 4 + tr;
        float v = tile[tc][p];
        float* cr = catt + ((size_t)b * HW + p0 + p) * 128;
        cr[tc]      = avs[p] * v;
        cr[64 + tc] = mvs[p] * v;
    }
}

// ---------------------------------------------------------------------------
// Final GN + relu -> d_out
// ---------------------------------------------------------------------------
__global__ __launch_bounds__(256) void gn_final(
    const float* __restrict__ dc, const float* __restrict__ stats,
    const float* __restrict__ gamma, const float* __restrict__ beta,
    float* __restrict__ out)
{
    int t = blockIdx.x * 256 + threadIdx.x;
    if (t >= BATCH * 64 * HW) return;
    int c = (t >> 14) & 63;
    int b = t >> 20;
    int g = c >> 2;
    float mean = stats[b * 16 + g];
    float rstd = stats[32 + b * 16 + g];
    float v = (dc[t] - mean) * rstd * gamma[c] + beta[c];
    out[t] = fmaxf(v, 0.f);
}

// ---------------------------------------------------------------------------
extern "C" void kernel_launch(void* const* d_in, const int* in_sizes, int n_in,
                              void* d_out, int out_size, void* d_ws, size_t ws_size,
                              hipStream_t stream) {
    (void)in_sizes; (void)n_in; (void)out_size; (void)ws_size;
    const float* x   = (const float*)d_in[0];
    const float* wp1 = (const float*)d_in[1];
    const float* bp1 = (const float*)d_in[2];
    const float* wm1 = (const float*)d_in[3];
    const float* bm1 = (const float*)d_in[4];
    const float* wc1 = (const float*)d_in[5];
    const float* g1  = (const float*)d_in[6];
    const float* be1 = (const float*)d_in[7];
    const float* wa  = (const float*)d_in[8];
    const float* ba  = (const float*)d_in[9];
    const float* wb  = (const float*)d_in[10];
    const float* bb  = (const float*)d_in[11];
    const float* wp2 = (const float*)d_in[12];
    const float* bp2 = (const float*)d_in[13];
    const float* wm2 = (const float*)d_in[14];
    const float* bm2 = (const float*)d_in[15];
    const float* wc2 = (const float*)d_in[16];
    const float* g2  = (const float*)d_in[17];
    const float* be2 = (const float*)d_in[18];
    float* out = (float*)d_out;

    // ---- workspace layout (floats) ----
    float* ws   = (float*)d_ws;
    float* offb = ws;                              //  884736
    float* dcb  = offb + 2 * 27 * HW;              // 2097152 (split-K partial 0)
    float* paux = dcb + 2 * 64 * HW;               // 2097152 (split-K partial 1)
    float* cmb  = paux + 2 * 64 * HW;              //   32768
    float* cxb  = cmb + 2 * HW;                    //   32768
    float* avb  = cxb + 2 * HW;                    //   32768
    float* mvb  = avb + 2 * HW;                    //   32768
    float* catt = mvb + 2 * HW;                    // 4194304 [B][HW][128]
    float* stb  = catt + (size_t)2 * 128 * HW;     //      64
    float* wo1  = stb + 64;                        //   18432
    float* wo2  = wo1 + 64 * 9 * 32;               //   36864
    unsigned short* wtp1 = (unsigned short*)(wo2 + 128 * 9 * 32);
    unsigned short* wtp2 = wtp1 + 64 * 8 * 96;
    // conv partials (4*2*27*HW = 3.54M floats) alias dcb+paux (dead then)
    float* partb = dcb;
    // x transposed [B][HW][64] in d_out scratch (rewritten by gn_final)
    float* xt1 = out;

    const int NPIXB = (BATCH * HW + 255) / 256;      // 128
    const int NCONV = NPIXB * 4;                     // 512
    const int NRED  = (BATCH * 27 * HW / 4 + 255) / 256;
    const int NDEF  = (BATCH * HW / 32) * 2;         // 2048 (x2 split-K)
    const int NSUM  = (BATCH * 64 * HW / 4 + 255) / 256;

    transpose_x64<<<512, 256, 0, stream>>>(x, xt1);
    transpose_wpad<64><<<(64 * 8 * 96 + 255) / 256, 256, 0, stream>>>(wc1, wtp1);
    transpose_wpad<128><<<(64 * 16 * 96 + 255) / 256, 256, 0, stream>>>(wc2, wtp2);
    transpose_woff<64><<<(27 * 64 * 9 + 255) / 256, 256, 0, stream>>>(wp1, wm1, wo1);
    transpose_woff<128><<<(27 * 128 * 9 + 255) / 256, 256, 0, stream>>>(wp2, wm2, wo2);

    // ---- stage 1 ----
    conv_off_part<64><<<NCONV, 256, 0, stream>>>(xt1, wo1, partb);
    conv_off_reduce<<<NRED, 256, 0, stream>>>(partb, bp1, bm1, offb);
    deform_mfma<64><<<NDEF, 256, 0, stream>>>(xt1, offb, wtp1, dcb);
    sum2<<<NSUM, 256, 0, stream>>>(dcb, paux, dcb);
    gn_stats<<<32, 256, 0, stream>>>(dcb, stb);
    gn_meanmax<<<NPIXB, 256, 0, stream>>>(dcb, stb, g1, be1, cmb, cxb);
    attn_sig<<<NPIXB, 256, 0, stream>>>(cmb, cxb, wa, ba, wb, bb, avb, mvb);
    attn_cat_t<<<512, 256, 0, stream>>>(dcb, stb, g1, be1, avb, mvb, catt);

    // ---- stage 2 ----
    conv_off_part<128><<<NCONV, 256, 0, stream>>>(catt, wo2, partb);
    conv_off_reduce<<<NRED, 256, 0, stream>>>(partb, bp2, bm2, offb);
    deform_mfma<128><<<NDEF, 256, 0, stream>>>(catt, offb, wtp2, dcb);
    sum2<<<NSUM, 256, 0, stream>>>(dcb, paux, dcb);
    gn_stats<<<32, 256, 0, stream>>>(dcb, stb);
    gn_final<<<(BATCH * 64 * HW + 255) / 256, 256, 0, stream>>>(dcb, stb, g2, be2, out);
}

// Round 6
// 337.571 us; speedup vs baseline: 1.2728x; 1.2728x over previous
//
#include <hip/hip_runtime.h>
#include <hip/hip_bf16.h>
#include <math.h>

#define H 128
#define W 128
#define HW (H*W)
#define BATCH 2

typedef __attribute__((ext_vector_type(8))) short          bf16x8;
typedef __attribute__((ext_vector_type(4))) float          f32x4;
typedef __attribute__((ext_vector_type(8))) unsigned short u16x8;

__device__ __forceinline__ float sigmoidf_(float x){ return 1.0f/(1.0f + expf(-x)); }

__device__ __forceinline__ unsigned short f2bf(float f) {
    __hip_bfloat16 h = __float2bfloat16(f);          // RTNE
    return __builtin_bit_cast(unsigned short, h);
}

// ---------------------------------------------------------------------------
// Transpose x [B][64][HW] -> xt [B][HW][64]
// ---------------------------------------------------------------------------
__global__ __launch_bounds__(256) void transpose_x64(
    const float* __restrict__ x, float* __restrict__ xt)
{
    __shared__ float tile[64][65];
    int blk = blockIdx.x;               // 512 = 2 b * 256 pix-tiles
    int b  = blk >> 8;
    int p0 = (blk & 255) * 64;
    int tr = threadIdx.x >> 6;
    int tc = threadIdx.x & 63;
    #pragma unroll
    for (int r = 0; r < 16; r++) {
        int c = r * 4 + tr;
        tile[c][tc] = x[((size_t)b * 64 + c) * HW + p0 + tc];
    }
    __syncthreads();
    #pragma unroll
    for (int r = 0; r < 16; r++) {
        int p = r * 4 + tr;
        xt[((size_t)b * HW + p0 + p) * 64 + tc] = tile[tc][p];
    }
}

// ---------------------------------------------------------------------------
// Deform-conv weights: wc [64][CIN][9] fp32 -> wtp [64][NCH*96] bf16,
// k' = ch*96 + n*8 + cl  (n 0..8 real, 9..11 zero-pad)
// ---------------------------------------------------------------------------
template<int CIN>
__global__ __launch_bounds__(256) void transpose_wpad(
    const float* __restrict__ wc, unsigned short* __restrict__ wtp)
{
    constexpr int NCH = CIN / 8;
    int t = blockIdx.x * 256 + threadIdx.x;
    if (t >= 64 * NCH * 96) return;
    int oc = t / (NCH * 96);
    int r  = t - oc * (NCH * 96);
    int ch = r / 96;
    int q  = r - ch * 96;
    int n  = q >> 3, cl = q & 7;
    float v = (n < 9) ? wc[((size_t)oc * CIN + ch * 8 + cl) * 9 + n] : 0.f;
    wtp[t] = f2bf(v);
}

// ---------------------------------------------------------------------------
// Offset/mask conv weights: wp [18][CIN][9], wm [9][CIN][9]
//   -> wt [(c*9+n)*32 + oc], oc 0..26
// ---------------------------------------------------------------------------
template<int CIN>
__global__ __launch_bounds__(256) void transpose_woff(
    const float* __restrict__ wp, const float* __restrict__ wm,
    float* __restrict__ wt)
{
    int t = blockIdx.x * 256 + threadIdx.x;
    if (t >= 27 * CIN * 9) return;
    int oc  = t / (CIN * 9);
    int rem = t - oc * (CIN * 9);
    int c = rem / 9, n = rem - (rem / 9) * 9;
    float v = (oc < 18) ? wp[((size_t)oc * CIN + c) * 9 + n]
                        : wm[((size_t)(oc - 18) * CIN + c) * 9 + n];
    wt[(size_t)(c * 9 + n) * 32 + oc] = v;
}

// ---------------------------------------------------------------------------
// Offset/mask 3x3 conv from channel-major xt [B][HW][CIN]; thread = 1 pixel,
// all 27 oc, 1/4 channel slice. part: [split][B][27][HW]
// ---------------------------------------------------------------------------
template<int CIN>
__global__ __launch_bounds__(256) void conv_off_part(
    const float* __restrict__ xt,
    const float* __restrict__ wt,
    float* __restrict__ part)
{
    constexpr int CPS = CIN / 4;
    int bid   = blockIdx.x;
    int split = bid & 3;
    int tile  = bid >> 2;
    int t   = tile * 256 + threadIdx.x;
    int b   = t >> 14;
    int pix = t & (HW - 1);
    int i = pix >> 7, j = pix & (W - 1);

    const float* nbase[9];
    float msk[9];
    #pragma unroll
    for (int r = 0; r < 9; r++) {
        int ii = i + r / 3 - 1;
        int jj = j + r % 3 - 1;
        bool v = (ii >= 0 && ii < H && jj >= 0 && jj < W);
        nbase[r] = xt + ((size_t)b * HW + (v ? (ii * W + jj) : 0)) * CIN;
        msk[r]   = v ? 1.f : 0.f;
    }

    float acc[27];
    #pragma unroll
    for (int o = 0; o < 27; o++) acc[o] = 0.f;

    for (int cb = 0; cb < CPS; cb += 4) {
        int c0 = split * CPS + cb;
        float4 nb[9];
        #pragma unroll
        for (int r = 0; r < 9; r++)
            nb[r] = *reinterpret_cast<const float4*>(nbase[r] + c0);
        #pragma unroll
        for (int n = 0; n < 9; n++) {
            float mn = msk[n];
            #pragma unroll
            for (int cl = 0; cl < 4; cl++) {
                float xv = ((const float*)&nb[n])[cl] * mn;
                const float* wcn = wt + ((size_t)(c0 + cl) * 9 + n) * 32;
                #pragma unroll
                for (int o = 0; o < 27; o++)
                    acc[o] = fmaf(wcn[o], xv, acc[o]);
            }
        }
    }

    float* pb = part + (((size_t)split * BATCH + b) * 27) * HW + pix;
    #pragma unroll
    for (int o = 0; o < 27; o++) pb[(size_t)o * HW] = acc[o];
}

// ---------------------------------------------------------------------------
// Reduce 4 channel-split partials, add bias, sigmoid mask channels.
// ---------------------------------------------------------------------------
__global__ __launch_bounds__(256) void conv_off_reduce(
    const float* __restrict__ part, const float* __restrict__ bp,
    const float* __restrict__ bm, float* __restrict__ out)
{
    int t4 = blockIdx.x * 256 + threadIdx.x;
    if (t4 >= BATCH * 27 * HW / 4) return;
    int t   = t4 * 4;
    int b   = t / (27 * HW);
    int rem = t - b * 27 * HW;
    int oc  = rem / HW;
    int pix = rem - oc * HW;

    float4 s = make_float4(0.f, 0.f, 0.f, 0.f);
    #pragma unroll
    for (int sp = 0; sp < 4; sp++) {
        float4 v = *reinterpret_cast<const float4*>(
            part + (((size_t)sp * BATCH + b) * 27 + oc) * HW + pix);
        s.x += v.x; s.y += v.y; s.z += v.z; s.w += v.w;
    }
    if (oc < 18) {
        float bv = bp[oc];
        s.x += bv; s.y += bv; s.z += bv; s.w += bv;
    } else {
        float bv = bm[oc - 18];
        s.x = sigmoidf_(s.x + bv); s.y = sigmoidf_(s.y + bv);
        s.z = sigmoidf_(s.z + bv); s.w = sigmoidf_(s.w + bv);
    }
    *reinterpret_cast<float4*>(out + ((size_t)b * 27 + oc) * HW + pix) = s;
}

// ---------------------------------------------------------------------------
// Bilinear metadata for one (pixel, tap): 4 element-offsets (idx*CIN) + wts
// ---------------------------------------------------------------------------
__device__ __forceinline__ void bilin_meta(
    const float* __restrict__ ob, int i, int j, int n, int cin,
    int* mi, float* mw)
{
    float px = ob[(size_t)n * HW]       + (float)(n / 3 - 1) + (float)(i + 1);
    float py = ob[(size_t)(9 + n) * HW] + (float)(n % 3 - 1) + (float)(j + 1);
    float mk = ob[(size_t)(18 + n) * HW];
    float fx = floorf(px), fy = floorf(py);
    const float lim = 129.0f;                 // Hp-1 = Wp-1
    int qltx = (int)fminf(fmaxf(fx, 0.f), lim);
    int qlty = (int)fminf(fmaxf(fy, 0.f), lim);
    int qrbx = (int)fminf(fmaxf(fx + 1.f, 0.f), lim);
    int qrby = (int)fminf(fmaxf(fy + 1.f, 0.f), lim);
    float pxc = fminf(fmaxf(px, 0.f), lim);
    float pyc = fminf(fmaxf(py, 0.f), lim);
    float gxl = 1.f + ((float)qltx - pxc);
    float gxr = 1.f - ((float)qrbx - pxc);
    float gyl = 1.f + ((float)qlty - pyc);
    float gyr = 1.f - ((float)qrby - pyc);
    int   xs[4] = {qltx, qrbx, qltx, qrbx};
    int   ys[4] = {qlty, qrby, qrby, qlty};
    float gs[4] = {gxl * gyl, gxr * gyr, gxl * gyr, gxr * gyl};
    #pragma unroll
    for (int q = 0; q < 4; q++) {
        int qx = xs[q], qy = ys[q];
        bool valid = (qx >= 1 && qx <= H && qy >= 1 && qy <= W);
        mi[q] = (valid ? ((qx - 1) * W + (qy - 1)) : 0) * cin;
        mw[q] = valid ? gs[q] * mk : 0.f;
    }
}

// ---------------------------------------------------------------------------
// Deformable sampling + main conv via MFMA (bf16 in, fp32 accum).
// Block: 64 pix x 64 oc, 576 threads = 9 waves. Each thread owns exactly one
// (pixel p=tid&63, tap n=tid>>6) gather task; waves 0..7 do the MFMA
// (2 oc-halves x 4 pix-quarters), wave 8 gathers tap 8 only.
// Meta in registers. Weights + samples double-buffered in LDS (52 KB).
// Per chunk: issue next gathers + weight loads FIRST, MFMA current, then
// commit LDS, one barrier.
// ---------------------------------------------------------------------------
template<int CIN>
__global__ __launch_bounds__(576, 6) void deform_mfma(
    const float* __restrict__ xt,           // [B][HW][CIN]
    const float* __restrict__ off,          // [B][27][HW]
    const unsigned short* __restrict__ wtp, // [64][NCH*96] bf16
    float* __restrict__ out)                // [B][64][HW]
{
    constexpr int NCH  = CIN / 8;
    constexpr int SROW = 104;
    __shared__ __align__(16) unsigned short sbuf[2][64][SROW];
    __shared__ __align__(16) unsigned short wbuf[2][64][SROW];

    int tid  = threadIdx.x;
    int pix0 = blockIdx.x * 64;
    int b    = pix0 >> 14;
    int base = pix0 & (HW - 1);
    int i    = base >> 7;
    int j0   = base & 127;

    int p = tid & 63;
    int n = tid >> 6;                       // 0..8
    const float* ob = off + (size_t)b * 27 * HW + (i << 7) + (j0 + p);
    int mi[4]; float mw[4];
    bilin_meta(ob, i, j0 + p, n, CIN, mi, mw);

    // zero pad k-slots (72..95) of both sample buffers: 2 x 64 rows x 3 segs
    if (tid < 384) {
        int bi = tid >= 192;
        int r2 = tid - bi * 192;
        int row = r2 / 3, sg = r2 - (r2 / 3) * 3;
        u16x8 z = {0,0,0,0,0,0,0,0};
        *reinterpret_cast<u16x8*>(&sbuf[bi][row][72 + sg * 8]) = z;
    }

    const float* xtb = xt + (size_t)b * HW * CIN;

    // ---- gather (issue) / commit split ----
    float vac[8];
    auto gather = [&](int ch) {
        const float* cb = xtb + ch * 8;
        #pragma unroll
        for (int e = 0; e < 8; e++) vac[e] = 0.f;
        #pragma unroll
        for (int q = 0; q < 4; q++) {
            const float4* sp = reinterpret_cast<const float4*>(cb + mi[q]);
            float4 lo = sp[0], hi = sp[1];
            float wq = mw[q];
            vac[0] = fmaf(lo.x, wq, vac[0]); vac[1] = fmaf(lo.y, wq, vac[1]);
            vac[2] = fmaf(lo.z, wq, vac[2]); vac[3] = fmaf(lo.w, wq, vac[3]);
            vac[4] = fmaf(hi.x, wq, vac[4]); vac[5] = fmaf(hi.y, wq, vac[5]);
            vac[6] = fmaf(hi.z, wq, vac[6]); vac[7] = fmaf(hi.w, wq, vac[7]);
        }
    };
    auto commit = [&](int bi) {
        u16x8 o;
        #pragma unroll
        for (int e = 0; e < 8; e++) o[e] = f2bf(vac[e]);
        *reinterpret_cast<u16x8*>(&sbuf[bi][p][n * 8]) = o;
    };

    // ---- weight stage (issue/commit split): 64 rows x 12 segs per chunk ----
    // slot space 64x16 (seg<12 used): pass1 idx=tid, pass2 idx=576+tid (tid<448)
    int row0 = tid >> 4,        seg0 = tid & 15;
    int idx1 = 576 + tid;
    int row1 = idx1 >> 4,       seg1 = idx1 & 15;
    bool wv0 = (seg0 < 12);
    bool wv1 = (tid < 448) && (seg1 < 12);
    u16x8 wreg0, wreg1;
    auto wload = [&](int ch) {
        if (wv0) wreg0 = *reinterpret_cast<const u16x8*>(
            wtp + (size_t)row0 * (NCH * 96) + ch * 96 + seg0 * 8);
        if (wv1) wreg1 = *reinterpret_cast<const u16x8*>(
            wtp + (size_t)row1 * (NCH * 96) + ch * 96 + seg1 * 8);
    };
    auto wcommit = [&](int bi) {
        if (wv0) *reinterpret_cast<u16x8*>(&wbuf[bi][row0][seg0 * 8]) = wreg0;
        if (wv1) *reinterpret_cast<u16x8*>(&wbuf[bi][row1][seg1 * 8]) = wreg1;
    };

    // ---- MFMA role (waves 0..7) ----
    int lane = tid & 63, wv = tid >> 6;
    int ocq = wv & 1, pq = wv >> 1;         // pq 0..3
    int lr = lane & 15, lg = lane >> 4;
    int srow = pq * 16 + lr;
    int wrow = ocq * 32 + lr;

    f32x4 acc0 = {0.f, 0.f, 0.f, 0.f};
    f32x4 acc1 = {0.f, 0.f, 0.f, 0.f};

    // prologue: fill chunk 0
    gather(0);
    wload(0);
    commit(0);
    wcommit(0);
    __syncthreads();

    for (int cc = 0; cc < NCH; cc++) {
        int cur = cc & 1;
        if (cc + 1 < NCH) {                 // issue next-chunk loads early
            gather(cc + 1);
            wload(cc + 1);
        }
        if (wv < 8) {
            #pragma unroll
            for (int ks = 0; ks < 3; ks++) {
                bf16x8 bfr = *reinterpret_cast<const bf16x8*>(&sbuf[cur][srow][ks * 32 + lg * 8]);
                bf16x8 a0  = *reinterpret_cast<const bf16x8*>(&wbuf[cur][wrow][ks * 32 + lg * 8]);
                bf16x8 a1  = *reinterpret_cast<const bf16x8*>(&wbuf[cur][wrow + 16][ks * 32 + lg * 8]);
                acc0 = __builtin_amdgcn_mfma_f32_16x16x32_bf16(a0, bfr, acc0, 0, 0, 0);
                acc1 = __builtin_amdgcn_mfma_f32_16x16x32_bf16(a1, bfr, acc1, 0, 0, 0);
            }
        }
        if (cc + 1 < NCH) {
            commit(cur ^ 1);
            wcommit(cur ^ 1);
        }
        __syncthreads();
    }

    if (wv < 8) {
        int pixo = base + pq * 16 + lr;
        float* ob0 = out + ((size_t)b * 64 + ocq * 32 + lg * 4) * HW + pixo;
        #pragma unroll
        for (int r = 0; r < 4; r++) ob0[(size_t)r * HW] = acc0[r];
        float* ob1 = out + ((size_t)b * 64 + ocq * 32 + 16 + lg * 4) * HW + pixo;
        #pragma unroll
        for (int r = 0; r < 4; r++) ob1[(size_t)r * HW] = acc1[r];
    }
}

// ---------------------------------------------------------------------------
// Group-norm statistics. One block per (b, group).
// ---------------------------------------------------------------------------
__global__ __launch_bounds__(256) void gn_stats(
    const float* __restrict__ buf, float* __restrict__ stats)
{
    int bg = blockIdx.x;
    const float4* v = reinterpret_cast<const float4*>(buf + (size_t)bg * 4 * HW);
    float sum = 0.f, ssq = 0.f;
    for (int idx = threadIdx.x; idx < 4 * HW / 4; idx += 256) {
        float4 x = v[idx];
        sum += x.x + x.y + x.z + x.w;
        ssq += x.x * x.x + x.y * x.y + x.z * x.z + x.w * x.w;
    }
    #pragma unroll
    for (int d = 32; d > 0; d >>= 1) {
        sum += __shfl_down(sum, d);
        ssq += __shfl_down(ssq, d);
    }
    __shared__ float ws1[4], ws2[4];
    int wid = threadIdx.x >> 6;
    if ((threadIdx.x & 63) == 0) { ws1[wid] = sum; ws2[wid] = ssq; }
    __syncthreads();
    if (threadIdx.x == 0) {
        float S = ws1[0] + ws1[1] + ws1[2] + ws1[3];
        float Q = ws2[0] + ws2[1] + ws2[2] + ws2[3];
        float mean = S * (1.0f / (4.0f * HW));
        float var  = Q * (1.0f / (4.0f * HW)) - mean * mean;
        stats[bg]      = mean;
        stats[32 + bg] = rsqrtf(var + 1e-5f);
    }
}

// ---------------------------------------------------------------------------
// GN(+relu) on the fly -> channel mean & max maps only.
// ---------------------------------------------------------------------------
__global__ __launch_bounds__(256) void gn_meanmax(
    const float* __restrict__ dc, const float* __restrict__ stats,
    const float* __restrict__ gamma, const float* __restrict__ beta,
    float* __restrict__ cm, float* __restrict__ cx)
{
    int t = blockIdx.x * 256 + threadIdx.x;
    if (t >= BATCH * HW) return;
    int b = t >> 14;
    int pix = t & (HW - 1);
    float msum = 0.f, mmax = -INFINITY;
    #pragma unroll 8
    for (int c = 0; c < 64; c++) {
        int g = c >> 2;
        float mean = stats[b * 16 + g];
        float rstd = stats[32 + b * 16 + g];
        size_t idx = ((size_t)b * 64 + c) * HW + pix;
        float v = (dc[idx] - mean) * rstd * gamma[c] + beta[c];
        v = fmaxf(v, 0.f);
        msum += v;
        mmax = fmaxf(mmax, v);
    }
    cm[t] = msum * (1.0f / 64.0f);
    cx[t] = mmax;
}

// ---------------------------------------------------------------------------
// 1-ch 3x3 convs over cm/cx + sigmoid -> av, mv maps.
// ---------------------------------------------------------------------------
__global__ __launch_bounds__(256) void attn_sig(
    const float* __restrict__ cm, const float* __restrict__ cx,
    const float* __restrict__ wa, const float* __restrict__ ba,
    const float* __restrict__ wb, const float* __restrict__ bb,
    float* __restrict__ avb, float* __restrict__ mvb)
{
    int t = blockIdx.x * 256 + threadIdx.x;
    if (t >= BATCH * HW) return;
    int b = t >> 14;
    int pix = t & (HW - 1);
    int i = pix >> 7, j = pix & (W - 1);
    float sa = ba[0], sb = bb[0];
    #pragma unroll
    for (int di = 0; di < 3; di++) {
        int ii = i + di - 1;
        if (ii < 0 || ii >= H) continue;
        #pragma unroll
        for (int dj = 0; dj < 3; dj++) {
            int jj = j + dj - 1;
            if (jj < 0 || jj >= W) continue;
            int q = (b << 14) + (ii << 7) + jj;
            sa = fmaf(cm[q], wa[di * 3 + dj], sa);
            sb = fmaf(cx[q], wb[di * 3 + dj], sb);
        }
    }
    avb[t] = sigmoidf_(sa);
    mvb[t] = sigmoidf_(sb);
}

// ---------------------------------------------------------------------------
// Fused GN+relu + attention-scale + concat + transpose:
// catt[b][pix][0:64] = av*GN(dc), catt[b][pix][64:128] = mv*GN(dc)
// ---------------------------------------------------------------------------
__global__ __launch_bounds__(256) void attn_cat_t(
    const float* __restrict__ dc, const float* __restrict__ stats,
    const float* __restrict__ gamma, const float* __restrict__ beta,
    const float* __restrict__ avb, const float* __restrict__ mvb,
    float* __restrict__ catt)
{
    __shared__ float tile[64][65];
    __shared__ float avs[64], mvs[64];
    int blk = blockIdx.x;               // 512
    int b  = blk >> 8;
    int p0 = (blk & 255) * 64;
    int tr = threadIdx.x >> 6;
    int tc = threadIdx.x & 63;
    if (threadIdx.x < 64)       avs[threadIdx.x] = avb[(size_t)b * HW + p0 + threadIdx.x];
    else if (threadIdx.x < 128) mvs[threadIdx.x - 64] = mvb[(size_t)b * HW + p0 + threadIdx.x - 64];
    #pragma unroll
    for (int r = 0; r < 16; r++) {
        int c = r * 4 + tr;
        float mean = stats[b * 16 + (c >> 2)];
        float rstd = stats[32 + b * 16 + (c >> 2)];
        float v = dc[((size_t)b * 64 + c) * HW + p0 + tc];
        tile[c][tc] = fmaxf((v - mean) * rstd * gamma[c] + beta[c], 0.f);
    }
    __syncthreads();
    #pragma unroll
    for (int r = 0; r < 16; r++) {
        int p = r * 4 + tr;
        float v = tile[tc][p];
        float* cr = catt + ((size_t)b * HW + p0 + p) * 128;
        cr[tc]      = avs[p] * v;
        cr[64 + tc] = mvs[p] * v;
    }
}

// ---------------------------------------------------------------------------
// Final GN + relu -> d_out
// ---------------------------------------------------------------------------
__global__ __launch_bounds__(256) void gn_final(
    const float* __restrict__ dc, const float* __restrict__ stats,
    const float* __restrict__ gamma, const float* __restrict__ beta,
    float* __restrict__ out)
{
    int t = blockIdx.x * 256 + threadIdx.x;
    if (t >= BATCH * 64 * HW) return;
    int c = (t >> 14) & 63;
    int b = t >> 20;
    int g = c >> 2;
    float mean = stats[b * 16 + g];
    float rstd = stats[32 + b * 16 + g];
    float v = (dc[t] - mean) * rstd * gamma[c] + beta[c];
    out[t] = fmaxf(v, 0.f);
}

// ---------------------------------------------------------------------------
extern "C" void kernel_launch(void* const* d_in, const int* in_sizes, int n_in,
                              void* d_out, int out_size, void* d_ws, size_t ws_size,
                              hipStream_t stream) {
    (void)in_sizes; (void)n_in; (void)out_size; (void)ws_size;
    const float* x   = (const float*)d_in[0];
    const float* wp1 = (const float*)d_in[1];
    const float* bp1 = (const float*)d_in[2];
    const float* wm1 = (const float*)d_in[3];
    const float* bm1 = (const float*)d_in[4];
    const float* wc1 = (const float*)d_in[5];
    const float* g1  = (const float*)d_in[6];
    const float* be1 = (const float*)d_in[7];
    const float* wa  = (const float*)d_in[8];
    const float* ba  = (const float*)d_in[9];
    const float* wb  = (const float*)d_in[10];
    const float* bb  = (const float*)d_in[11];
    const float* wp2 = (const float*)d_in[12];
    const float* bp2 = (const float*)d_in[13];
    const float* wm2 = (const float*)d_in[14];
    const float* bm2 = (const float*)d_in[15];
    const float* wc2 = (const float*)d_in[16];
    const float* g2  = (const float*)d_in[17];
    const float* be2 = (const float*)d_in[18];
    float* out = (float*)d_out;

    // ---- workspace layout (floats) ----
    float* ws   = (float*)d_ws;
    float* offb = ws;                              //  884736
    float* dcb  = offb + 2 * 27 * HW;              // 2097152
    float* paux = dcb + 2 * 64 * HW;               // 2097152 (partb overflow)
    float* cmb  = paux + 2 * 64 * HW;              //   32768
    float* cxb  = cmb + 2 * HW;                    //   32768
    float* avb  = cxb + 2 * HW;                    //   32768
    float* mvb  = avb + 2 * HW;                    //   32768
    float* catt = mvb + 2 * HW;                    // 4194304 [B][HW][128]
    float* stb  = catt + (size_t)2 * 128 * HW;     //      64
    float* wo1  = stb + 64;                        //   18432
    float* wo2  = wo1 + 64 * 9 * 32;               //   36864
    unsigned short* wtp1 = (unsigned short*)(wo2 + 128 * 9 * 32);
    unsigned short* wtp2 = wtp1 + 64 * 8 * 96;
    // conv partials (4*2*27*HW = 3.54M floats) alias dcb+paux (dead then)
    float* partb = dcb;
    // x transposed [B][HW][64] in d_out scratch (rewritten by gn_final)
    float* xt1 = out;

    const int NPIXB = (BATCH * HW + 255) / 256;      // 128
    const int NCONV = NPIXB * 4;                     // 512
    const int NRED  = (BATCH * 27 * HW / 4 + 255) / 256;
    const int NDEF  = BATCH * HW / 64;               // 512

    transpose_x64<<<512, 256, 0, stream>>>(x, xt1);
    transpose_wpad<64><<<(64 * 8 * 96 + 255) / 256, 256, 0, stream>>>(wc1, wtp1);
    transpose_wpad<128><<<(64 * 16 * 96 + 255) / 256, 256, 0, stream>>>(wc2, wtp2);
    transpose_woff<64><<<(27 * 64 * 9 + 255) / 256, 256, 0, stream>>>(wp1, wm1, wo1);
    transpose_woff<128><<<(27 * 128 * 9 + 255) / 256, 256, 0, stream>>>(wp2, wm2, wo2);

    // ---- stage 1 ----
    conv_off_part<64><<<NCONV, 256, 0, stream>>>(xt1, wo1, partb);
    conv_off_reduce<<<NRED, 256, 0, stream>>>(partb, bp1, bm1, offb);
    deform_mfma<64><<<NDEF, 576, 0, stream>>>(xt1, offb, wtp1, dcb);
    gn_stats<<<32, 256, 0, stream>>>(dcb, stb);
    gn_meanmax<<<NPIXB, 256, 0, stream>>>(dcb, stb, g1, be1, cmb, cxb);
    attn_sig<<<NPIXB, 256, 0, stream>>>(cmb, cxb, wa, ba, wb, bb, avb, mvb);
    attn_cat_t<<<512, 256, 0, stream>>>(dcb, stb, g1, be1, avb, mvb, catt);

    // ---- stage 2 ----
    conv_off_part<128><<<NCONV, 256, 0, stream>>>(catt, wo2, partb);
    conv_off_reduce<<<NRED, 256, 0, stream>>>(partb, bp2, bm2, offb);
    deform_mfma<128><<<NDEF, 576, 0, stream>>>(catt, offb, wtp2, dcb);
    gn_stats<<<32, 256, 0, stream>>>(dcb, stb);
    gn_final<<<(BATCH * 64 * HW + 255) / 256, 256, 0, stream>>>(dcb, stb, g2, be2, out);
}

// Round 7
// 284.721 us; speedup vs baseline: 1.5090x; 1.1856x over previous
//
#include <hip/hip_runtime.h>
#include <hip/hip_bf16.h>
#include <math.h>

#define H 128
#define W 128
#define HW (H*W)
#define BATCH 2

typedef __attribute__((ext_vector_type(8))) short          bf16x8;
typedef __attribute__((ext_vector_type(4))) float          f32x4;
typedef __attribute__((ext_vector_type(8))) unsigned short u16x8;

__device__ __forceinline__ float sigmoidf_(float x){ return 1.0f/(1.0f + expf(-x)); }

__device__ __forceinline__ unsigned short f2bf(float f) {
    __hip_bfloat16 h = __float2bfloat16(f);          // RTNE
    return __builtin_bit_cast(unsigned short, h);
}
__device__ __forceinline__ float bf2f(unsigned short b) {
    return __uint_as_float(((unsigned)b) << 16);
}
__device__ __forceinline__ float bflo(unsigned u){ return __uint_as_float(u << 16); }
__device__ __forceinline__ float bfhi(unsigned u){ return __uint_as_float(u & 0xFFFF0000u); }

// ---------------------------------------------------------------------------
// Transpose x [B][64][HW] fp32 -> xt [B][HW][64] bf16
// ---------------------------------------------------------------------------
__global__ __launch_bounds__(256) void transpose_x64(
    const float* __restrict__ x, unsigned short* __restrict__ xt)
{
    __shared__ float tile[64][65];
    int blk = blockIdx.x;               // 512 = 2 b * 256 pix-tiles
    int b  = blk >> 8;
    int p0 = (blk & 255) * 64;
    int tr = threadIdx.x >> 6;
    int tc = threadIdx.x & 63;
    #pragma unroll
    for (int r = 0; r < 16; r++) {
        int c = r * 4 + tr;
        tile[c][tc] = x[((size_t)b * 64 + c) * HW + p0 + tc];
    }
    __syncthreads();
    #pragma unroll
    for (int r = 0; r < 16; r++) {
        int p = r * 4 + tr;
        xt[((size_t)b * HW + p0 + p) * 64 + tc] = f2bf(tile[tc][p]);
    }
}

// ---------------------------------------------------------------------------
// Deform-conv weights: wc [64][CIN][9] fp32 -> wtp [64][NCH*96] bf16,
// k' = ch*96 + n*8 + cl  (n 0..8 real, 9..11 zero-pad)
// ---------------------------------------------------------------------------
template<int CIN>
__global__ __launch_bounds__(256) void transpose_wpad(
    const float* __restrict__ wc, unsigned short* __restrict__ wtp)
{
    constexpr int NCH = CIN / 8;
    int t = blockIdx.x * 256 + threadIdx.x;
    if (t >= 64 * NCH * 96) return;
    int oc = t / (NCH * 96);
    int r  = t - oc * (NCH * 96);
    int ch = r / 96;
    int q  = r - ch * 96;
    int n  = q >> 3, cl = q & 7;
    float v = (n < 9) ? wc[((size_t)oc * CIN + ch * 8 + cl) * 9 + n] : 0.f;
    wtp[t] = f2bf(v);
}

// ---------------------------------------------------------------------------
// Offset/mask conv weights: wp [18][CIN][9], wm [9][CIN][9]
//   -> wt [(c*9+n)*32 + oc], oc 0..26
// ---------------------------------------------------------------------------
template<int CIN>
__global__ __launch_bounds__(256) void transpose_woff(
    const float* __restrict__ wp, const float* __restrict__ wm,
    float* __restrict__ wt)
{
    int t = blockIdx.x * 256 + threadIdx.x;
    if (t >= 27 * CIN * 9) return;
    int oc  = t / (CIN * 9);
    int rem = t - oc * (CIN * 9);
    int c = rem / 9, n = rem - (rem / 9) * 9;
    float v = (oc < 18) ? wp[((size_t)oc * CIN + c) * 9 + n]
                        : wm[((size_t)(oc - 18) * CIN + c) * 9 + n];
    wt[(size_t)(c * 9 + n) * 32 + oc] = v;
}

// ---------------------------------------------------------------------------
// Offset/mask 3x3 conv from channel-major bf16 xt [B][HW][CIN]; thread = 1
// pixel, all 27 oc, 1/4 channel slice. part: [split][B][27][HW]
// ---------------------------------------------------------------------------
template<int CIN>
__global__ __launch_bounds__(256) void conv_off_part(
    const unsigned short* __restrict__ xt,
    const float* __restrict__ wt,
    float* __restrict__ part)
{
    constexpr int CPS = CIN / 4;
    int bid   = blockIdx.x;
    int split = bid & 3;
    int tile  = bid >> 2;
    int t   = tile * 256 + threadIdx.x;
    int b   = t >> 14;
    int pix = t & (HW - 1);
    int i = pix >> 7, j = pix & (W - 1);

    const unsigned short* nbase[9];
    float msk[9];
    #pragma unroll
    for (int r = 0; r < 9; r++) {
        int ii = i + r / 3 - 1;
        int jj = j + r % 3 - 1;
        bool v = (ii >= 0 && ii < H && jj >= 0 && jj < W);
        nbase[r] = xt + ((size_t)b * HW + (v ? (ii * W + jj) : 0)) * CIN;
        msk[r]   = v ? 1.f : 0.f;
    }

    float acc[27];
    #pragma unroll
    for (int o = 0; o < 27; o++) acc[o] = 0.f;

    for (int cb = 0; cb < CPS; cb += 8) {
        int c0 = split * CPS + cb;
        u16x8 nb[9];
        #pragma unroll
        for (int r = 0; r < 9; r++)
            nb[r] = *reinterpret_cast<const u16x8*>(nbase[r] + c0);
        #pragma unroll
        for (int n = 0; n < 9; n++) {
            float mn = msk[n];
            const unsigned* nd = reinterpret_cast<const unsigned*>(&nb[n]);
            #pragma unroll
            for (int d = 0; d < 4; d++) {
                float xlo = bflo(nd[d]) * mn;
                float xhi = bfhi(nd[d]) * mn;
                const float* w0 = wt + ((size_t)(c0 + 2 * d) * 9 + n) * 32;
                const float* w1 = w0 + 9 * 32;
                #pragma unroll
                for (int o = 0; o < 27; o++)
                    acc[o] = fmaf(w0[o], xlo, acc[o]);
                #pragma unroll
                for (int o = 0; o < 27; o++)
                    acc[o] = fmaf(w1[o], xhi, acc[o]);
            }
        }
    }

    float* pb = part + (((size_t)split * BATCH + b) * 27) * HW + pix;
    #pragma unroll
    for (int o = 0; o < 27; o++) pb[(size_t)o * HW] = acc[o];
}

// ---------------------------------------------------------------------------
// Reduce 4 channel-split partials, add bias, sigmoid mask channels.
// ---------------------------------------------------------------------------
__global__ __launch_bounds__(256) void conv_off_reduce(
    const float* __restrict__ part, const float* __restrict__ bp,
    const float* __restrict__ bm, float* __restrict__ out)
{
    int t4 = blockIdx.x * 256 + threadIdx.x;
    if (t4 >= BATCH * 27 * HW / 4) return;
    int t   = t4 * 4;
    int b   = t / (27 * HW);
    int rem = t - b * 27 * HW;
    int oc  = rem / HW;
    int pix = rem - oc * HW;

    float4 s = make_float4(0.f, 0.f, 0.f, 0.f);
    #pragma unroll
    for (int sp = 0; sp < 4; sp++) {
        float4 v = *reinterpret_cast<const float4*>(
            part + (((size_t)sp * BATCH + b) * 27 + oc) * HW + pix);
        s.x += v.x; s.y += v.y; s.z += v.z; s.w += v.w;
    }
    if (oc < 18) {
        float bv = bp[oc];
        s.x += bv; s.y += bv; s.z += bv; s.w += bv;
    } else {
        float bv = bm[oc - 18];
        s.x = sigmoidf_(s.x + bv); s.y = sigmoidf_(s.y + bv);
        s.z = sigmoidf_(s.z + bv); s.w = sigmoidf_(s.w + bv);
    }
    *reinterpret_cast<float4*>(out + ((size_t)b * 27 + oc) * HW + pix) = s;
}

// ---------------------------------------------------------------------------
// Deformable sampling + main conv via MFMA (bf16 in, fp32 accum).
// R3-proven structure: 512 threads, 64 pix x 64 oc per block, meta in LDS,
// weights+samples double-buffered in LDS; per chunk: MFMA(cur) ->
// sample+stage(next) -> barrier. Only change vs R3: gathers read bf16 xt
// (one u16x8 load = 8 channels; halves VMEM instruction count).
// ---------------------------------------------------------------------------
template<int CIN>
__global__ __launch_bounds__(512, 4) void deform_mfma(
    const unsigned short* __restrict__ xt,  // [B][HW][CIN] bf16
    const float* __restrict__ off,          // [B][27][HW]
    const unsigned short* __restrict__ wtp, // [64][NCH*96] bf16
    float* __restrict__ out)                // [B][64][HW]
{
    constexpr int NCH  = CIN / 8;
    constexpr int SROW = 104;
    __shared__ __align__(16) unsigned short sbuf[2][64][SROW];
    __shared__ __align__(16) unsigned short wbuf[2][64][SROW];
    __shared__ __align__(16) unsigned short meta[9][64][8];

    int tid  = threadIdx.x;
    int pix0 = blockIdx.x * 64;
    int b    = pix0 >> 14;
    int base = pix0 & (HW - 1);
    int i    = base >> 7;
    int j0   = base & 127;

    // ---- bilinear metadata (once per block): 4x u16 pix-idx + 4x bf16 wt ----
    for (int task = tid; task < 576; task += 512) {
        int p = task & 63, n = task >> 6;
        int j = j0 + p;
        const float* ob = off + (size_t)b * 27 * HW + (i << 7) + j;
        float px = ob[(size_t)n * HW]       + (float)(n / 3 - 1) + (float)(i + 1);
        float py = ob[(size_t)(9 + n) * HW] + (float)(n % 3 - 1) + (float)(j + 1);
        float mk = ob[(size_t)(18 + n) * HW];
        float fx = floorf(px), fy = floorf(py);
        const float lim = 129.0f;            // Hp-1 = Wp-1
        int qltx = (int)fminf(fmaxf(fx, 0.f), lim);
        int qlty = (int)fminf(fmaxf(fy, 0.f), lim);
        int qrbx = (int)fminf(fmaxf(fx + 1.f, 0.f), lim);
        int qrby = (int)fminf(fmaxf(fy + 1.f, 0.f), lim);
        float pxc = fminf(fmaxf(px, 0.f), lim);
        float pyc = fminf(fmaxf(py, 0.f), lim);
        float gxl = 1.f + ((float)qltx - pxc);
        float gxr = 1.f - ((float)qrbx - pxc);
        float gyl = 1.f + ((float)qlty - pyc);
        float gyr = 1.f - ((float)qrby - pyc);
        int   xs[4] = {qltx, qrbx, qltx, qrbx};
        int   ys[4] = {qlty, qrby, qrby, qlty};
        float gs[4] = {gxl * gyl, gxr * gyr, gxl * gyr, gxr * gyl};
        u16x8 m;
        #pragma unroll
        for (int q = 0; q < 4; q++) {
            int qx = xs[q], qy = ys[q];
            bool valid = (qx >= 1 && qx <= H && qy >= 1 && qy <= W);
            m[q]     = valid ? (unsigned short)((qx - 1) * W + (qy - 1)) : (unsigned short)0;
            m[4 + q] = f2bf(valid ? gs[q] * mk : 0.f);
        }
        *reinterpret_cast<u16x8*>(&meta[n][p][0]) = m;
    }
    // ---- zero-init pad k-slots (72..95) of both sample buffers ----
    for (int idx = tid; idx < 2 * 64 * 3; idx += 512) {
        int bi = idx / 192;
        int r2 = idx - bi * 192;
        int row = r2 / 3, sg = r2 - (r2 / 3) * 3;
        u16x8 z = {0,0,0,0,0,0,0,0};
        *reinterpret_cast<u16x8*>(&sbuf[bi][row][72 + sg * 8]) = z;
    }
    __syncthreads();

    const unsigned short* xtb = xt + (size_t)b * HW * CIN;

    auto stage_w = [&](int ch, int bi) {
        #pragma unroll
        for (int pass = 0; pass < 2; pass++) {
            int idx = pass * 512 + tid;
            int row = idx >> 4, seg = idx & 15;
            if (seg < 12) {
                u16x8 v = *reinterpret_cast<const u16x8*>(
                    wtp + (size_t)row * (NCH * 96) + ch * 96 + seg * 8);
                *reinterpret_cast<u16x8*>(&wbuf[bi][row][seg * 8]) = v;
            }
        }
    };
    auto sample = [&](int ch, int bi) {
        for (int task = tid; task < 576; task += 512) {
            int p = task & 63, n = task >> 6;
            u16x8 m = *reinterpret_cast<const u16x8*>(&meta[n][p][0]);
            float vac[8];
            #pragma unroll
            for (int e = 0; e < 8; e++) vac[e] = 0.f;
            #pragma unroll
            for (int q = 0; q < 4; q++) {
                const unsigned short* sp = xtb + (size_t)m[q] * CIN + ch * 8;
                u16x8 v = *reinterpret_cast<const u16x8*>(sp);
                float wq = bf2f(m[4 + q]);
                const unsigned* vd = reinterpret_cast<const unsigned*>(&v);
                #pragma unroll
                for (int d = 0; d < 4; d++) {
                    vac[2 * d]     = fmaf(bflo(vd[d]), wq, vac[2 * d]);
                    vac[2 * d + 1] = fmaf(bfhi(vd[d]), wq, vac[2 * d + 1]);
                }
            }
            u16x8 o;
            #pragma unroll
            for (int e = 0; e < 8; e++) o[e] = f2bf(vac[e]);
            *reinterpret_cast<u16x8*>(&sbuf[bi][p][n * 8]) = o;
        }
    };

    // prologue: fill chunk 0
    stage_w(0, 0);
    sample(0, 0);
    __syncthreads();

    int lane = tid & 63, wv = tid >> 6;
    int ocq = wv & 1, pq = wv >> 1;
    int lr = lane & 15, lg = lane >> 4;
    int srow = pq * 16 + lr;
    int wrow = ocq * 32 + lr;

    f32x4 acc0 = {0.f, 0.f, 0.f, 0.f};
    f32x4 acc1 = {0.f, 0.f, 0.f, 0.f};

    for (int ch = 0; ch < NCH; ch++) {
        int cur = ch & 1;
        #pragma unroll
        for (int ks = 0; ks < 3; ks++) {
            bf16x8 bfr = *reinterpret_cast<const bf16x8*>(&sbuf[cur][srow][ks * 32 + lg * 8]);
            bf16x8 a0  = *reinterpret_cast<const bf16x8*>(&wbuf[cur][wrow][ks * 32 + lg * 8]);
            bf16x8 a1  = *reinterpret_cast<const bf16x8*>(&wbuf[cur][wrow + 16][ks * 32 + lg * 8]);
            acc0 = __builtin_amdgcn_mfma_f32_16x16x32_bf16(a0, bfr, acc0, 0, 0, 0);
            acc1 = __builtin_amdgcn_mfma_f32_16x16x32_bf16(a1, bfr, acc1, 0, 0, 0);
        }
        if (ch + 1 < NCH) {
            sample(ch + 1, cur ^ 1);
            stage_w(ch + 1, cur ^ 1);
        }
        __syncthreads();
    }

    // ---- store: D col = lane&15 (pixel), row = (lane>>4)*4 + r (oc) ----
    int pixo = base + pq * 16 + lr;
    float* ob0 = out + ((size_t)b * 64 + ocq * 32 + lg * 4) * HW + pixo;
    #pragma unroll
    for (int r = 0; r < 4; r++) ob0[(size_t)r * HW] = acc0[r];
    float* ob1 = out + ((size_t)b * 64 + ocq * 32 + 16 + lg * 4) * HW + pixo;
    #pragma unroll
    for (int r = 0; r < 4; r++) ob1[(size_t)r * HW] = acc1[r];
}

// ---------------------------------------------------------------------------
// Group-norm statistics. One block per (b, group).
// ---------------------------------------------------------------------------
__global__ __launch_bounds__(256) void gn_stats(
    const float* __restrict__ buf, float* __restrict__ stats)
{
    int bg = blockIdx.x;
    const float4* v = reinterpret_cast<const float4*>(buf + (size_t)bg * 4 * HW);
    float sum = 0.f, ssq = 0.f;
    for (int idx = threadIdx.x; idx < 4 * HW / 4; idx += 256) {
        float4 x = v[idx];
        sum += x.x + x.y + x.z + x.w;
        ssq += x.x * x.x + x.y * x.y + x.z * x.z + x.w * x.w;
    }
    #pragma unroll
    for (int d = 32; d > 0; d >>= 1) {
        sum += __shfl_down(sum, d);
        ssq += __shfl_down(ssq, d);
    }
    __shared__ float ws1[4], ws2[4];
    int wid = threadIdx.x >> 6;
    if ((threadIdx.x & 63) == 0) { ws1[wid] = sum; ws2[wid] = ssq; }
    __syncthreads();
    if (threadIdx.x == 0) {
        float S = ws1[0] + ws1[1] + ws1[2] + ws1[3];
        float Q = ws2[0] + ws2[1] + ws2[2] + ws2[3];
        float mean = S * (1.0f / (4.0f * HW));
        float var  = Q * (1.0f / (4.0f * HW)) - mean * mean;
        stats[bg]      = mean;
        stats[32 + bg] = rsqrtf(var + 1e-5f);
    }
}

// ---------------------------------------------------------------------------
// GN(+relu) on the fly -> channel mean & max maps only.
// ---------------------------------------------------------------------------
__global__ __launch_bounds__(256) void gn_meanmax(
    const float* __restrict__ dc, const float* __restrict__ stats,
    const float* __restrict__ gamma, const float* __restrict__ beta,
    float* __restrict__ cm, float* __restrict__ cx)
{
    int t = blockIdx.x * 256 + threadIdx.x;
    if (t >= BATCH * HW) return;
    int b = t >> 14;
    int pix = t & (HW - 1);
    float msum = 0.f, mmax = -INFINITY;
    #pragma unroll 8
    for (int c = 0; c < 64; c++) {
        int g = c >> 2;
        float mean = stats[b * 16 + g];
        float rstd = stats[32 + b * 16 + g];
        size_t idx = ((size_t)b * 64 + c) * HW + pix;
        float v = (dc[idx] - mean) * rstd * gamma[c] + beta[c];
        v = fmaxf(v, 0.f);
        msum += v;
        mmax = fmaxf(mmax, v);
    }
    cm[t] = msum * (1.0f / 64.0f);
    cx[t] = mmax;
}

// ---------------------------------------------------------------------------
// 1-ch 3x3 convs over cm/cx + sigmoid -> av, mv maps.
// ---------------------------------------------------------------------------
__global__ __launch_bounds__(256) void attn_sig(
    const float* __restrict__ cm, const float* __restrict__ cx,
    const float* __restrict__ wa, const float* __restrict__ ba,
    const float* __restrict__ wb, const float* __restrict__ bb,
    float* __restrict__ avb, float* __restrict__ mvb)
{
    int t = blockIdx.x * 256 + threadIdx.x;
    if (t >= BATCH * HW) return;
    int b = t >> 14;
    int pix = t & (HW - 1);
    int i = pix >> 7, j = pix & (W - 1);
    float sa = ba[0], sb = bb[0];
    #pragma unroll
    for (int di = 0; di < 3; di++) {
        int ii = i + di - 1;
        if (ii < 0 || ii >= H) continue;
        #pragma unroll
        for (int dj = 0; dj < 3; dj++) {
            int jj = j + dj - 1;
            if (jj < 0 || jj >= W) continue;
            int q = (b << 14) + (ii << 7) + jj;
            sa = fmaf(cm[q], wa[di * 3 + dj], sa);
            sb = fmaf(cx[q], wb[di * 3 + dj], sb);
        }
    }
    avb[t] = sigmoidf_(sa);
    mvb[t] = sigmoidf_(sb);
}

// ---------------------------------------------------------------------------
// Fused GN+relu + attention-scale + concat + transpose -> bf16 catt:
// catt[b][pix][0:64] = av*GN(dc), catt[b][pix][64:128] = mv*GN(dc)
// ---------------------------------------------------------------------------
__global__ __launch_bounds__(256) void attn_cat_t(
    const float* __restrict__ dc, const float* __restrict__ stats,
    const float* __restrict__ gamma, const float* __restrict__ beta,
    const float* __restrict__ avb, const float* __restrict__ mvb,
    unsigned short* __restrict__ catt)
{
    __shared__ float tile[64][65];
    __shared__ float avs[64], mvs[64];
    int blk = blockIdx.x;               // 512
    int b  = blk >> 8;
    int p0 = (blk & 255) * 64;
    int tr = threadIdx.x >> 6;
    int tc = threadIdx.x & 63;
    if (threadIdx.x < 64)       avs[threadIdx.x] = avb[(size_t)b * HW + p0 + threadIdx.x];
    else if (threadIdx.x < 128) mvs[threadIdx.x - 64] = mvb[(size_t)b * HW + p0 + threadIdx.x - 64];
    #pragma unroll
    for (int r = 0; r < 16; r++) {
        int c = r * 4 + tr;
        float mean = stats[b * 16 + (c >> 2)];
        float rstd = stats[32 + b * 16 + (c >> 2)];
        float v = dc[((size_t)b * 64 + c) * HW + p0 + tc];
        tile[c][tc] = fmaxf((v - mean) * rstd * gamma[c] + beta[c], 0.f);
    }
    __syncthreads();
    #pragma unroll
    for (int r = 0; r < 16; r++) {
        int p = r * 4 + tr;
        float v = tile[tc][p];
        unsigned short* cr = catt + ((size_t)b * HW + p0 + p) * 128;
        cr[tc]      = f2bf(avs[p] * v);
        cr[64 + tc] = f2bf(mvs[p] * v);
    }
}

// ---------------------------------------------------------------------------
// Final GN + relu -> d_out
// ---------------------------------------------------------------------------
__global__ __launch_bounds__(256) void gn_final(
    const float* __restrict__ dc, const float* __restrict__ stats,
    const float* __restrict__ gamma, const float* __restrict__ beta,
    float* __restrict__ out)
{
    int t = blockIdx.x * 256 + threadIdx.x;
    if (t >= BATCH * 64 * HW) return;
    int c = (t >> 14) & 63;
    int b = t >> 20;
    int g = c >> 2;
    float mean = stats[b * 16 + g];
    float rstd = stats[32 + b * 16 + g];
    float v = (dc[t] - mean) * rstd * gamma[c] + beta[c];
    out[t] = fmaxf(v, 0.f);
}

// ---------------------------------------------------------------------------
extern "C" void kernel_launch(void* const* d_in, const int* in_sizes, int n_in,
                              void* d_out, int out_size, void* d_ws, size_t ws_size,
                              hipStream_t stream) {
    (void)in_sizes; (void)n_in; (void)out_size; (void)ws_size;
    const float* x   = (const float*)d_in[0];
    const float* wp1 = (const float*)d_in[1];
    const float* bp1 = (const float*)d_in[2];
    const float* wm1 = (const float*)d_in[3];
    const float* bm1 = (const float*)d_in[4];
    const float* wc1 = (const float*)d_in[5];
    const float* g1  = (const float*)d_in[6];
    const float* be1 = (const float*)d_in[7];
    const float* wa  = (const float*)d_in[8];
    const float* ba  = (const float*)d_in[9];
    const float* wb  = (const float*)d_in[10];
    const float* bb  = (const float*)d_in[11];
    const float* wp2 = (const float*)d_in[12];
    const float* bp2 = (const float*)d_in[13];
    const float* wm2 = (const float*)d_in[14];
    const float* bm2 = (const float*)d_in[15];
    const float* wc2 = (const float*)d_in[16];
    const float* g2  = (const float*)d_in[17];
    const float* be2 = (const float*)d_in[18];
    float* out = (float*)d_out;

    // ---- workspace layout (floats) ----
    float* ws   = (float*)d_ws;
    float* offb = ws;                              //  884736
    float* dcb  = offb + 2 * 27 * HW;              // 2097152
    float* paux = dcb + 2 * 64 * HW;               // 2097152 (partb overflow)
    float* cmb  = paux + 2 * 64 * HW;              //   32768
    float* cxb  = cmb + 2 * HW;                    //   32768
    float* avb  = cxb + 2 * HW;                    //   32768
    float* mvb  = avb + 2 * HW;                    //   32768
    unsigned short* catt = (unsigned short*)(mvb + 2 * HW);  // 2*HW*128 u16
    float* stb  = (float*)(catt + (size_t)2 * 128 * HW);     //      64
    float* wo1  = stb + 64;                        //   18432
    float* wo2  = wo1 + 64 * 9 * 32;               //   36864
    unsigned short* wtp1 = (unsigned short*)(wo2 + 128 * 9 * 32);
    unsigned short* wtp2 = wtp1 + 64 * 8 * 96;
    // conv partials (4*2*27*HW = 3.54M floats) alias dcb+paux (dead then)
    float* partb = dcb;
    // x transposed [B][HW][64] bf16 in d_out scratch (rewritten by gn_final)
    unsigned short* xt1 = (unsigned short*)out;    // 2.1M u16 = 4.2 MB <= 8.4

    const int NPIXB = (BATCH * HW + 255) / 256;      // 128
    const int NCONV = NPIXB * 4;                     // 512
    const int NRED  = (BATCH * 27 * HW / 4 + 255) / 256;
    const int NDEF  = BATCH * HW / 64;               // 512

    transpose_x64<<<512, 256, 0, stream>>>(x, xt1);
    transpose_wpad<64><<<(64 * 8 * 96 + 255) / 256, 256, 0, stream>>>(wc1, wtp1);
    transpose_wpad<128><<<(64 * 16 * 96 + 255) / 256, 256, 0, stream>>>(wc2, wtp2);
    transpose_woff<64><<<(27 * 64 * 9 + 255) / 256, 256, 0, stream>>>(wp1, wm1, wo1);
    transpose_woff<128><<<(27 * 128 * 9 + 255) / 256, 256, 0, stream>>>(wp2, wm2, wo2);

    // ---- stage 1 ----
    conv_off_part<64><<<NCONV, 256, 0, stream>>>(xt1, wo1, partb);
    conv_off_reduce<<<NRED, 256, 0, stream>>>(partb, bp1, bm1, offb);
    deform_mfma<64><<<NDEF, 512, 0, stream>>>(xt1, offb, wtp1, dcb);
    gn_stats<<<32, 256, 0, stream>>>(dcb, stb);
    gn_meanmax<<<NPIXB, 256, 0, stream>>>(dcb, stb, g1, be1, cmb, cxb);
    attn_sig<<<NPIXB, 256, 0, stream>>>(cmb, cxb, wa, ba, wb, bb, avb, mvb);
    attn_cat_t<<<512, 256, 0, stream>>>(dcb, stb, g1, be1, avb, mvb, catt);

    // ---- stage 2 ----
    conv_off_part<128><<<NCONV, 256, 0, stream>>>(catt, wo2, partb);
    conv_off_reduce<<<NRED, 256, 0, stream>>>(partb, bp2, bm2, offb);
    deform_mfma<128><<<NDEF, 512, 0, stream>>>(catt, offb, wtp2, dcb);
    gn_stats<<<32, 256, 0, stream>>>(dcb, stb);
    gn_final<<<(BATCH * 64 * HW + 255) / 256, 256, 0, stream>>>(dcb, stb, g2, be2, out);
}

// Round 9
// 182.330 us; speedup vs baseline: 2.3564x; 1.5616x over previous
//
#include <hip/hip_runtime.h>
#include <hip/hip_bf16.h>
#include <math.h>

#define H 128
#define W 128
#define HW (H*W)
#define BATCH 2

typedef __attribute__((ext_vector_type(8))) short          bf16x8;
typedef __attribute__((ext_vector_type(4))) float          f32x4;
typedef __attribute__((ext_vector_type(8))) unsigned short u16x8;

__device__ __forceinline__ float sigmoidf_(float x){ return 1.0f/(1.0f + expf(-x)); }

__device__ __forceinline__ unsigned short f2bf(float f) {
    __hip_bfloat16 h = __float2bfloat16(f);          // RTNE
    return __builtin_bit_cast(unsigned short, h);
}
__device__ __forceinline__ float bf2f(unsigned short b) {
    return __uint_as_float(((unsigned)b) << 16);
}
__device__ __forceinline__ float bflo(unsigned u){ return __uint_as_float(u << 16); }
__device__ __forceinline__ float bfhi(unsigned u){ return __uint_as_float(u & 0xFFFF0000u); }

// ---------------------------------------------------------------------------
// Transpose x [B][64][HW] fp32 -> xt [B][HW][64] bf16
// ---------------------------------------------------------------------------
__global__ __launch_bounds__(256) void transpose_x64(
    const float* __restrict__ x, unsigned short* __restrict__ xt)
{
    __shared__ float tile[64][65];
    int blk = blockIdx.x;               // 512 = 2 b * 256 pix-tiles
    int b  = blk >> 8;
    int p0 = (blk & 255) * 64;
    int tr = threadIdx.x >> 6;
    int tc = threadIdx.x & 63;
    #pragma unroll
    for (int r = 0; r < 16; r++) {
        int c = r * 4 + tr;
        tile[c][tc] = x[((size_t)b * 64 + c) * HW + p0 + tc];
    }
    __syncthreads();
    #pragma unroll
    for (int r = 0; r < 16; r++) {
        int p = r * 4 + tr;
        xt[((size_t)b * HW + p0 + p) * 64 + tc] = f2bf(tile[tc][p]);
    }
}

// ---------------------------------------------------------------------------
// Deform-conv weights: wc [64][CIN][9] fp32 -> wtp [64][NCH*96] bf16,
// k' = ch*96 + n*8 + cl  (n 0..8 real, 9..11 zero-pad)
// ---------------------------------------------------------------------------
template<int CIN>
__global__ __launch_bounds__(256) void transpose_wpad(
    const float* __restrict__ wc, unsigned short* __restrict__ wtp)
{
    constexpr int NCH = CIN / 8;
    int t = blockIdx.x * 256 + threadIdx.x;
    if (t >= 64 * NCH * 96) return;
    int oc = t / (NCH * 96);
    int r  = t - oc * (NCH * 96);
    int ch = r / 96;
    int q  = r - ch * 96;
    int n  = q >> 3, cl = q & 7;
    float v = (n < 9) ? wc[((size_t)oc * CIN + ch * 8 + cl) * 9 + n] : 0.f;
    wtp[t] = f2bf(v);
}

// ---------------------------------------------------------------------------
// Offset/mask conv weights -> MFMA layout: wop [32][NCH*96] bf16
// row oc: 0..17 = wp, 18..26 = wm, 27..31 = zero.  k' = ch*96 + n*8 + cl.
// ---------------------------------------------------------------------------
template<int CIN>
__global__ __launch_bounds__(256) void transpose_woffp(
    const float* __restrict__ wp, const float* __restrict__ wm,
    unsigned short* __restrict__ wop)
{
    constexpr int NCH = CIN / 8;
    int t = blockIdx.x * 256 + threadIdx.x;
    if (t >= 32 * NCH * 96) return;
    int oc = t / (NCH * 96);
    int r  = t - oc * (NCH * 96);
    int ch = r / 96;
    int q  = r - ch * 96;
    int n  = q >> 3, cl = q & 7;
    int c  = ch * 8 + cl;
    float v = 0.f;
    if (n < 9) {
        if (oc < 18)      v = wp[((size_t)oc * CIN + c) * 9 + n];
        else if (oc < 27) v = wm[((size_t)(oc - 18) * CIN + c) * 9 + n];
    }
    wop[t] = f2bf(v);
}

// ---------------------------------------------------------------------------
// Offset/mask 3x3 conv via MFMA: off[27 (pad 32)][pix] = Wop x im2col(xt).
// Block: 64 pix x 32 oc, 512 threads (8 waves; wave = one 16x16 tile:
// mt=wv&1 oc-half, nt=wv>>1 pix-quarter). Sampling = masked shifted u16x8
// copy. Epilogue fuses bias + sigmoid, writes offb [B][27][HW].
// ---------------------------------------------------------------------------
template<int CIN>
__global__ __launch_bounds__(512, 4) void conv_off_mfma(
    const unsigned short* __restrict__ xt,  // [B][HW][CIN] bf16
    const unsigned short* __restrict__ wop, // [32][NCH*96] bf16
    const float* __restrict__ bp,           // [18]
    const float* __restrict__ bm,           // [9]
    float* __restrict__ offb)               // [B][27][HW]
{
    constexpr int NCH  = CIN / 8;
    constexpr int SROW = 104;
    __shared__ __align__(16) unsigned short sbuf[2][64][SROW];
    __shared__ __align__(16) unsigned short wbuf[2][32][SROW];

    int tid  = threadIdx.x;
    int pix0 = blockIdx.x * 64;
    int b    = pix0 >> 14;
    int base = pix0 & (HW - 1);
    int i    = base >> 7;
    int j0   = base & 127;

    // ---- per-thread sampling tasks (1 or 2), meta in registers ----
    // task0: (p = tid&63, n = tid>>6 in 0..7); task1 (tid<64): (p=tid, n=8)
    int p0t = tid & 63, n0t = tid >> 6;
    int ii0 = i + n0t / 3 - 1, jj0 = j0 + p0t + n0t % 3 - 1;
    bool v0 = (ii0 >= 0 && ii0 < H && jj0 >= 0 && jj0 < W);
    size_t off0 = v0 ? (size_t)(ii0 * W + jj0) * CIN : 0;
    bool t1 = (tid < 64);
    int ii1 = i + 2 - 1, jj1 = j0 + tid + 2 - 1;      // n=8 -> di=2,dj=2
    bool v1 = t1 && (ii1 >= 0 && ii1 < H && jj1 >= 0 && jj1 < W);
    size_t off1 = v1 ? (size_t)(ii1 * W + jj1) * CIN : 0;

    // zero pad k-slots (72..95) of both sample buffers
    if (tid < 384) {
        int bi = tid >= 192;
        int r2 = tid - bi * 192;
        int row = r2 / 3, sg = r2 - (r2 / 3) * 3;
        u16x8 z = {0,0,0,0,0,0,0,0};
        *reinterpret_cast<u16x8*>(&sbuf[bi][row][72 + sg * 8]) = z;
    }

    const unsigned short* xtb = xt + (size_t)b * HW * CIN;
    const u16x8 zero8 = {0,0,0,0,0,0,0,0};

    auto sample = [&](int ch, int bi) {
        u16x8 v = v0 ? *reinterpret_cast<const u16x8*>(xtb + off0 + ch * 8) : zero8;
        *reinterpret_cast<u16x8*>(&sbuf[bi][p0t][n0t * 8]) = v;
        if (t1) {
            u16x8 w = v1 ? *reinterpret_cast<const u16x8*>(xtb + off1 + ch * 8) : zero8;
            *reinterpret_cast<u16x8*>(&sbuf[bi][tid][64]) = w;
        }
    };
    // weight tile: 32 rows x 16 segs = 512 slots -> ALL 512 threads (R7 bug:
    // tid<384 gate left rows 24..31 unstaged -> garbage mask channels)
    auto stage_w = [&](int ch, int bi) {
        int row = tid >> 4, seg = tid & 15;
        if (seg < 12) {
            u16x8 v = *reinterpret_cast<const u16x8*>(
                wop + (size_t)row * (NCH * 96) + ch * 96 + seg * 8);
            *reinterpret_cast<u16x8*>(&wbuf[bi][row][seg * 8]) = v;
        }
    };

    stage_w(0, 0);
    sample(0, 0);
    __syncthreads();

    int lane = tid & 63, wv = tid >> 6;
    int mt = wv & 1, nt = wv >> 1;          // oc-half, pix-quarter
    int lr = lane & 15, lg = lane >> 4;
    int srow = nt * 16 + lr;
    int wrow = mt * 16 + lr;

    f32x4 acc = {0.f, 0.f, 0.f, 0.f};

    for (int ch = 0; ch < NCH; ch++) {
        int cur = ch & 1;
        #pragma unroll
        for (int ks = 0; ks < 3; ks++) {
            bf16x8 bfr = *reinterpret_cast<const bf16x8*>(&sbuf[cur][srow][ks * 32 + lg * 8]);
            bf16x8 a   = *reinterpret_cast<const bf16x8*>(&wbuf[cur][wrow][ks * 32 + lg * 8]);
            acc = __builtin_amdgcn_mfma_f32_16x16x32_bf16(a, bfr, acc, 0, 0, 0);
        }
        if (ch + 1 < NCH) {
            sample(ch + 1, cur ^ 1);
            stage_w(ch + 1, cur ^ 1);
        }
        __syncthreads();
    }

    // epilogue: D col = lane&15 (pixel), row = lg*4 + r (oc within half)
    int pixo = base + nt * 16 + lr;
    #pragma unroll
    for (int r = 0; r < 4; r++) {
        int oc = mt * 16 + lg * 4 + r;
        if (oc < 27) {
            float v = acc[r];
            v = (oc < 18) ? (v + bp[oc]) : sigmoidf_(v + bm[oc - 18]);
            offb[((size_t)b * 27 + oc) * HW + pixo] = v;
        }
    }
}

// ---------------------------------------------------------------------------
// Deformable sampling + main conv via MFMA (bf16 in, fp32 accum).
// R3-proven structure + bf16 gathers (R6).
// ---------------------------------------------------------------------------
template<int CIN>
__global__ __launch_bounds__(512, 4) void deform_mfma(
    const unsigned short* __restrict__ xt,  // [B][HW][CIN] bf16
    const float* __restrict__ off,          // [B][27][HW]
    const unsigned short* __restrict__ wtp, // [64][NCH*96] bf16
    float* __restrict__ out)                // [B][64][HW]
{
    constexpr int NCH  = CIN / 8;
    constexpr int SROW = 104;
    __shared__ __align__(16) unsigned short sbuf[2][64][SROW];
    __shared__ __align__(16) unsigned short wbuf[2][64][SROW];
    __shared__ __align__(16) unsigned short meta[9][64][8];

    int tid  = threadIdx.x;
    int pix0 = blockIdx.x * 64;
    int b    = pix0 >> 14;
    int base = pix0 & (HW - 1);
    int i    = base >> 7;
    int j0   = base & 127;

    for (int task = tid; task < 576; task += 512) {
        int p = task & 63, n = task >> 6;
        int j = j0 + p;
        const float* ob = off + (size_t)b * 27 * HW + (i << 7) + j;
        float px = ob[(size_t)n * HW]       + (float)(n / 3 - 1) + (float)(i + 1);
        float py = ob[(size_t)(9 + n) * HW] + (float)(n % 3 - 1) + (float)(j + 1);
        float mk = ob[(size_t)(18 + n) * HW];
        float fx = floorf(px), fy = floorf(py);
        const float lim = 129.0f;            // Hp-1 = Wp-1
        int qltx = (int)fminf(fmaxf(fx, 0.f), lim);
        int qlty = (int)fminf(fmaxf(fy, 0.f), lim);
        int qrbx = (int)fminf(fmaxf(fx + 1.f, 0.f), lim);
        int qrby = (int)fminf(fmaxf(fy + 1.f, 0.f), lim);
        float pxc = fminf(fmaxf(px, 0.f), lim);
        float pyc = fminf(fmaxf(py, 0.f), lim);
        float gxl = 1.f + ((float)qltx - pxc);
        float gxr = 1.f - ((float)qrbx - pxc);
        float gyl = 1.f + ((float)qlty - pyc);
        float gyr = 1.f - ((float)qrby - pyc);
        int   xs[4] = {qltx, qrbx, qltx, qrbx};
        int   ys[4] = {qlty, qrby, qrby, qlty};
        float gs[4] = {gxl * gyl, gxr * gyr, gxl * gyr, gxr * gyl};
        u16x8 m;
        #pragma unroll
        for (int q = 0; q < 4; q++) {
            int qx = xs[q], qy = ys[q];
            bool valid = (qx >= 1 && qx <= H && qy >= 1 && qy <= W);
            m[q]     = valid ? (unsigned short)((qx - 1) * W + (qy - 1)) : (unsigned short)0;
            m[4 + q] = f2bf(valid ? gs[q] * mk : 0.f);
        }
        *reinterpret_cast<u16x8*>(&meta[n][p][0]) = m;
    }
    for (int idx = tid; idx < 2 * 64 * 3; idx += 512) {
        int bi = idx / 192;
        int r2 = idx - bi * 192;
        int row = r2 / 3, sg = r2 - (r2 / 3) * 3;
        u16x8 z = {0,0,0,0,0,0,0,0};
        *reinterpret_cast<u16x8*>(&sbuf[bi][row][72 + sg * 8]) = z;
    }
    __syncthreads();

    const unsigned short* xtb = xt + (size_t)b * HW * CIN;

    auto stage_w = [&](int ch, int bi) {
        #pragma unroll
        for (int pass = 0; pass < 2; pass++) {
            int idx = pass * 512 + tid;
            int row = idx >> 4, seg = idx & 15;
            if (seg < 12) {
                u16x8 v = *reinterpret_cast<const u16x8*>(
                    wtp + (size_t)row * (NCH * 96) + ch * 96 + seg * 8);
                *reinterpret_cast<u16x8*>(&wbuf[bi][row][seg * 8]) = v;
            }
        }
    };
    auto sample = [&](int ch, int bi) {
        for (int task = tid; task < 576; task += 512) {
            int p = task & 63, n = task >> 6;
            u16x8 m = *reinterpret_cast<const u16x8*>(&meta[n][p][0]);
            float vac[8];
            #pragma unroll
            for (int e = 0; e < 8; e++) vac[e] = 0.f;
            #pragma unroll
            for (int q = 0; q < 4; q++) {
                const unsigned short* sp = xtb + (size_t)m[q] * CIN + ch * 8;
                u16x8 v = *reinterpret_cast<const u16x8*>(sp);
                float wq = bf2f(m[4 + q]);
                const unsigned* vd = reinterpret_cast<const unsigned*>(&v);
                #pragma unroll
                for (int d = 0; d < 4; d++) {
                    vac[2 * d]     = fmaf(bflo(vd[d]), wq, vac[2 * d]);
                    vac[2 * d + 1] = fmaf(bfhi(vd[d]), wq, vac[2 * d + 1]);
                }
            }
            u16x8 o;
            #pragma unroll
            for (int e = 0; e < 8; e++) o[e] = f2bf(vac[e]);
            *reinterpret_cast<u16x8*>(&sbuf[bi][p][n * 8]) = o;
        }
    };

    stage_w(0, 0);
    sample(0, 0);
    __syncthreads();

    int lane = tid & 63, wv = tid >> 6;
    int ocq = wv & 1, pq = wv >> 1;
    int lr = lane & 15, lg = lane >> 4;
    int srow = pq * 16 + lr;
    int wrow = ocq * 32 + lr;

    f32x4 acc0 = {0.f, 0.f, 0.f, 0.f};
    f32x4 acc1 = {0.f, 0.f, 0.f, 0.f};

    for (int ch = 0; ch < NCH; ch++) {
        int cur = ch & 1;
        #pragma unroll
        for (int ks = 0; ks < 3; ks++) {
            bf16x8 bfr = *reinterpret_cast<const bf16x8*>(&sbuf[cur][srow][ks * 32 + lg * 8]);
            bf16x8 a0  = *reinterpret_cast<const bf16x8*>(&wbuf[cur][wrow][ks * 32 + lg * 8]);
            bf16x8 a1  = *reinterpret_cast<const bf16x8*>(&wbuf[cur][wrow + 16][ks * 32 + lg * 8]);
            acc0 = __builtin_amdgcn_mfma_f32_16x16x32_bf16(a0, bfr, acc0, 0, 0, 0);
            acc1 = __builtin_amdgcn_mfma_f32_16x16x32_bf16(a1, bfr, acc1, 0, 0, 0);
        }
        if (ch + 1 < NCH) {
            sample(ch + 1, cur ^ 1);
            stage_w(ch + 1, cur ^ 1);
        }
        __syncthreads();
    }

    int pixo = base + pq * 16 + lr;
    float* ob0 = out + ((size_t)b * 64 + ocq * 32 + lg * 4) * HW + pixo;
    #pragma unroll
    for (int r = 0; r < 4; r++) ob0[(size_t)r * HW] = acc0[r];
    float* ob1 = out + ((size_t)b * 64 + ocq * 32 + 16 + lg * 4) * HW + pixo;
    #pragma unroll
    for (int r = 0; r < 4; r++) ob1[(size_t)r * HW] = acc1[r];
}

// ---------------------------------------------------------------------------
// Group-norm statistics. One block per (b, group).
// ---------------------------------------------------------------------------
__global__ __launch_bounds__(256) void gn_stats(
    const float* __restrict__ buf, float* __restrict__ stats)
{
    int bg = blockIdx.x;
    const float4* v = reinterpret_cast<const float4*>(buf + (size_t)bg * 4 * HW);
    float sum = 0.f, ssq = 0.f;
    for (int idx = threadIdx.x; idx < 4 * HW / 4; idx += 256) {
        float4 x = v[idx];
        sum += x.x + x.y + x.z + x.w;
        ssq += x.x * x.x + x.y * x.y + x.z * x.z + x.w * x.w;
    }
    #pragma unroll
    for (int d = 32; d > 0; d >>= 1) {
        sum += __shfl_down(sum, d);
        ssq += __shfl_down(ssq, d);
    }
    __shared__ float ws1[4], ws2[4];
    int wid = threadIdx.x >> 6;
    if ((threadIdx.x & 63) == 0) { ws1[wid] = sum; ws2[wid] = ssq; }
    __syncthreads();
    if (threadIdx.x == 0) {
        float S = ws1[0] + ws1[1] + ws1[2] + ws1[3];
        float Q = ws2[0] + ws2[1] + ws2[2] + ws2[3];
        float mean = S * (1.0f / (4.0f * HW));
        float var  = Q * (1.0f / (4.0f * HW)) - mean * mean;
        stats[bg]      = mean;
        stats[32 + bg] = rsqrtf(var + 1e-5f);
    }
}

// ---------------------------------------------------------------------------
// GN(+relu) on the fly -> channel mean & max maps only.
// ---------------------------------------------------------------------------
__global__ __launch_bounds__(256) void gn_meanmax(
    const float* __restrict__ dc, const float* __restrict__ stats,
    const float* __restrict__ gamma, const float* __restrict__ beta,
    float* __restrict__ cm, float* __restrict__ cx)
{
    int t = blockIdx.x * 256 + threadIdx.x;
    if (t >= BATCH * HW) return;
    int b = t >> 14;
    int pix = t & (HW - 1);
    float msum = 0.f, mmax = -INFINITY;
    #pragma unroll 8
    for (int c = 0; c < 64; c++) {
        int g = c >> 2;
        float mean = stats[b * 16 + g];
        float rstd = stats[32 + b * 16 + g];
        size_t idx = ((size_t)b * 64 + c) * HW + pix;
        float v = (dc[idx] - mean) * rstd * gamma[c] + beta[c];
        v = fmaxf(v, 0.f);
        msum += v;
        mmax = fmaxf(mmax, v);
    }
    cm[t] = msum * (1.0f / 64.0f);
    cx[t] = mmax;
}

// ---------------------------------------------------------------------------
// 1-ch 3x3 convs over cm/cx + sigmoid -> av, mv maps.
// ---------------------------------------------------------------------------
__global__ __launch_bounds__(256) void attn_sig(
    const float* __restrict__ cm, const float* __restrict__ cx,
    const float* __restrict__ wa, const float* __restrict__ ba,
    const float* __restrict__ wb, const float* __restrict__ bb,
    float* __restrict__ avb, float* __restrict__ mvb)
{
    int t = blockIdx.x * 256 + threadIdx.x;
    if (t >= BATCH * HW) return;
    int b = t >> 14;
    int pix = t & (HW - 1);
    int i = pix >> 7, j = pix & (W - 1);
    float sa = ba[0], sb = bb[0];
    #pragma unroll
    for (int di = 0; di < 3; di++) {
        int ii = i + di - 1;
        if (ii < 0 || ii >= H) continue;
        #pragma unroll
        for (int dj = 0; dj < 3; dj++) {
            int jj = j + dj - 1;
            if (jj < 0 || jj >= W) continue;
            int q = (b << 14) + (ii << 7) + jj;
            sa = fmaf(cm[q], wa[di * 3 + dj], sa);
            sb = fmaf(cx[q], wb[di * 3 + dj], sb);
        }
    }
    avb[t] = sigmoidf_(sa);
    mvb[t] = sigmoidf_(sb);
}

// ---------------------------------------------------------------------------
// Fused GN+relu + attention-scale + concat + transpose -> bf16 catt
// ---------------------------------------------------------------------------
__global__ __launch_bounds__(256) void attn_cat_t(
    const float* __restrict__ dc, const float* __restrict__ stats,
    const float* __restrict__ gamma, const float* __restrict__ beta,
    const float* __restrict__ avb, const float* __restrict__ mvb,
    unsigned short* __restrict__ catt)
{
    __shared__ float tile[64][65];
    __shared__ float avs[64], mvs[64];
    int blk = blockIdx.x;               // 512
    int b  = blk >> 8;
    int p0 = (blk & 255) * 64;
    int tr = threadIdx.x >> 6;
    int tc = threadIdx.x & 63;
    if (threadIdx.x < 64)       avs[threadIdx.x] = avb[(size_t)b * HW + p0 + threadIdx.x];
    else if (threadIdx.x < 128) mvs[threadIdx.x - 64] = mvb[(size_t)b * HW + p0 + threadIdx.x - 64];
    #pragma unroll
    for (int r = 0; r < 16; r++) {
        int c = r * 4 + tr;
        float mean = stats[b * 16 + (c >> 2)];
        float rstd = stats[32 + b * 16 + (c >> 2)];
        float v = dc[((size_t)b * 64 + c) * HW + p0 + tc];
        tile[c][tc] = fmaxf((v - mean) * rstd * gamma[c] + beta[c], 0.f);
    }
    __syncthreads();
    #pragma unroll
    for (int r = 0; r < 16; r++) {
        int p = r * 4 + tr;
        float v = tile[tc][p];
        unsigned short* cr = catt + ((size_t)b * HW + p0 + p) * 128;
        cr[tc]      = f2bf(avs[p] * v);
        cr[64 + tc] = f2bf(mvs[p] * v);
    }
}

// ---------------------------------------------------------------------------
// Final GN + relu -> d_out
// ---------------------------------------------------------------------------
__global__ __launch_bounds__(256) void gn_final(
    const float* __restrict__ dc, const float* __restrict__ stats,
    const float* __restrict__ gamma, const float* __restrict__ beta,
    float* __restrict__ out)
{
    int t = blockIdx.x * 256 + threadIdx.x;
    if (t >= BATCH * 64 * HW) return;
    int c = (t >> 14) & 63;
    int b = t >> 20;
    int g = c >> 2;
    float mean = stats[b * 16 + g];
    float rstd = stats[32 + b * 16 + g];
    float v = (dc[t] - mean) * rstd * gamma[c] + beta[c];
    out[t] = fmaxf(v, 0.f);
}

// ---------------------------------------------------------------------------
extern "C" void kernel_launch(void* const* d_in, const int* in_sizes, int n_in,
                              void* d_out, int out_size, void* d_ws, size_t ws_size,
                              hipStream_t stream) {
    (void)in_sizes; (void)n_in; (void)out_size; (void)ws_size;
    const float* x   = (const float*)d_in[0];
    const float* wp1 = (const float*)d_in[1];
    const float* bp1 = (const float*)d_in[2];
    const float* wm1 = (const float*)d_in[3];
    const float* bm1 = (const float*)d_in[4];
    const float* wc1 = (const float*)d_in[5];
    const float* g1  = (const float*)d_in[6];
    const float* be1 = (const float*)d_in[7];
    const float* wa  = (const float*)d_in[8];
    const float* ba  = (const float*)d_in[9];
    const float* wb  = (const float*)d_in[10];
    const float* bb  = (const float*)d_in[11];
    const float* wp2 = (const float*)d_in[12];
    const float* bp2 = (const float*)d_in[13];
    const float* wm2 = (const float*)d_in[14];
    const float* bm2 = (const float*)d_in[15];
    const float* wc2 = (const float*)d_in[16];
    const float* g2  = (const float*)d_in[17];
    const float* be2 = (const float*)d_in[18];
    float* out = (float*)d_out;

    // ---- workspace layout ----
    float* ws   = (float*)d_ws;
    float* offb = ws;                              //  884736 f
    float* dcb  = offb + 2 * 27 * HW;              // 2097152 f
    float* cmb  = dcb + 2 * 64 * HW;               //   32768 f
    float* cxb  = cmb + 2 * HW;                    //   32768 f
    float* avb  = cxb + 2 * HW;                    //   32768 f
    float* mvb  = avb + 2 * HW;                    //   32768 f
    unsigned short* catt = (unsigned short*)(mvb + 2 * HW);  // 2*HW*128 u16
    float* stb  = (float*)(catt + (size_t)2 * 128 * HW);     //      64 f
    unsigned short* wtp1 = (unsigned short*)(stb + 64);      // 64*8*96
    unsigned short* wtp2 = wtp1 + 64 * 8 * 96;               // 64*16*96
    unsigned short* wop1 = wtp2 + 64 * 16 * 96;              // 32*8*96
    unsigned short* wop2 = wop1 + 32 * 8 * 96;               // 32*16*96
    // x transposed [B][HW][64] bf16 in d_out scratch (rewritten by gn_final)
    unsigned short* xt1 = (unsigned short*)out;

    const int NPIXB = (BATCH * HW + 255) / 256;      // 128
    const int NDEF  = BATCH * HW / 64;               // 512

    transpose_x64<<<512, 256, 0, stream>>>(x, xt1);
    transpose_wpad<64><<<(64 * 8 * 96 + 255) / 256, 256, 0, stream>>>(wc1, wtp1);
    transpose_wpad<128><<<(64 * 16 * 96 + 255) / 256, 256, 0, stream>>>(wc2, wtp2);
    transpose_woffp<64><<<(32 * 8 * 96 + 255) / 256, 256, 0, stream>>>(wp1, wm1, wop1);
    transpose_woffp<128><<<(32 * 16 * 96 + 255) / 256, 256, 0, stream>>>(wp2, wm2, wop2);

    // ---- stage 1 ----
    conv_off_mfma<64><<<NDEF, 512, 0, stream>>>(xt1, wop1, bp1, bm1, offb);
    deform_mfma<64><<<NDEF, 512, 0, stream>>>(xt1, offb, wtp1, dcb);
    gn_stats<<<32, 256, 0, stream>>>(dcb, stb);
    gn_meanmax<<<NPIXB, 256, 0, stream>>>(dcb, stb, g1, be1, cmb, cxb);
    attn_sig<<<NPIXB, 256, 0, stream>>>(cmb, cxb, wa, ba, wb, bb, avb, mvb);
    attn_cat_t<<<512, 256, 0, stream>>>(dcb, stb, g1, be1, avb, mvb, catt);

    // ---- stage 2 ----
    conv_off_mfma<128><<<NDEF, 512, 0, stream>>>(catt, wop2, bp2, bm2, offb);
    deform_mfma<128><<<NDEF, 512, 0, stream>>>(catt, offb, wtp2, dcb);
    gn_stats<<<32, 256, 0, stream>>>(dcb, stb);
    gn_final<<<(BATCH * 64 * HW + 255) / 256, 256, 0, stream>>>(dcb, stb, g2, be2, out);
}

// Round 10
// 177.412 us; speedup vs baseline: 2.4218x; 1.0277x over previous
//
#include <hip/hip_runtime.h>
#include <hip/hip_bf16.h>
#include <math.h>

#define H 128
#define W 128
#define HW (H*W)
#define BATCH 2

typedef __attribute__((ext_vector_type(8))) short          bf16x8;
typedef __attribute__((ext_vector_type(4))) float          f32x4;
typedef __attribute__((ext_vector_type(8))) unsigned short u16x8;

__device__ __forceinline__ float sigmoidf_(float x){ return 1.0f/(1.0f + expf(-x)); }

__device__ __forceinline__ unsigned short f2bf(float f) {
    __hip_bfloat16 h = __float2bfloat16(f);          // RTNE
    return __builtin_bit_cast(unsigned short, h);
}
__device__ __forceinline__ float bf2f(unsigned short b) {
    return __uint_as_float(((unsigned)b) << 16);
}
__device__ __forceinline__ float bflo(unsigned u){ return __uint_as_float(u << 16); }
__device__ __forceinline__ float bfhi(unsigned u){ return __uint_as_float(u & 0xFFFF0000u); }

// ---------------------------------------------------------------------------
// Transpose x [B][64][HW] fp32 -> xt [B][HW][64] bf16
// ---------------------------------------------------------------------------
__global__ __launch_bounds__(256) void transpose_x64(
    const float* __restrict__ x, unsigned short* __restrict__ xt)
{
    __shared__ float tile[64][65];
    int blk = blockIdx.x;               // 512 = 2 b * 256 pix-tiles
    int b  = blk >> 8;
    int p0 = (blk & 255) * 64;
    int tr = threadIdx.x >> 6;
    int tc = threadIdx.x & 63;
    #pragma unroll
    for (int r = 0; r < 16; r++) {
        int c = r * 4 + tr;
        tile[c][tc] = x[((size_t)b * 64 + c) * HW + p0 + tc];
    }
    __syncthreads();
    #pragma unroll
    for (int r = 0; r < 16; r++) {
        int p = r * 4 + tr;
        xt[((size_t)b * HW + p0 + p) * 64 + tc] = f2bf(tile[tc][p]);
    }
}

// ---------------------------------------------------------------------------
// Deform-conv weights: wc [64][CIN][9] fp32 -> wtp [64][NCH*96] bf16,
// k' = ch*96 + n*8 + cl  (n 0..8 real, 9..11 zero-pad)
// ---------------------------------------------------------------------------
template<int CIN>
__global__ __launch_bounds__(256) void transpose_wpad(
    const float* __restrict__ wc, unsigned short* __restrict__ wtp)
{
    constexpr int NCH = CIN / 8;
    int t = blockIdx.x * 256 + threadIdx.x;
    if (t >= 64 * NCH * 96) return;
    int oc = t / (NCH * 96);
    int r  = t - oc * (NCH * 96);
    int ch = r / 96;
    int q  = r - ch * 96;
    int n  = q >> 3, cl = q & 7;
    float v = (n < 9) ? wc[((size_t)oc * CIN + ch * 8 + cl) * 9 + n] : 0.f;
    wtp[t] = f2bf(v);
}

// ---------------------------------------------------------------------------
// Offset/mask conv weights -> MFMA layout: wop [32][NCH*96] bf16
// row oc: 0..17 = wp, 18..26 = wm, 27..31 = zero.  k' = ch*96 + n*8 + cl.
// ---------------------------------------------------------------------------
template<int CIN>
__global__ __launch_bounds__(256) void transpose_woffp(
    const float* __restrict__ wp, const float* __restrict__ wm,
    unsigned short* __restrict__ wop)
{
    constexpr int NCH = CIN / 8;
    int t = blockIdx.x * 256 + threadIdx.x;
    if (t >= 32 * NCH * 96) return;
    int oc = t / (NCH * 96);
    int r  = t - oc * (NCH * 96);
    int ch = r / 96;
    int q  = r - ch * 96;
    int n  = q >> 3, cl = q & 7;
    int c  = ch * 8 + cl;
    float v = 0.f;
    if (n < 9) {
        if (oc < 18)      v = wp[((size_t)oc * CIN + c) * 9 + n];
        else if (oc < 27) v = wm[((size_t)(oc - 18) * CIN + c) * 9 + n];
    }
    wop[t] = f2bf(v);
}

// ---------------------------------------------------------------------------
// Offset/mask 3x3 conv via MFMA: off[27 (pad 32)][pix] = Wop x im2col(xt).
// Block: 64 pix x 32 oc, 512 threads. LDS 39.9 KB -> 4 blocks/CU with
// __launch_bounds__(512,8) (VGPR <= 64).
// ---------------------------------------------------------------------------
template<int CIN>
__global__ __launch_bounds__(512, 8) void conv_off_mfma(
    const unsigned short* __restrict__ xt,  // [B][HW][CIN] bf16
    const unsigned short* __restrict__ wop, // [32][NCH*96] bf16
    const float* __restrict__ bp,           // [18]
    const float* __restrict__ bm,           // [9]
    float* __restrict__ offb)               // [B][27][HW]
{
    constexpr int NCH  = CIN / 8;
    constexpr int SROW = 104;
    __shared__ __align__(16) unsigned short sbuf[2][64][SROW];
    __shared__ __align__(16) unsigned short wbuf[2][32][SROW];

    int tid  = threadIdx.x;
    int pix0 = blockIdx.x * 64;
    int b    = pix0 >> 14;
    int base = pix0 & (HW - 1);
    int i    = base >> 7;
    int j0   = base & 127;

    // ---- per-thread sampling tasks (1 or 2), meta in registers (int) ----
    int p0t = tid & 63, n0t = tid >> 6;
    int ii0 = i + n0t / 3 - 1, jj0 = j0 + p0t + n0t % 3 - 1;
    bool v0 = (ii0 >= 0 && ii0 < H && jj0 >= 0 && jj0 < W);
    int off0 = v0 ? (ii0 * W + jj0) * CIN : 0;
    bool t1 = (tid < 64);
    int ii1 = i + 1, jj1 = j0 + tid + 1;               // n=8 -> di=2,dj=2
    bool v1 = t1 && (ii1 >= 0 && ii1 < H && jj1 >= 0 && jj1 < W);
    int off1 = v1 ? (ii1 * W + jj1) * CIN : 0;

    // zero pad k-slots (72..95) of both sample buffers
    if (tid < 384) {
        int bi = tid >= 192;
        int r2 = tid - bi * 192;
        int row = r2 / 3, sg = r2 - (r2 / 3) * 3;
        u16x8 z = {0,0,0,0,0,0,0,0};
        *reinterpret_cast<u16x8*>(&sbuf[bi][row][72 + sg * 8]) = z;
    }

    const unsigned short* xtb = xt + (size_t)b * HW * CIN;
    const u16x8 zero8 = {0,0,0,0,0,0,0,0};

    auto sample = [&](int ch, int bi) {
        u16x8 v = v0 ? *reinterpret_cast<const u16x8*>(xtb + off0 + ch * 8) : zero8;
        *reinterpret_cast<u16x8*>(&sbuf[bi][p0t][n0t * 8]) = v;
        if (t1) {
            u16x8 w = v1 ? *reinterpret_cast<const u16x8*>(xtb + off1 + ch * 8) : zero8;
            *reinterpret_cast<u16x8*>(&sbuf[bi][tid][64]) = w;
        }
    };
    // weight tile: 32 rows x 16 segs = 512 slots -> all 512 threads
    auto stage_w = [&](int ch, int bi) {
        int row = tid >> 4, seg = tid & 15;
        if (seg < 12) {
            u16x8 v = *reinterpret_cast<const u16x8*>(
                wop + (size_t)row * (NCH * 96) + ch * 96 + seg * 8);
            *reinterpret_cast<u16x8*>(&wbuf[bi][row][seg * 8]) = v;
        }
    };

    stage_w(0, 0);
    sample(0, 0);
    __syncthreads();

    int lane = tid & 63, wv = tid >> 6;
    int mt = wv & 1, nt = wv >> 1;          // oc-half, pix-quarter
    int lr = lane & 15, lg = lane >> 4;
    int srow = nt * 16 + lr;
    int wrow = mt * 16 + lr;

    f32x4 acc = {0.f, 0.f, 0.f, 0.f};

    for (int ch = 0; ch < NCH; ch++) {
        int cur = ch & 1;
        #pragma unroll
        for (int ks = 0; ks < 3; ks++) {
            bf16x8 bfr = *reinterpret_cast<const bf16x8*>(&sbuf[cur][srow][ks * 32 + lg * 8]);
            bf16x8 a   = *reinterpret_cast<const bf16x8*>(&wbuf[cur][wrow][ks * 32 + lg * 8]);
            acc = __builtin_amdgcn_mfma_f32_16x16x32_bf16(a, bfr, acc, 0, 0, 0);
        }
        if (ch + 1 < NCH) {
            sample(ch + 1, cur ^ 1);
            stage_w(ch + 1, cur ^ 1);
        }
        __syncthreads();
    }

    // epilogue: D col = lane&15 (pixel), row = lg*4 + r (oc within half)
    int pixo = base + nt * 16 + lr;
    #pragma unroll
    for (int r = 0; r < 4; r++) {
        int oc = mt * 16 + lg * 4 + r;
        if (oc < 27) {
            float v = acc[r];
            v = (oc < 18) ? (v + bp[oc]) : sigmoidf_(v + bm[oc - 18]);
            offb[((size_t)b * 27 + oc) * HW + pixo] = v;
        }
    }
}

// ---------------------------------------------------------------------------
// Deformable sampling + main conv via MFMA (bf16 in, fp32 accum).
// R8 structure, but bilinear meta in REGISTERS (task map is static:
// thread -> (p=tid&63, n=tid>>6), tid<64 also handles n=8). Removes the
// 9.2 KB meta LDS -> 52 KB total -> 3 blocks/CU (launch_bounds(512,6)).
// Meta arithmetic identical to R8 (weights pre-rounded to bf16).
// ---------------------------------------------------------------------------
template<int CIN>
__global__ __launch_bounds__(512, 6) void deform_mfma(
    const unsigned short* __restrict__ xt,  // [B][HW][CIN] bf16
    const float* __restrict__ off,          // [B][27][HW]
    const unsigned short* __restrict__ wtp, // [64][NCH*96] bf16
    float* __restrict__ out)                // [B][64][HW]
{
    constexpr int NCH  = CIN / 8;
    constexpr int SROW = 104;
    __shared__ __align__(16) unsigned short sbuf[2][64][SROW];
    __shared__ __align__(16) unsigned short wbuf[2][64][SROW];

    int tid  = threadIdx.x;
    int pix0 = blockIdx.x * 64;
    int b    = pix0 >> 14;
    int base = pix0 & (HW - 1);
    int i    = base >> 7;
    int j0   = base & 127;

    // ---- bilinear meta in registers: mi = element offset (pix*CIN),
    //      mw = 4 bf16 sampling weights packed into 2 uints -----------------
    auto comp_meta = [&](int pp, int nn, int* mi, unsigned* mwp) {
        int j = j0 + pp;
        const float* ob = off + (size_t)b * 27 * HW + (i << 7) + j;
        float px = ob[(size_t)nn * HW]       + (float)(nn / 3 - 1) + (float)(i + 1);
        float py = ob[(size_t)(9 + nn) * HW] + (float)(nn % 3 - 1) + (float)(j + 1);
        float mk = ob[(size_t)(18 + nn) * HW];
        float fx = floorf(px), fy = floorf(py);
        const float lim = 129.0f;            // Hp-1 = Wp-1
        int qltx = (int)fminf(fmaxf(fx, 0.f), lim);
        int qlty = (int)fminf(fmaxf(fy, 0.f), lim);
        int qrbx = (int)fminf(fmaxf(fx + 1.f, 0.f), lim);
        int qrby = (int)fminf(fmaxf(fy + 1.f, 0.f), lim);
        float pxc = fminf(fmaxf(px, 0.f), lim);
        float pyc = fminf(fmaxf(py, 0.f), lim);
        float gxl = 1.f + ((float)qltx - pxc);
        float gxr = 1.f - ((float)qrbx - pxc);
        float gyl = 1.f + ((float)qlty - pyc);
        float gyr = 1.f - ((float)qrby - pyc);
        int   xs[4] = {qltx, qrbx, qltx, qrbx};
        int   ys[4] = {qlty, qrby, qrby, qlty};
        float gs[4] = {gxl * gyl, gxr * gyr, gxl * gyr, gxr * gyl};
        unsigned short wbits[4];
        #pragma unroll
        for (int q = 0; q < 4; q++) {
            int qx = xs[q], qy = ys[q];
            bool valid = (qx >= 1 && qx <= H && qy >= 1 && qy <= W);
            mi[q]    = (valid ? ((qx - 1) * W + (qy - 1)) : 0) * CIN;
            wbits[q] = f2bf(valid ? gs[q] * mk : 0.f);
        }
        mwp[0] = (unsigned)wbits[0] | ((unsigned)wbits[1] << 16);
        mwp[1] = (unsigned)wbits[2] | ((unsigned)wbits[3] << 16);
    };

    int p  = tid & 63;
    int n0 = tid >> 6;
    int mi0[4]; unsigned mw0[2];
    comp_meta(p, n0, mi0, mw0);
    bool t8 = (tid < 64);
    int mi8[4]; unsigned mw8[2];
    if (t8) comp_meta(tid, 8, mi8, mw8);

    // zero pad k-slots (72..95) of both sample buffers
    if (tid < 384) {
        int bi = tid >= 192;
        int r2 = tid - bi * 192;
        int row = r2 / 3, sg = r2 - (r2 / 3) * 3;
        u16x8 z = {0,0,0,0,0,0,0,0};
        *reinterpret_cast<u16x8*>(&sbuf[bi][row][72 + sg * 8]) = z;
    }

    const unsigned short* xtb = xt + (size_t)b * HW * CIN;

    auto stage_w = [&](int ch, int bi) {
        #pragma unroll
        for (int pass = 0; pass < 2; pass++) {
            int idx = pass * 512 + tid;
            int row = idx >> 4, seg = idx & 15;
            if (seg < 12) {
                u16x8 v = *reinterpret_cast<const u16x8*>(
                    wtp + (size_t)row * (NCH * 96) + ch * 96 + seg * 8);
                *reinterpret_cast<u16x8*>(&wbuf[bi][row][seg * 8]) = v;
            }
        }
    };
    auto gather1 = [&](int ch, const int* mi, const unsigned* mwp,
                       unsigned short* dst) {
        float vac[8];
        #pragma unroll
        for (int e = 0; e < 8; e++) vac[e] = 0.f;
        #pragma unroll
        for (int q = 0; q < 4; q++) {
            const unsigned short* sp = xtb + mi[q] + ch * 8;
            u16x8 v = *reinterpret_cast<const u16x8*>(sp);
            float wq = (q & 1) ? bfhi(mwp[q >> 1]) : bflo(mwp[q >> 1]);
            const unsigned* vd = reinterpret_cast<const unsigned*>(&v);
            #pragma unroll
            for (int d = 0; d < 4; d++) {
                vac[2 * d]     = fmaf(bflo(vd[d]), wq, vac[2 * d]);
                vac[2 * d + 1] = fmaf(bfhi(vd[d]), wq, vac[2 * d + 1]);
            }
        }
        u16x8 o;
        #pragma unroll
        for (int e = 0; e < 8; e++) o[e] = f2bf(vac[e]);
        *reinterpret_cast<u16x8*>(dst) = o;
    };
    auto sample = [&](int ch, int bi) {
        gather1(ch, mi0, mw0, &sbuf[bi][p][n0 * 8]);
        if (t8) gather1(ch, mi8, mw8, &sbuf[bi][p][64]);
    };

    stage_w(0, 0);
    sample(0, 0);
    __syncthreads();

    int lane = tid & 63, wv = tid >> 6;
    int ocq = wv & 1, pq = wv >> 1;
    int lr = lane & 15, lg = lane >> 4;
    int srow = pq * 16 + lr;
    int wrow = ocq * 32 + lr;

    f32x4 acc0 = {0.f, 0.f, 0.f, 0.f};
    f32x4 acc1 = {0.f, 0.f, 0.f, 0.f};

    for (int ch = 0; ch < NCH; ch++) {
        int cur = ch & 1;
        #pragma unroll
        for (int ks = 0; ks < 3; ks++) {
            bf16x8 bfr = *reinterpret_cast<const bf16x8*>(&sbuf[cur][srow][ks * 32 + lg * 8]);
            bf16x8 a0  = *reinterpret_cast<const bf16x8*>(&wbuf[cur][wrow][ks * 32 + lg * 8]);
            bf16x8 a1  = *reinterpret_cast<const bf16x8*>(&wbuf[cur][wrow + 16][ks * 32 + lg * 8]);
            acc0 = __builtin_amdgcn_mfma_f32_16x16x32_bf16(a0, bfr, acc0, 0, 0, 0);
            acc1 = __builtin_amdgcn_mfma_f32_16x16x32_bf16(a1, bfr, acc1, 0, 0, 0);
        }
        if (ch + 1 < NCH) {
            sample(ch + 1, cur ^ 1);
            stage_w(ch + 1, cur ^ 1);
        }
        __syncthreads();
    }

    int pixo = base + pq * 16 + lr;
    float* ob0 = out + ((size_t)b * 64 + ocq * 32 + lg * 4) * HW + pixo;
    #pragma unroll
    for (int r = 0; r < 4; r++) ob0[(size_t)r * HW] = acc0[r];
    float* ob1 = out + ((size_t)b * 64 + ocq * 32 + 16 + lg * 4) * HW + pixo;
    #pragma unroll
    for (int r = 0; r < 4; r++) ob1[(size_t)r * HW] = acc1[r];
}

// ---------------------------------------------------------------------------
// Group-norm statistics. One block per (b, group).
// ---------------------------------------------------------------------------
__global__ __launch_bounds__(256) void gn_stats(
    const float* __restrict__ buf, float* __restrict__ stats)
{
    int bg = blockIdx.x;
    const float4* v = reinterpret_cast<const float4*>(buf + (size_t)bg * 4 * HW);
    float sum = 0.f, ssq = 0.f;
    for (int idx = threadIdx.x; idx < 4 * HW / 4; idx += 256) {
        float4 x = v[idx];
        sum += x.x + x.y + x.z + x.w;
        ssq += x.x * x.x + x.y * x.y + x.z * x.z + x.w * x.w;
    }
    #pragma unroll
    for (int d = 32; d > 0; d >>= 1) {
        sum += __shfl_down(sum, d);
        ssq += __shfl_down(ssq, d);
    }
    __shared__ float ws1[4], ws2[4];
    int wid = threadIdx.x >> 6;
    if ((threadIdx.x & 63) == 0) { ws1[wid] = sum; ws2[wid] = ssq; }
    __syncthreads();
    if (threadIdx.x == 0) {
        float S = ws1[0] + ws1[1] + ws1[2] + ws1[3];
        float Q = ws2[0] + ws2[1] + ws2[2] + ws2[3];
        float mean = S * (1.0f / (4.0f * HW));
        float var  = Q * (1.0f / (4.0f * HW)) - mean * mean;
        stats[bg]      = mean;
        stats[32 + bg] = rsqrtf(var + 1e-5f);
    }
}

// ---------------------------------------------------------------------------
// GN(+relu) on the fly -> channel mean & max maps only.
// ---------------------------------------------------------------------------
__global__ __launch_bounds__(256) void gn_meanmax(
    const float* __restrict__ dc, const float* __restrict__ stats,
    const float* __restrict__ gamma, const float* __restrict__ beta,
    float* __restrict__ cm, float* __restrict__ cx)
{
    int t = blockIdx.x * 256 + threadIdx.x;
    if (t >= BATCH * HW) return;
    int b = t >> 14;
    int pix = t & (HW - 1);
    float msum = 0.f, mmax = -INFINITY;
    #pragma unroll 8
    for (int c = 0; c < 64; c++) {
        int g = c >> 2;
        float mean = stats[b * 16 + g];
        float rstd = stats[32 + b * 16 + g];
        size_t idx = ((size_t)b * 64 + c) * HW + pix;
        float v = (dc[idx] - mean) * rstd * gamma[c] + beta[c];
        v = fmaxf(v, 0.f);
        msum += v;
        mmax = fmaxf(mmax, v);
    }
    cm[t] = msum * (1.0f / 64.0f);
    cx[t] = mmax;
}

// ---------------------------------------------------------------------------
// 1-ch 3x3 convs over cm/cx + sigmoid -> av, mv maps.
// ---------------------------------------------------------------------------
__global__ __launch_bounds__(256) void attn_sig(
    const float* __restrict__ cm, const float* __restrict__ cx,
    const float* __restrict__ wa, const float* __restrict__ ba,
    const float* __restrict__ wb, const float* __restrict__ bb,
    float* __restrict__ avb, float* __restrict__ mvb)
{
    int t = blockIdx.x * 256 + threadIdx.x;
    if (t >= BATCH * HW) return;
    int b = t >> 14;
    int pix = t & (HW - 1);
    int i = pix >> 7, j = pix & (W - 1);
    float sa = ba[0], sb = bb[0];
    #pragma unroll
    for (int di = 0; di < 3; di++) {
        int ii = i + di - 1;
        if (ii < 0 || ii >= H) continue;
        #pragma unroll
        for (int dj = 0; dj < 3; dj++) {
            int jj = j + dj - 1;
            if (jj < 0 || jj >= W) continue;
            int q = (b << 14) + (ii << 7) + jj;
            sa = fmaf(cm[q], wa[di * 3 + dj], sa);
            sb = fmaf(cx[q], wb[di * 3 + dj], sb);
        }
    }
    avb[t] = sigmoidf_(sa);
    mvb[t] = sigmoidf_(sb);
}

// ---------------------------------------------------------------------------
// Fused GN+relu + attention-scale + concat + transpose -> bf16 catt
// ---------------------------------------------------------------------------
__global__ __launch_bounds__(256) void attn_cat_t(
    const float* __restrict__ dc, const float* __restrict__ stats,
    const float* __restrict__ gamma, const float* __restrict__ beta,
    const float* __restrict__ avb, const float* __restrict__ mvb,
    unsigned short* __restrict__ catt)
{
    __shared__ float tile[64][65];
    __shared__ float avs[64], mvs[64];
    int blk = blockIdx.x;               // 512
    int b  = blk >> 8;
    int p0 = (blk & 255) * 64;
    int tr = threadIdx.x >> 6;
    int tc = threadIdx.x & 63;
    if (threadIdx.x < 64)       avs[threadIdx.x] = avb[(size_t)b * HW + p0 + threadIdx.x];
    else if (threadIdx.x < 128) mvs[threadIdx.x - 64] = mvb[(size_t)b * HW + p0 + threadIdx.x - 64];
    #pragma unroll
    for (int r = 0; r < 16; r++) {
        int c = r * 4 + tr;
        float mean = stats[b * 16 + (c >> 2)];
        float rstd = stats[32 + b * 16 + (c >> 2)];
        float v = dc[((size_t)b * 64 + c) * HW + p0 + tc];
        tile[c][tc] = fmaxf((v - mean) * rstd * gamma[c] + beta[c], 0.f);
    }
    __syncthreads();
    #pragma unroll
    for (int r = 0; r < 16; r++) {
        int p = r * 4 + tr;
        float v = tile[tc][p];
        unsigned short* cr = catt + ((size_t)b * HW + p0 + p) * 128;
        cr[tc]      = f2bf(avs[p] * v);
        cr[64 + tc] = f2bf(mvs[p] * v);
    }
}

// ---------------------------------------------------------------------------
// Final GN + relu -> d_out
// ---------------------------------------------------------------------------
__global__ __launch_bounds__(256) void gn_final(
    const float* __restrict__ dc, const float* __restrict__ stats,
    const float* __restrict__ gamma, const float* __restrict__ beta,
    float* __restrict__ out)
{
    int t = blockIdx.x * 256 + threadIdx.x;
    if (t >= BATCH * 64 * HW) return;
    int c = (t >> 14) & 63;
    int b = t >> 20;
    int g = c >> 2;
    float mean = stats[b * 16 + g];
    float rstd = stats[32 + b * 16 + g];
    float v = (dc[t] - mean) * rstd * gamma[c] + beta[c];
    out[t] = fmaxf(v, 0.f);
}

// ---------------------------------------------------------------------------
extern "C" void kernel_launch(void* const* d_in, const int* in_sizes, int n_in,
                              void* d_out, int out_size, void* d_ws, size_t ws_size,
                              hipStream_t stream) {
    (void)in_sizes; (void)n_in; (void)out_size; (void)ws_size;
    const float* x   = (const float*)d_in[0];
    const float* wp1 = (const float*)d_in[1];
    const float* bp1 = (const float*)d_in[2];
    const float* wm1 = (const float*)d_in[3];
    const float* bm1 = (const float*)d_in[4];
    const float* wc1 = (const float*)d_in[5];
    const float* g1  = (const float*)d_in[6];
    const float* be1 = (const float*)d_in[7];
    const float* wa  = (const float*)d_in[8];
    const float* ba  = (const float*)d_in[9];
    const float* wb  = (const float*)d_in[10];
    const float* bb  = (const float*)d_in[11];
    const float* wp2 = (const float*)d_in[12];
    const float* bp2 = (const float*)d_in[13];
    const float* wm2 = (const float*)d_in[14];
    const float* bm2 = (const float*)d_in[15];
    const float* wc2 = (const float*)d_in[16];
    const float* g2  = (const float*)d_in[17];
    const float* be2 = (const float*)d_in[18];
    float* out = (float*)d_out;

    // ---- workspace layout ----
    float* ws   = (float*)d_ws;
    float* offb = ws;                              //  884736 f
    float* dcb  = offb + 2 * 27 * HW;              // 2097152 f
    float* cmb  = dcb + 2 * 64 * HW;               //   32768 f
    float* cxb  = cmb + 2 * HW;                    //   32768 f
    float* avb  = cxb + 2 * HW;                    //   32768 f
    float* mvb  = avb + 2 * HW;                    //   32768 f
    unsigned short* catt = (unsigned short*)(mvb + 2 * HW);  // 2*HW*128 u16
    float* stb  = (float*)(catt + (size_t)2 * 128 * HW);     //      64 f
    unsigned short* wtp1 = (unsigned short*)(stb + 64);      // 64*8*96
    unsigned short* wtp2 = wtp1 + 64 * 8 * 96;               // 64*16*96
    unsigned short* wop1 = wtp2 + 64 * 16 * 96;              // 32*8*96
    unsigned short* wop2 = wop1 + 32 * 8 * 96;               // 32*16*96
    // x transposed [B][HW][64] bf16 in d_out scratch (rewritten by gn_final)
    unsigned short* xt1 = (unsigned short*)out;

    const int NPIXB = (BATCH * HW + 255) / 256;      // 128
    const int NDEF  = BATCH * HW / 64;               // 512

    transpose_x64<<<512, 256, 0, stream>>>(x, xt1);
    transpose_wpad<64><<<(64 * 8 * 96 + 255) / 256, 256, 0, stream>>>(wc1, wtp1);
    transpose_wpad<128><<<(64 * 16 * 96 + 255) / 256, 256, 0, stream>>>(wc2, wtp2);
    transpose_woffp<64><<<(32 * 8 * 96 + 255) / 256, 256, 0, stream>>>(wp1, wm1, wop1);
    transpose_woffp<128><<<(32 * 16 * 96 + 255) / 256, 256, 0, stream>>>(wp2, wm2, wop2);

    // ---- stage 1 ----
    conv_off_mfma<64><<<NDEF, 512, 0, stream>>>(xt1, wop1, bp1, bm1, offb);
    deform_mfma<64><<<NDEF, 512, 0, stream>>>(xt1, offb, wtp1, dcb);
    gn_stats<<<32, 256, 0, stream>>>(dcb, stb);
    gn_meanmax<<<NPIXB, 256, 0, stream>>>(dcb, stb, g1, be1, cmb, cxb);
    attn_sig<<<NPIXB, 256, 0, stream>>>(cmb, cxb, wa, ba, wb, bb, avb, mvb);
    attn_cat_t<<<512, 256, 0, stream>>>(dcb, stb, g1, be1, avb, mvb, catt);

    // ---- stage 2 ----
    conv_off_mfma<128><<<NDEF, 512, 0, stream>>>(catt, wop2, bp2, bm2, offb);
    deform_mfma<128><<<NDEF, 512, 0, stream>>>(catt, offb, wtp2, dcb);
    gn_stats<<<32, 256, 0, stream>>>(dcb, stb);
    gn_final<<<(BATCH * 64 * HW + 255) / 256, 256, 0, stream>>>(dcb, stb, g2, be2, out);
}

// Round 11
// 137.079 us; speedup vs baseline: 3.1343x; 1.2942x over previous
//
#include <hip/hip_runtime.h>
#include <hip/hip_bf16.h>
#include <math.h>

#define H 128
#define W 128
#define HW (H*W)
#define BATCH 2

typedef __attribute__((ext_vector_type(8))) short          bf16x8;
typedef __attribute__((ext_vector_type(4))) float          f32x4;
typedef __attribute__((ext_vector_type(8))) unsigned short u16x8;

__device__ __forceinline__ float sigmoidf_(float x){ return 1.0f/(1.0f + expf(-x)); }

__device__ __forceinline__ unsigned short f2bf(float f) {
    __hip_bfloat16 h = __float2bfloat16(f);          // RTNE
    return __builtin_bit_cast(unsigned short, h);
}
__device__ __forceinline__ float bf2f(unsigned short b) {
    return __uint_as_float(((unsigned)b) << 16);
}
__device__ __forceinline__ float bflo(unsigned u){ return __uint_as_float(u << 16); }
__device__ __forceinline__ float bfhi(unsigned u){ return __uint_as_float(u & 0xFFFF0000u); }

// ---------------------------------------------------------------------------
// Transpose x [B][64][HW] fp32 -> xt [B][HW][64] bf16
// ---------------------------------------------------------------------------
__global__ __launch_bounds__(256) void transpose_x64(
    const float* __restrict__ x, unsigned short* __restrict__ xt)
{
    __shared__ float tile[64][65];
    int blk = blockIdx.x;               // 512 = 2 b * 256 pix-tiles
    int b  = blk >> 8;
    int p0 = (blk & 255) * 64;
    int tr = threadIdx.x >> 6;
    int tc = threadIdx.x & 63;
    #pragma unroll
    for (int r = 0; r < 16; r++) {
        int c = r * 4 + tr;
        tile[c][tc] = x[((size_t)b * 64 + c) * HW + p0 + tc];
    }
    __syncthreads();
    #pragma unroll
    for (int r = 0; r < 16; r++) {
        int p = r * 4 + tr;
        xt[((size_t)b * HW + p0 + p) * 64 + tc] = f2bf(tile[tc][p]);
    }
}

// ---------------------------------------------------------------------------
// Deform-conv weights, TAP-MAJOR: wtp[oc][n*CIN + c] = wc[oc][c][n]  (bf16)
// ---------------------------------------------------------------------------
template<int CIN>
__global__ __launch_bounds__(256) void transpose_wtap(
    const float* __restrict__ wc, unsigned short* __restrict__ wtp)
{
    int t = blockIdx.x * 256 + threadIdx.x;
    if (t >= 64 * 9 * CIN) return;
    int oc = t / (9 * CIN);
    int r  = t - oc * (9 * CIN);
    int n  = r / CIN;
    int c  = r - n * CIN;
    wtp[t] = f2bf(wc[((size_t)oc * CIN + c) * 9 + n]);
}

// ---------------------------------------------------------------------------
// Offset/mask conv weights, TAP-MAJOR: wop[oc][n*CIN+c]; oc 0..17 = wp,
// 18..26 = wm, 27..31 = zero.
// ---------------------------------------------------------------------------
template<int CIN>
__global__ __launch_bounds__(256) void transpose_wofft(
    const float* __restrict__ wp, const float* __restrict__ wm,
    unsigned short* __restrict__ wop)
{
    int t = blockIdx.x * 256 + threadIdx.x;
    if (t >= 32 * 9 * CIN) return;
    int oc = t / (9 * CIN);
    int r  = t - oc * (9 * CIN);
    int n  = r / CIN;
    int c  = r - n * CIN;
    float v = 0.f;
    if (oc < 18)      v = wp[((size_t)oc * CIN + c) * 9 + n];
    else if (oc < 27) v = wm[((size_t)(oc - 18) * CIN + c) * 9 + n];
    wop[t] = f2bf(v);
}

// ---------------------------------------------------------------------------
// Offset/mask conv via MFMA, tap-major chunks (chunk = tap n, K-slice = CIN).
// Block: 64 pix x 32 oc, 512 threads. Sampling task = (pixel, 8ch segment):
// 16 (or 8) consecutive lanes read contiguous segments of the SAME shifted
// pixel -> ~8 cache lines per wave-load instead of 64.
// ---------------------------------------------------------------------------
template<int CIN>
__global__ __launch_bounds__(512, 6) void conv_off_mfma(
    const unsigned short* __restrict__ xt,  // [B][HW][CIN] bf16
    const unsigned short* __restrict__ wop, // [32][9*CIN] bf16 tap-major
    const float* __restrict__ bp,           // [18]
    const float* __restrict__ bm,           // [9]
    float* __restrict__ offb)               // [B][27][HW]
{
    constexpr int SEG   = CIN / 8;           // 8 or 16 segments/row
    constexpr int SROW  = CIN + 4;           // stride ≡ 2 dw mod 32: no conflicts
    constexpr int TASKS = (64 * SEG) / 512;  // 1 or 2 sample tasks/thread
    constexpr int SHIFT = (SEG == 16) ? 4 : 3;
    __shared__ __align__(16) unsigned short sbuf[2][64][SROW];
    __shared__ __align__(16) unsigned short wbuf[2][32][SROW];

    int tid  = threadIdx.x;
    int pix0 = blockIdx.x * 64;
    int b    = pix0 >> 14;
    int base = pix0 & (HW - 1);
    int i    = base >> 7;
    int j0   = base & 127;

    const unsigned short* xtb = xt + (size_t)b * HW * CIN;
    const u16x8 zero8 = {0,0,0,0,0,0,0,0};

    auto sample = [&](int n, int bi) {
        int di = n / 3 - 1, dj = n - (n / 3) * 3 - 1;
        int ii = i + di;
        bool rowok = (ii >= 0 && ii < H);
        #pragma unroll
        for (int t2 = 0; t2 < TASKS; t2++) {
            int T = t2 * 512 + tid;
            int p = T >> SHIFT, cl = T & (SEG - 1);
            int jj = j0 + p + dj;
            bool v = rowok && (jj >= 0 && jj < W);
            u16x8 val = v ? *reinterpret_cast<const u16x8*>(
                                xtb + (size_t)(ii * W + jj) * CIN + cl * 8)
                          : zero8;
            *reinterpret_cast<u16x8*>(&sbuf[bi][p][cl * 8]) = val;
        }
    };
    auto stage_w = [&](int n, int bi) {
        if (tid < 32 * SEG) {
            int row = tid >> SHIFT, seg = tid & (SEG - 1);
            u16x8 v = *reinterpret_cast<const u16x8*>(
                wop + (size_t)row * (9 * CIN) + n * CIN + seg * 8);
            *reinterpret_cast<u16x8*>(&wbuf[bi][row][seg * 8]) = v;
        }
    };

    sample(0, 0);
    stage_w(0, 0);
    __syncthreads();

    int lane = tid & 63, wv = tid >> 6;
    int mt = wv & 1, nt = wv >> 1;          // oc-half, pix-quarter
    int lr = lane & 15, lg = lane >> 4;
    int srow = nt * 16 + lr;
    int wrow = mt * 16 + lr;

    f32x4 acc = {0.f, 0.f, 0.f, 0.f};

    for (int n = 0; n < 9; n++) {
        int cur = n & 1;
        #pragma unroll
        for (int ks = 0; ks < CIN / 32; ks++) {
            bf16x8 bfr = *reinterpret_cast<const bf16x8*>(&sbuf[cur][srow][ks * 32 + lg * 8]);
            bf16x8 a   = *reinterpret_cast<const bf16x8*>(&wbuf[cur][wrow][ks * 32 + lg * 8]);
            acc = __builtin_amdgcn_mfma_f32_16x16x32_bf16(a, bfr, acc, 0, 0, 0);
        }
        if (n + 1 < 9) {
            sample(n + 1, cur ^ 1);
            stage_w(n + 1, cur ^ 1);
        }
        __syncthreads();
    }

    // epilogue: D col = lane&15 (pixel), row = lg*4 + r (oc within half)
    int pixo = base + nt * 16 + lr;
    #pragma unroll
    for (int r = 0; r < 4; r++) {
        int oc = mt * 16 + lg * 4 + r;
        if (oc < 27) {
            float v = acc[r];
            v = (oc < 18) ? (v + bp[oc]) : sigmoidf_(v + bm[oc - 18]);
            offb[((size_t)b * 27 + oc) * HW + pixo] = v;
        }
    }
}

// ---------------------------------------------------------------------------
// Deformable sampling + main conv via MFMA, tap-major chunks.
// Block: 64 pix x 64 oc, 512 threads. Chunk = tap n (K-slice = CIN channels).
// Sampling task = (pixel, segment): 16 (8) lanes share each pixel-neighbor's
// contiguous 256B (128B) -> 8x fewer L1 line-transactions per wave-load.
// Bilinear meta (4 idx + 4 bf16 wt per (tap,pixel)) in LDS, computed once.
// ---------------------------------------------------------------------------
template<int CIN>
__global__ __launch_bounds__(512, 6) void deform_mfma(
    const unsigned short* __restrict__ xt,  // [B][HW][CIN] bf16
    const float* __restrict__ off,          // [B][27][HW]
    const unsigned short* __restrict__ wtp, // [64][9*CIN] bf16 tap-major
    float* __restrict__ out)                // [B][64][HW]
{
    constexpr int SEG   = CIN / 8;
    constexpr int SROW  = CIN + 4;
    constexpr int TASKS = (64 * SEG) / 512;  // 1 or 2
    constexpr int SHIFT = (SEG == 16) ? 4 : 3;
    __shared__ __align__(16) unsigned short sbuf[2][64][SROW];
    __shared__ __align__(16) unsigned short wbuf[2][64][SROW];
    __shared__ __align__(16) unsigned short meta[9][64][8];

    int tid  = threadIdx.x;
    int pix0 = blockIdx.x * 64;
    int b    = pix0 >> 14;
    int base = pix0 & (HW - 1);
    int i    = base >> 7;
    int j0   = base & 127;

    // ---- bilinear metadata (once per block): 4x u16 pix-idx + 4x bf16 wt ---
    for (int task = tid; task < 576; task += 512) {
        int p = task & 63, n = task >> 6;
        int j = j0 + p;
        const float* ob = off + (size_t)b * 27 * HW + (i << 7) + j;
        float px = ob[(size_t)n * HW]       + (float)(n / 3 - 1) + (float)(i + 1);
        float py = ob[(size_t)(9 + n) * HW] + (float)(n % 3 - 1) + (float)(j + 1);
        float mk = ob[(size_t)(18 + n) * HW];
        float fx = floorf(px), fy = floorf(py);
        const float lim = 129.0f;            // Hp-1 = Wp-1
        int qltx = (int)fminf(fmaxf(fx, 0.f), lim);
        int qlty = (int)fminf(fmaxf(fy, 0.f), lim);
        int qrbx = (int)fminf(fmaxf(fx + 1.f, 0.f), lim);
        int qrby = (int)fminf(fmaxf(fy + 1.f, 0.f), lim);
        float pxc = fminf(fmaxf(px, 0.f), lim);
        float pyc = fminf(fmaxf(py, 0.f), lim);
        float gxl = 1.f + ((float)qltx - pxc);
        float gxr = 1.f - ((float)qrbx - pxc);
        float gyl = 1.f + ((float)qlty - pyc);
        float gyr = 1.f - ((float)qrby - pyc);
        int   xs[4] = {qltx, qrbx, qltx, qrbx};
        int   ys[4] = {qlty, qrby, qrby, qlty};
        float gs[4] = {gxl * gyl, gxr * gyr, gxl * gyr, gxr * gyl};
        u16x8 m;
        #pragma unroll
        for (int q = 0; q < 4; q++) {
            int qx = xs[q], qy = ys[q];
            bool valid = (qx >= 1 && qx <= H && qy >= 1 && qy <= W);
            m[q]     = valid ? (unsigned short)((qx - 1) * W + (qy - 1)) : (unsigned short)0;
            m[4 + q] = f2bf(valid ? gs[q] * mk : 0.f);
        }
        *reinterpret_cast<u16x8*>(&meta[n][p][0]) = m;
    }
    __syncthreads();

    const unsigned short* xtb = xt + (size_t)b * HW * CIN;

    auto sample = [&](int n, int bi) {
        #pragma unroll
        for (int t2 = 0; t2 < TASKS; t2++) {
            int T = t2 * 512 + tid;
            int p = T >> SHIFT, cl = T & (SEG - 1);
            u16x8 m = *reinterpret_cast<const u16x8*>(&meta[n][p][0]);
            float vac[8];
            #pragma unroll
            for (int e = 0; e < 8; e++) vac[e] = 0.f;
            #pragma unroll
            for (int q = 0; q < 4; q++) {
                const unsigned short* sp = xtb + (size_t)m[q] * CIN + cl * 8;
                u16x8 v = *reinterpret_cast<const u16x8*>(sp);
                float wq = bf2f(m[4 + q]);
                const unsigned* vd = reinterpret_cast<const unsigned*>(&v);
                #pragma unroll
                for (int d = 0; d < 4; d++) {
                    vac[2 * d]     = fmaf(bflo(vd[d]), wq, vac[2 * d]);
                    vac[2 * d + 1] = fmaf(bfhi(vd[d]), wq, vac[2 * d + 1]);
                }
            }
            u16x8 o;
            #pragma unroll
            for (int e = 0; e < 8; e++) o[e] = f2bf(vac[e]);
            *reinterpret_cast<u16x8*>(&sbuf[bi][p][cl * 8]) = o;
        }
    };
    auto stage_w = [&](int n, int bi) {
        #pragma unroll
        for (int t2 = 0; t2 < TASKS; t2++) {
            int S = t2 * 512 + tid;
            int row = S >> SHIFT, seg = S & (SEG - 1);
            u16x8 v = *reinterpret_cast<const u16x8*>(
                wtp + (size_t)row * (9 * CIN) + n * CIN + seg * 8);
            *reinterpret_cast<u16x8*>(&wbuf[bi][row][seg * 8]) = v;
        }
    };

    sample(0, 0);
    stage_w(0, 0);
    __syncthreads();

    int lane = tid & 63, wv = tid >> 6;
    int ocq = wv & 1, pq = wv >> 1;
    int lr = lane & 15, lg = lane >> 4;
    int srow = pq * 16 + lr;
    int wrow = ocq * 32 + lr;

    f32x4 acc0 = {0.f, 0.f, 0.f, 0.f};
    f32x4 acc1 = {0.f, 0.f, 0.f, 0.f};

    for (int n = 0; n < 9; n++) {
        int cur = n & 1;
        #pragma unroll
        for (int ks = 0; ks < CIN / 32; ks++) {
            bf16x8 bfr = *reinterpret_cast<const bf16x8*>(&sbuf[cur][srow][ks * 32 + lg * 8]);
            bf16x8 a0  = *reinterpret_cast<const bf16x8*>(&wbuf[cur][wrow][ks * 32 + lg * 8]);
            bf16x8 a1  = *reinterpret_cast<const bf16x8*>(&wbuf[cur][wrow + 16][ks * 32 + lg * 8]);
            acc0 = __builtin_amdgcn_mfma_f32_16x16x32_bf16(a0, bfr, acc0, 0, 0, 0);
            acc1 = __builtin_amdgcn_mfma_f32_16x16x32_bf16(a1, bfr, acc1, 0, 0, 0);
        }
        if (n + 1 < 9) {
            sample(n + 1, cur ^ 1);
            stage_w(n + 1, cur ^ 1);
        }
        __syncthreads();
    }

    int pixo = base + pq * 16 + lr;
    float* ob0 = out + ((size_t)b * 64 + ocq * 32 + lg * 4) * HW + pixo;
    #pragma unroll
    for (int r = 0; r < 4; r++) ob0[(size_t)r * HW] = acc0[r];
    float* ob1 = out + ((size_t)b * 64 + ocq * 32 + 16 + lg * 4) * HW + pixo;
    #pragma unroll
    for (int r = 0; r < 4; r++) ob1[(size_t)r * HW] = acc1[r];
}

// ---------------------------------------------------------------------------
// Group-norm statistics. One block per (b, group).
// ---------------------------------------------------------------------------
__global__ __launch_bounds__(256) void gn_stats(
    const float* __restrict__ buf, float* __restrict__ stats)
{
    int bg = blockIdx.x;
    const float4* v = reinterpret_cast<const float4*>(buf + (size_t)bg * 4 * HW);
    float sum = 0.f, ssq = 0.f;
    for (int idx = threadIdx.x; idx < 4 * HW / 4; idx += 256) {
        float4 x = v[idx];
        sum += x.x + x.y + x.z + x.w;
        ssq += x.x * x.x + x.y * x.y + x.z * x.z + x.w * x.w;
    }
    #pragma unroll
    for (int d = 32; d > 0; d >>= 1) {
        sum += __shfl_down(sum, d);
        ssq += __shfl_down(ssq, d);
    }
    __shared__ float ws1[4], ws2[4];
    int wid = threadIdx.x >> 6;
    if ((threadIdx.x & 63) == 0) { ws1[wid] = sum; ws2[wid] = ssq; }
    __syncthreads();
    if (threadIdx.x == 0) {
        float S = ws1[0] + ws1[1] + ws1[2] + ws1[3];
        float Q = ws2[0] + ws2[1] + ws2[2] + ws2[3];
        float mean = S * (1.0f / (4.0f * HW));
        float var  = Q * (1.0f / (4.0f * HW)) - mean * mean;
        stats[bg]      = mean;
        stats[32 + bg] = rsqrtf(var + 1e-5f);
    }
}

// ---------------------------------------------------------------------------
// GN(+relu) on the fly -> channel mean & max maps only.
// ---------------------------------------------------------------------------
__global__ __launch_bounds__(256) void gn_meanmax(
    const float* __restrict__ dc, const float* __restrict__ stats,
    const float* __restrict__ gamma, const float* __restrict__ beta,
    float* __restrict__ cm, float* __restrict__ cx)
{
    int t = blockIdx.x * 256 + threadIdx.x;
    if (t >= BATCH * HW) return;
    int b = t >> 14;
    int pix = t & (HW - 1);
    float msum = 0.f, mmax = -INFINITY;
    #pragma unroll 8
    for (int c = 0; c < 64; c++) {
        int g = c >> 2;
        float mean = stats[b * 16 + g];
        float rstd = stats[32 + b * 16 + g];
        size_t idx = ((size_t)b * 64 + c) * HW + pix;
        float v = (dc[idx] - mean) * rstd * gamma[c] + beta[c];
        v = fmaxf(v, 0.f);
        msum += v;
        mmax = fmaxf(mmax, v);
    }
    cm[t] = msum * (1.0f / 64.0f);
    cx[t] = mmax;
}

// ---------------------------------------------------------------------------
// 1-ch 3x3 convs over cm/cx + sigmoid -> av, mv maps.
// ---------------------------------------------------------------------------
__global__ __launch_bounds__(256) void attn_sig(
    const float* __restrict__ cm, const float* __restrict__ cx,
    const float* __restrict__ wa, const float* __restrict__ ba,
    const float* __restrict__ wb, const float* __restrict__ bb,
    float* __restrict__ avb, float* __restrict__ mvb)
{
    int t = blockIdx.x * 256 + threadIdx.x;
    if (t >= BATCH * HW) return;
    int b = t >> 14;
    int pix = t & (HW - 1);
    int i = pix >> 7, j = pix & (W - 1);
    float sa = ba[0], sb = bb[0];
    #pragma unroll
    for (int di = 0; di < 3; di++) {
        int ii = i + di - 1;
        if (ii < 0 || ii >= H) continue;
        #pragma unroll
        for (int dj = 0; dj < 3; dj++) {
            int jj = j + dj - 1;
            if (jj < 0 || jj >= W) continue;
            int q = (b << 14) + (ii << 7) + jj;
            sa = fmaf(cm[q], wa[di * 3 + dj], sa);
            sb = fmaf(cx[q], wb[di * 3 + dj], sb);
        }
    }
    avb[t] = sigmoidf_(sa);
    mvb[t] = sigmoidf_(sb);
}

// ---------------------------------------------------------------------------
// Fused GN+relu + attention-scale + concat + transpose -> bf16 catt
// ---------------------------------------------------------------------------
__global__ __launch_bounds__(256) void attn_cat_t(
    const float* __restrict__ dc, const float* __restrict__ stats,
    const float* __restrict__ gamma, const float* __restrict__ beta,
    const float* __restrict__ avb, const float* __restrict__ mvb,
    unsigned short* __restrict__ catt)
{
    __shared__ float tile[64][65];
    __shared__ float avs[64], mvs[64];
    int blk = blockIdx.x;               // 512
    int b  = blk >> 8;
    int p0 = (blk & 255) * 64;
    int tr = threadIdx.x >> 6;
    int tc = threadIdx.x & 63;
    if (threadIdx.x < 64)       avs[threadIdx.x] = avb[(size_t)b * HW + p0 + threadIdx.x];
    else if (threadIdx.x < 128) mvs[threadIdx.x - 64] = mvb[(size_t)b * HW + p0 + threadIdx.x - 64];
    #pragma unroll
    for (int r = 0; r < 16; r++) {
        int c = r * 4 + tr;
        float mean = stats[b * 16 + (c >> 2)];
        float rstd = stats[32 + b * 16 + (c >> 2)];
        float v = dc[((size_t)b * 64 + c) * HW + p0 + tc];
        tile[c][tc] = fmaxf((v - mean) * rstd * gamma[c] + beta[c], 0.f);
    }
    __syncthreads();
    #pragma unroll
    for (int r = 0; r < 16; r++) {
        int p = r * 4 + tr;
        float v = tile[tc][p];
        unsigned short* cr = catt + ((size_t)b * HW + p0 + p) * 128;
        cr[tc]      = f2bf(avs[p] * v);
        cr[64 + tc] = f2bf(mvs[p] * v);
    }
}

// ---------------------------------------------------------------------------
// Final GN + relu -> d_out
// ---------------------------------------------------------------------------
__global__ __launch_bounds__(256) void gn_final(
    const float* __restrict__ dc, const float* __restrict__ stats,
    const float* __restrict__ gamma, const float* __restrict__ beta,
    float* __restrict__ out)
{
    int t = blockIdx.x * 256 + threadIdx.x;
    if (t >= BATCH * 64 * HW) return;
    int c = (t >> 14) & 63;
    int b = t >> 20;
    int g = c >> 2;
    float mean = stats[b * 16 + g];
    float rstd = stats[32 + b * 16 + g];
    float v = (dc[t] - mean) * rstd * gamma[c] + beta[c];
    out[t] = fmaxf(v, 0.f);
}

// ---------------------------------------------------------------------------
extern "C" void kernel_launch(void* const* d_in, const int* in_sizes, int n_in,
                              void* d_out, int out_size, void* d_ws, size_t ws_size,
                              hipStream_t stream) {
    (void)in_sizes; (void)n_in; (void)out_size; (void)ws_size;
    const float* x   = (const float*)d_in[0];
    const float* wp1 = (const float*)d_in[1];
    const float* bp1 = (const float*)d_in[2];
    const float* wm1 = (const float*)d_in[3];
    const float* bm1 = (const float*)d_in[4];
    const float* wc1 = (const float*)d_in[5];
    const float* g1  = (const float*)d_in[6];
    const float* be1 = (const float*)d_in[7];
    const float* wa  = (const float*)d_in[8];
    const float* ba  = (const float*)d_in[9];
    const float* wb  = (const float*)d_in[10];
    const float* bb  = (const float*)d_in[11];
    const float* wp2 = (const float*)d_in[12];
    const float* bp2 = (const float*)d_in[13];
    const float* wm2 = (const float*)d_in[14];
    const float* bm2 = (const float*)d_in[15];
    const float* wc2 = (const float*)d_in[16];
    const float* g2  = (const float*)d_in[17];
    const float* be2 = (const float*)d_in[18];
    float* out = (float*)d_out;

    // ---- workspace layout ----
    float* ws   = (float*)d_ws;
    float* offb = ws;                              //  884736 f
    float* dcb  = offb + 2 * 27 * HW;              // 2097152 f
    float* cmb  = dcb + 2 * 64 * HW;               //   32768 f
    float* cxb  = cmb + 2 * HW;                    //   32768 f
    float* avb  = cxb + 2 * HW;                    //   32768 f
    float* mvb  = avb + 2 * HW;                    //   32768 f
    unsigned short* catt = (unsigned short*)(mvb + 2 * HW);  // 2*HW*128 u16
    float* stb  = (float*)(catt + (size_t)2 * 128 * HW);     //      64 f
    unsigned short* wtp1 = (unsigned short*)(stb + 64);      // 64*576
    unsigned short* wtp2 = wtp1 + 64 * 576;                  // 64*1152
    unsigned short* wop1 = wtp2 + 64 * 1152;                 // 32*576
    unsigned short* wop2 = wop1 + 32 * 576;                  // 32*1152
    // x transposed [B][HW][64] bf16 in d_out scratch (rewritten by gn_final)
    unsigned short* xt1 = (unsigned short*)out;

    const int NPIXB = (BATCH * HW + 255) / 256;      // 128
    const int NDEF  = BATCH * HW / 64;               // 512

    transpose_x64<<<512, 256, 0, stream>>>(x, xt1);
    transpose_wtap<64><<<(64 * 9 * 64 + 255) / 256, 256, 0, stream>>>(wc1, wtp1);
    transpose_wtap<128><<<(64 * 9 * 128 + 255) / 256, 256, 0, stream>>>(wc2, wtp2);
    transpose_wofft<64><<<(32 * 9 * 64 + 255) / 256, 256, 0, stream>>>(wp1, wm1, wop1);
    transpose_wofft<128><<<(32 * 9 * 128 + 255) / 256, 256, 0, stream>>>(wp2, wm2, wop2);

    // ---- stage 1 ----
    conv_off_mfma<64><<<NDEF, 512, 0, stream>>>(xt1, wop1, bp1, bm1, offb);
    deform_mfma<64><<<NDEF, 512, 0, stream>>>(xt1, offb, wtp1, dcb);
    gn_stats<<<32, 256, 0, stream>>>(dcb, stb);
    gn_meanmax<<<NPIXB, 256, 0, stream>>>(dcb, stb, g1, be1, cmb, cxb);
    attn_sig<<<NPIXB, 256, 0, stream>>>(cmb, cxb, wa, ba, wb, bb, avb, mvb);
    attn_cat_t<<<512, 256, 0, stream>>>(dcb, stb, g1, be1, avb, mvb, catt);

    // ---- stage 2 ----
    conv_off_mfma<128><<<NDEF, 512, 0, stream>>>(catt, wop2, bp2, bm2, offb);
    deform_mfma<128><<<NDEF, 512, 0, stream>>>(catt, offb, wtp2, dcb);
    gn_stats<<<32, 256, 0, stream>>>(dcb, stb);
    gn_final<<<(BATCH * 64 * HW + 255) / 256, 256, 0, stream>>>(dcb, stb, g2, be2, out);
}

// Round 12
// 132.071 us; speedup vs baseline: 3.2532x; 1.0379x over previous
//
#include <hip/hip_runtime.h>
#include <hip/hip_bf16.h>
#include <math.h>

#define H 128
#define W 128
#define HW (H*W)
#define BATCH 2

typedef __attribute__((ext_vector_type(8))) short          bf16x8;
typedef __attribute__((ext_vector_type(4))) float          f32x4;
typedef __attribute__((ext_vector_type(8))) unsigned short u16x8;

__device__ __forceinline__ float sigmoidf_(float x){ return 1.0f/(1.0f + expf(-x)); }

__device__ __forceinline__ unsigned short f2bf(float f) {
    __hip_bfloat16 h = __float2bfloat16(f);          // RTNE
    return __builtin_bit_cast(unsigned short, h);
}
__device__ __forceinline__ float bf2f(unsigned short b) {
    return __uint_as_float(((unsigned)b) << 16);
}
__device__ __forceinline__ float bflo(unsigned u){ return __uint_as_float(u << 16); }
__device__ __forceinline__ float bfhi(unsigned u){ return __uint_as_float(u & 0xFFFF0000u); }

// ---------------------------------------------------------------------------
// Transpose x [B][64][HW] fp32 -> xt [B][HW][64] bf16
// ---------------------------------------------------------------------------
__global__ __launch_bounds__(256) void transpose_x64(
    const float* __restrict__ x, unsigned short* __restrict__ xt)
{
    __shared__ float tile[64][65];
    int blk = blockIdx.x;               // 512 = 2 b * 256 pix-tiles
    int b  = blk >> 8;
    int p0 = (blk & 255) * 64;
    int tr = threadIdx.x >> 6;
    int tc = threadIdx.x & 63;
    #pragma unroll
    for (int r = 0; r < 16; r++) {
        int c = r * 4 + tr;
        tile[c][tc] = x[((size_t)b * 64 + c) * HW + p0 + tc];
    }
    __syncthreads();
    #pragma unroll
    for (int r = 0; r < 16; r++) {
        int p = r * 4 + tr;
        xt[((size_t)b * HW + p0 + p) * 64 + tc] = f2bf(tile[tc][p]);
    }
}

// ---------------------------------------------------------------------------
// All weight preps fused (tap-major layouts, bf16):
//   wtp1[oc][n*64+c]  = wc1[oc][c][n]   (64 oc)
//   wtp2[oc][n*128+c] = wc2[oc][c][n]   (64 oc)
//   wop1[oc][n*64+c]  = {wp1|wm1|0}     (32 oc rows, 27 used)
//   wop2[oc][n*128+c] = {wp2|wm2|0}
// ---------------------------------------------------------------------------
__global__ __launch_bounds__(256) void prep_weights(
    const float* __restrict__ wc1, const float* __restrict__ wc2,
    const float* __restrict__ wp1, const float* __restrict__ wm1,
    const float* __restrict__ wp2, const float* __restrict__ wm2,
    unsigned short* __restrict__ wtp1, unsigned short* __restrict__ wtp2,
    unsigned short* __restrict__ wop1, unsigned short* __restrict__ wop2)
{
    const int s1 = 64 * 9 * 64, s2 = 64 * 9 * 128;
    const int s3 = 32 * 9 * 64, s4 = 32 * 9 * 128;
    int t = blockIdx.x * 256 + threadIdx.x;
    if (t < s1) {
        int oc = t / (9 * 64); int r = t - oc * (9 * 64);
        int n = r / 64, c = r - n * 64;
        wtp1[t] = f2bf(wc1[((size_t)oc * 64 + c) * 9 + n]);
        return;
    }
    t -= s1;
    if (t < s2) {
        int oc = t / (9 * 128); int r = t - oc * (9 * 128);
        int n = r / 128, c = r - n * 128;
        wtp2[t] = f2bf(wc2[((size_t)oc * 128 + c) * 9 + n]);
        return;
    }
    t -= s2;
    if (t < s3) {
        int oc = t / (9 * 64); int r = t - oc * (9 * 64);
        int n = r / 64, c = r - n * 64;
        float v = 0.f;
        if (oc < 18)      v = wp1[((size_t)oc * 64 + c) * 9 + n];
        else if (oc < 27) v = wm1[((size_t)(oc - 18) * 64 + c) * 9 + n];
        wop1[t] = f2bf(v);
        return;
    }
    t -= s3;
    if (t < s4) {
        int oc = t / (9 * 128); int r = t - oc * (9 * 128);
        int n = r / 128, c = r - n * 128;
        float v = 0.f;
        if (oc < 18)      v = wp2[((size_t)oc * 128 + c) * 9 + n];
        else if (oc < 27) v = wm2[((size_t)(oc - 18) * 128 + c) * 9 + n];
        wop2[t] = f2bf(v);
    }
}

// ---------------------------------------------------------------------------
// Offset/mask conv via MFMA. Chunk = 64 channels of one tap (CCH=64):
// CIN=64 -> 9 chunks (same as R10); CIN=128 -> 18 chunks, halved LDS ->
// 4 blocks/CU. Block: 64 pix x 32 oc, 512 threads.
// ---------------------------------------------------------------------------
template<int CIN>
__global__ __launch_bounds__(512, 8) void conv_off_mfma(
    const unsigned short* __restrict__ xt,  // [B][HW][CIN] bf16
    const unsigned short* __restrict__ wop, // [32][9*CIN] bf16 tap-major
    const float* __restrict__ bp,           // [18]
    const float* __restrict__ bm,           // [9]
    float* __restrict__ offb)               // [B][27][HW]
{
    constexpr int HPC  = CIN / 64;           // half-chunks per tap: 1 or 2
    constexpr int NCH  = 9 * HPC;
    constexpr int SROW = 68;                 // 64 + 4 pad
    __shared__ __align__(16) unsigned short sbuf[2][64][SROW];
    __shared__ __align__(16) unsigned short wbuf[2][32][SROW];

    int tid  = threadIdx.x;
    int pix0 = blockIdx.x * 64;
    int b    = pix0 >> 14;
    int base = pix0 & (HW - 1);
    int i    = base >> 7;
    int j0   = base & 127;

    const unsigned short* xtb = xt + (size_t)b * HW * CIN;
    const u16x8 zero8 = {0,0,0,0,0,0,0,0};

    auto sample = [&](int cc, int bi) {
        int n = cc / HPC, h = cc - n * HPC;
        int di = n / 3 - 1, dj = n - (n / 3) * 3 - 1;
        int ii = i + di;
        bool rowok = (ii >= 0 && ii < H);
        int p = tid >> 3, cl = tid & 7;
        int jj = j0 + p + dj;
        bool v = rowok && (jj >= 0 && jj < W);
        u16x8 val = v ? *reinterpret_cast<const u16x8*>(
                            xtb + (size_t)(ii * W + jj) * CIN + h * 64 + cl * 8)
                      : zero8;
        *reinterpret_cast<u16x8*>(&sbuf[bi][p][cl * 8]) = val;
    };
    auto stage_w = [&](int cc, int bi) {
        if (tid < 256) {
            int n = cc / HPC, h = cc - n * HPC;
            int row = tid >> 3, seg = tid & 7;
            u16x8 v = *reinterpret_cast<const u16x8*>(
                wop + (size_t)row * (9 * CIN) + n * CIN + h * 64 + seg * 8);
            *reinterpret_cast<u16x8*>(&wbuf[bi][row][seg * 8]) = v;
        }
    };

    sample(0, 0);
    stage_w(0, 0);
    __syncthreads();

    int lane = tid & 63, wv = tid >> 6;
    int mt = wv & 1, nt = wv >> 1;          // oc-half, pix-quarter
    int lr = lane & 15, lg = lane >> 4;
    int srow = nt * 16 + lr;
    int wrow = mt * 16 + lr;

    f32x4 acc = {0.f, 0.f, 0.f, 0.f};

    for (int cc = 0; cc < NCH; cc++) {
        int cur = cc & 1;
        #pragma unroll
        for (int ks = 0; ks < 2; ks++) {
            bf16x8 bfr = *reinterpret_cast<const bf16x8*>(&sbuf[cur][srow][ks * 32 + lg * 8]);
            bf16x8 a   = *reinterpret_cast<const bf16x8*>(&wbuf[cur][wrow][ks * 32 + lg * 8]);
            acc = __builtin_amdgcn_mfma_f32_16x16x32_bf16(a, bfr, acc, 0, 0, 0);
        }
        if (cc + 1 < NCH) {
            sample(cc + 1, cur ^ 1);
            stage_w(cc + 1, cur ^ 1);
        }
        __syncthreads();
    }

    // epilogue: D col = lane&15 (pixel), row = lg*4 + r (oc within half)
    int pixo = base + nt * 16 + lr;
    #pragma unroll
    for (int r = 0; r < 4; r++) {
        int oc = mt * 16 + lg * 4 + r;
        if (oc < 27) {
            float v = acc[r];
            v = (oc < 18) ? (v + bp[oc]) : sigmoidf_(v + bm[oc - 18]);
            offb[((size_t)b * 27 + oc) * HW + pixo] = v;
        }
    }
}

// ---------------------------------------------------------------------------
// Deformable sampling + main conv via MFMA. Chunk = 64 channels of one tap.
// CIN=64 -> 9 chunks (R10-identical); CIN=128 -> 18 chunks, LDS 44 KB ->
// 3 blocks/CU. Block: 64 pix x 64 oc, 512 threads. Meta in LDS (once).
// ---------------------------------------------------------------------------
template<int CIN>
__global__ __launch_bounds__(512, 6) void deform_mfma(
    const unsigned short* __restrict__ xt,  // [B][HW][CIN] bf16
    const float* __restrict__ off,          // [B][27][HW]
    const unsigned short* __restrict__ wtp, // [64][9*CIN] bf16 tap-major
    float* __restrict__ out)                // [B][64][HW]
{
    constexpr int HPC  = CIN / 64;
    constexpr int NCH  = 9 * HPC;
    constexpr int SROW = 68;
    __shared__ __align__(16) unsigned short sbuf[2][64][SROW];
    __shared__ __align__(16) unsigned short wbuf[2][64][SROW];
    __shared__ __align__(16) unsigned short meta[9][64][8];

    int tid  = threadIdx.x;
    int pix0 = blockIdx.x * 64;
    int b    = pix0 >> 14;
    int base = pix0 & (HW - 1);
    int i    = base >> 7;
    int j0   = base & 127;

    // ---- bilinear metadata (once per block): 4x u16 pix-idx + 4x bf16 wt ---
    for (int task = tid; task < 576; task += 512) {
        int p = task & 63, n = task >> 6;
        int j = j0 + p;
        const float* ob = off + (size_t)b * 27 * HW + (i << 7) + j;
        float px = ob[(size_t)n * HW]       + (float)(n / 3 - 1) + (float)(i + 1);
        float py = ob[(size_t)(9 + n) * HW] + (float)(n % 3 - 1) + (float)(j + 1);
        float mk = ob[(size_t)(18 + n) * HW];
        float fx = floorf(px), fy = floorf(py);
        const float lim = 129.0f;            // Hp-1 = Wp-1
        int qltx = (int)fminf(fmaxf(fx, 0.f), lim);
        int qlty = (int)fminf(fmaxf(fy, 0.f), lim);
        int qrbx = (int)fminf(fmaxf(fx + 1.f, 0.f), lim);
        int qrby = (int)fminf(fmaxf(fy + 1.f, 0.f), lim);
        float pxc = fminf(fmaxf(px, 0.f), lim);
        float pyc = fminf(fmaxf(py, 0.f), lim);
        float gxl = 1.f + ((float)qltx - pxc);
        float gxr = 1.f - ((float)qrbx - pxc);
        float gyl = 1.f + ((float)qlty - pyc);
        float gyr = 1.f - ((float)qrby - pyc);
        int   xs[4] = {qltx, qrbx, qltx, qrbx};
        int   ys[4] = {qlty, qrby, qrby, qlty};
        float gs[4] = {gxl * gyl, gxr * gyr, gxl * gyr, gxr * gyl};
        u16x8 m;
        #pragma unroll
        for (int q = 0; q < 4; q++) {
            int qx = xs[q], qy = ys[q];
            bool valid = (qx >= 1 && qx <= H && qy >= 1 && qy <= W);
            m[q]     = valid ? (unsigned short)((qx - 1) * W + (qy - 1)) : (unsigned short)0;
            m[4 + q] = f2bf(valid ? gs[q] * mk : 0.f);
        }
        *reinterpret_cast<u16x8*>(&meta[n][p][0]) = m;
    }
    __syncthreads();

    const unsigned short* xtb = xt + (size_t)b * HW * CIN;

    auto sample = [&](int cc, int bi) {
        int n = cc / HPC, h = cc - n * HPC;
        int p = tid >> 3, cl = tid & 7;
        u16x8 m = *reinterpret_cast<const u16x8*>(&meta[n][p][0]);
        float vac[8];
        #pragma unroll
        for (int e = 0; e < 8; e++) vac[e] = 0.f;
        #pragma unroll
        for (int q = 0; q < 4; q++) {
            const unsigned short* sp = xtb + (size_t)m[q] * CIN + h * 64 + cl * 8;
            u16x8 v = *reinterpret_cast<const u16x8*>(sp);
            float wq = bf2f(m[4 + q]);
            const unsigned* vd = reinterpret_cast<const unsigned*>(&v);
            #pragma unroll
            for (int d = 0; d < 4; d++) {
                vac[2 * d]     = fmaf(bflo(vd[d]), wq, vac[2 * d]);
                vac[2 * d + 1] = fmaf(bfhi(vd[d]), wq, vac[2 * d + 1]);
            }
        }
        u16x8 o;
        #pragma unroll
        for (int e = 0; e < 8; e++) o[e] = f2bf(vac[e]);
        *reinterpret_cast<u16x8*>(&sbuf[bi][p][cl * 8]) = o;
    };
    auto stage_w = [&](int cc, int bi) {
        int n = cc / HPC, h = cc - n * HPC;
        int row = tid >> 3, seg = tid & 7;
        u16x8 v = *reinterpret_cast<const u16x8*>(
            wtp + (size_t)row * (9 * CIN) + n * CIN + h * 64 + seg * 8);
        *reinterpret_cast<u16x8*>(&wbuf[bi][row][seg * 8]) = v;
    };

    sample(0, 0);
    stage_w(0, 0);
    __syncthreads();

    int lane = tid & 63, wv = tid >> 6;
    int ocq = wv & 1, pq = wv >> 1;
    int lr = lane & 15, lg = lane >> 4;
    int srow = pq * 16 + lr;
    int wrow = ocq * 32 + lr;

    f32x4 acc0 = {0.f, 0.f, 0.f, 0.f};
    f32x4 acc1 = {0.f, 0.f, 0.f, 0.f};

    for (int cc = 0; cc < NCH; cc++) {
        int cur = cc & 1;
        #pragma unroll
        for (int ks = 0; ks < 2; ks++) {
            bf16x8 bfr = *reinterpret_cast<const bf16x8*>(&sbuf[cur][srow][ks * 32 + lg * 8]);
            bf16x8 a0  = *reinterpret_cast<const bf16x8*>(&wbuf[cur][wrow][ks * 32 + lg * 8]);
            bf16x8 a1  = *reinterpret_cast<const bf16x8*>(&wbuf[cur][wrow + 16][ks * 32 + lg * 8]);
            acc0 = __builtin_amdgcn_mfma_f32_16x16x32_bf16(a0, bfr, acc0, 0, 0, 0);
            acc1 = __builtin_amdgcn_mfma_f32_16x16x32_bf16(a1, bfr, acc1, 0, 0, 0);
        }
        if (cc + 1 < NCH) {
            sample(cc + 1, cur ^ 1);
            stage_w(cc + 1, cur ^ 1);
        }
        __syncthreads();
    }

    int pixo = base + pq * 16 + lr;
    float* ob0 = out + ((size_t)b * 64 + ocq * 32 + lg * 4) * HW + pixo;
    #pragma unroll
    for (int r = 0; r < 4; r++) ob0[(size_t)r * HW] = acc0[r];
    float* ob1 = out + ((size_t)b * 64 + ocq * 32 + 16 + lg * 4) * HW + pixo;
    #pragma unroll
    for (int r = 0; r < 4; r++) ob1[(size_t)r * HW] = acc1[r];
}

// ---------------------------------------------------------------------------
// Group-norm statistics. One block per (b, group).
// ---------------------------------------------------------------------------
__global__ __launch_bounds__(256) void gn_stats(
    const float* __restrict__ buf, float* __restrict__ stats)
{
    int bg = blockIdx.x;
    const float4* v = reinterpret_cast<const float4*>(buf + (size_t)bg * 4 * HW);
    float sum = 0.f, ssq = 0.f;
    for (int idx = threadIdx.x; idx < 4 * HW / 4; idx += 256) {
        float4 x = v[idx];
        sum += x.x + x.y + x.z + x.w;
        ssq += x.x * x.x + x.y * x.y + x.z * x.z + x.w * x.w;
    }
    #pragma unroll
    for (int d = 32; d > 0; d >>= 1) {
        sum += __shfl_down(sum, d);
        ssq += __shfl_down(ssq, d);
    }
    __shared__ float ws1[4], ws2[4];
    int wid = threadIdx.x >> 6;
    if ((threadIdx.x & 63) == 0) { ws1[wid] = sum; ws2[wid] = ssq; }
    __syncthreads();
    if (threadIdx.x == 0) {
        float S = ws1[0] + ws1[1] + ws1[2] + ws1[3];
        float Q = ws2[0] + ws2[1] + ws2[2] + ws2[3];
        float mean = S * (1.0f / (4.0f * HW));
        float var  = Q * (1.0f / (4.0f * HW)) - mean * mean;
        stats[bg]      = mean;
        stats[32 + bg] = rsqrtf(var + 1e-5f);
    }
}

// ---------------------------------------------------------------------------
// GN(+relu) on the fly -> channel mean & max maps only.
// ---------------------------------------------------------------------------
__global__ __launch_bounds__(256) void gn_meanmax(
    const float* __restrict__ dc, const float* __restrict__ stats,
    const float* __restrict__ gamma, const float* __restrict__ beta,
    float* __restrict__ cm, float* __restrict__ cx)
{
    int t = blockIdx.x * 256 + threadIdx.x;
    if (t >= BATCH * HW) return;
    int b = t >> 14;
    int pix = t & (HW - 1);
    float msum = 0.f, mmax = -INFINITY;
    #pragma unroll 8
    for (int c = 0; c < 64; c++) {
        int g = c >> 2;
        float mean = stats[b * 16 + g];
        float rstd = stats[32 + b * 16 + g];
        size_t idx = ((size_t)b * 64 + c) * HW + pix;
        float v = (dc[idx] - mean) * rstd * gamma[c] + beta[c];
        v = fmaxf(v, 0.f);
        msum += v;
        mmax = fmaxf(mmax, v);
    }
    cm[t] = msum * (1.0f / 64.0f);
    cx[t] = mmax;
}

// ---------------------------------------------------------------------------
// Fused: spatial-attention sigmoids (inline 1-ch 3x3 convs over cm/cx) +
// GN+relu + scale + concat + transpose -> bf16 catt [B][HW][128]
// ---------------------------------------------------------------------------
__global__ __launch_bounds__(256) void attn_cat_t(
    const float* __restrict__ dc, const float* __restrict__ stats,
    const float* __restrict__ gamma, const float* __restrict__ beta,
    const float* __restrict__ cm, const float* __restrict__ cx,
    const float* __restrict__ wa, const float* __restrict__ ba,
    const float* __restrict__ wb, const float* __restrict__ bb,
    unsigned short* __restrict__ catt)
{
    __shared__ float tile[64][65];
    __shared__ float avs[64], mvs[64];
    int blk = blockIdx.x;               // 512
    int b  = blk >> 8;
    int p0 = (blk & 255) * 64;
    int tr = threadIdx.x >> 6;
    int tc = threadIdx.x & 63;
    // threads 0..63: compute av/mv for pixel p0+tid via 3x3 conv + sigmoid
    if (threadIdx.x < 64) {
        int pix = p0 + threadIdx.x;
        int i = pix >> 7, j = pix & (W - 1);
        float sa = ba[0], sb = bb[0];
        #pragma unroll
        for (int di = 0; di < 3; di++) {
            int ii = i + di - 1;
            if (ii < 0 || ii >= H) continue;
            #pragma unroll
            for (int dj = 0; dj < 3; dj++) {
                int jj = j + dj - 1;
                if (jj < 0 || jj >= W) continue;
                int q = (b << 14) + (ii << 7) + jj;
                sa = fmaf(cm[q], wa[di * 3 + dj], sa);
                sb = fmaf(cx[q], wb[di * 3 + dj], sb);
            }
        }
        avs[threadIdx.x] = sigmoidf_(sa);
        mvs[threadIdx.x] = sigmoidf_(sb);
    }
    #pragma unroll
    for (int r = 0; r < 16; r++) {
        int c = r * 4 + tr;
        float mean = stats[b * 16 + (c >> 2)];
        float rstd = stats[32 + b * 16 + (c >> 2)];
        float v = dc[((size_t)b * 64 + c) * HW + p0 + tc];
        tile[c][tc] = fmaxf((v - mean) * rstd * gamma[c] + beta[c], 0.f);
    }
    __syncthreads();
    #pragma unroll
    for (int r = 0; r < 16; r++) {
        int p = r * 4 + tr;
        float v = tile[tc][p];
        unsigned short* cr = catt + ((size_t)b * HW + p0 + p) * 128;
        cr[tc]      = f2bf(avs[p] * v);
        cr[64 + tc] = f2bf(mvs[p] * v);
    }
}

// ---------------------------------------------------------------------------
// Final GN + relu -> d_out
// ---------------------------------------------------------------------------
__global__ __launch_bounds__(256) void gn_final(
    const float* __restrict__ dc, const float* __restrict__ stats,
    const float* __restrict__ gamma, const float* __restrict__ beta,
    float* __restrict__ out)
{
    int t = blockIdx.x * 256 + threadIdx.x;
    if (t >= BATCH * 64 * HW) return;
    int c = (t >> 14) & 63;
    int b = t >> 20;
    int g = c >> 2;
    float mean = stats[b * 16 + g];
    float rstd = stats[32 + b * 16 + g];
    float v = (dc[t] - mean) * rstd * gamma[c] + beta[c];
    out[t] = fmaxf(v, 0.f);
}

// ---------------------------------------------------------------------------
extern "C" void kernel_launch(void* const* d_in, const int* in_sizes, int n_in,
                              void* d_out, int out_size, void* d_ws, size_t ws_size,
                              hipStream_t stream) {
    (void)in_sizes; (void)n_in; (void)out_size; (void)ws_size;
    const float* x   = (const float*)d_in[0];
    const float* wp1 = (const float*)d_in[1];
    const float* bp1 = (const float*)d_in[2];
    const float* wm1 = (const float*)d_in[3];
    const float* bm1 = (const float*)d_in[4];
    const float* wc1 = (const float*)d_in[5];
    const float* g1  = (const float*)d_in[6];
    const float* be1 = (const float*)d_in[7];
    const float* wa  = (const float*)d_in[8];
    const float* ba  = (const float*)d_in[9];
    const float* wb  = (const float*)d_in[10];
    const float* bb  = (const float*)d_in[11];
    const float* wp2 = (const float*)d_in[12];
    const float* bp2 = (const float*)d_in[13];
    const float* wm2 = (const float*)d_in[14];
    const float* bm2 = (const float*)d_in[15];
    const float* wc2 = (const float*)d_in[16];
    const float* g2  = (const float*)d_in[17];
    const float* be2 = (const float*)d_in[18];
    float* out = (float*)d_out;

    // ---- workspace layout ----
    float* ws   = (float*)d_ws;
    float* offb = ws;                              //  884736 f
    float* dcb  = offb + 2 * 27 * HW;              // 2097152 f
    float* cmb  = dcb + 2 * 64 * HW;               //   32768 f
    float* cxb  = cmb + 2 * HW;                    //   32768 f
    unsigned short* catt = (unsigned short*)(cxb + 2 * HW);  // 2*HW*128 u16
    float* stb  = (float*)(catt + (size_t)2 * 128 * HW);     //      64 f
    unsigned short* wtp1 = (unsigned short*)(stb + 64);      // 64*576
    unsigned short* wtp2 = wtp1 + 64 * 576;                  // 64*1152
    unsigned short* wop1 = wtp2 + 64 * 1152;                 // 32*576
    unsigned short* wop2 = wop1 + 32 * 576;                  // 32*1152
    // x transposed [B][HW][64] bf16 in d_out scratch (rewritten by gn_final)
    unsigned short* xt1 = (unsigned short*)out;

    const int NPIXB = (BATCH * HW + 255) / 256;      // 128
    const int NDEF  = BATCH * HW / 64;               // 512
    const int NPREP = (64 * 576 + 64 * 1152 + 32 * 576 + 32 * 1152 + 255) / 256;

    transpose_x64<<<512, 256, 0, stream>>>(x, xt1);
    prep_weights<<<NPREP, 256, 0, stream>>>(wc1, wc2, wp1, wm1, wp2, wm2,
                                            wtp1, wtp2, wop1, wop2);

    // ---- stage 1 ----
    conv_off_mfma<64><<<NDEF, 512, 0, stream>>>(xt1, wop1, bp1, bm1, offb);
    deform_mfma<64><<<NDEF, 512, 0, stream>>>(xt1, offb, wtp1, dcb);
    gn_stats<<<32, 256, 0, stream>>>(dcb, stb);
    gn_meanmax<<<NPIXB, 256, 0, stream>>>(dcb, stb, g1, be1, cmb, cxb);
    attn_cat_t<<<512, 256, 0, stream>>>(dcb, stb, g1, be1, cmb, cxb,
                                        wa, ba, wb, bb, catt);

    // ---- stage 2 ----
    conv_off_mfma<128><<<NDEF, 512, 0, stream>>>(catt, wop2, bp2, bm2, offb);
    deform_mfma<128><<<NDEF, 512, 0, stream>>>(catt, offb, wtp2, dcb);
    gn_stats<<<32, 256, 0, stream>>>(dcb, stb);
    gn_final<<<(BATCH * 64 * HW + 255) / 256, 256, 0, stream>>>(dcb, stb, g2, be2, out);
}

// Round 13
// 124.424 us; speedup vs baseline: 3.4531x; 1.0615x over previous
//
#include <hip/hip_runtime.h>
#include <hip/hip_bf16.h>
#include <math.h>

#define H 128
#define W 128
#define HW (H*W)
#define BATCH 2

typedef __attribute__((ext_vector_type(8))) short          bf16x8;
typedef __attribute__((ext_vector_type(4))) float          f32x4;
typedef __attribute__((ext_vector_type(8))) unsigned short u16x8;

__device__ __forceinline__ float sigmoidf_(float x){ return 1.0f/(1.0f + expf(-x)); }

__device__ __forceinline__ unsigned short f2bf(float f) {
    __hip_bfloat16 h = __float2bfloat16(f);          // RTNE
    return __builtin_bit_cast(unsigned short, h);
}
__device__ __forceinline__ float bf2f(unsigned short b) {
    return __uint_as_float(((unsigned)b) << 16);
}
__device__ __forceinline__ float bflo(unsigned u){ return __uint_as_float(u << 16); }
__device__ __forceinline__ float bfhi(unsigned u){ return __uint_as_float(u & 0xFFFF0000u); }

// ---------------------------------------------------------------------------
// prep_all: blocks 0..511 transpose x [B][64][HW] f32 -> xt [B][HW][64] bf16;
// blocks 512+ build all tap-major bf16 weight layouts.
// ---------------------------------------------------------------------------
__global__ __launch_bounds__(256) void prep_all(
    const float* __restrict__ x,
    const float* __restrict__ wc1, const float* __restrict__ wc2,
    const float* __restrict__ wp1, const float* __restrict__ wm1,
    const float* __restrict__ wp2, const float* __restrict__ wm2,
    unsigned short* __restrict__ xt,
    unsigned short* __restrict__ wtp1, unsigned short* __restrict__ wtp2,
    unsigned short* __restrict__ wop1, unsigned short* __restrict__ wop2)
{
    __shared__ float tile[64][65];
    if (blockIdx.x < 512) {
        int blk = blockIdx.x;
        int b  = blk >> 8;
        int p0 = (blk & 255) * 64;
        int tr = threadIdx.x >> 6;
        int tc = threadIdx.x & 63;
        #pragma unroll
        for (int r = 0; r < 16; r++) {
            int c = r * 4 + tr;
            tile[c][tc] = x[((size_t)b * 64 + c) * HW + p0 + tc];
        }
        __syncthreads();
        #pragma unroll
        for (int r = 0; r < 16; r++) {
            int p = r * 4 + tr;
            xt[((size_t)b * HW + p0 + p) * 64 + tc] = f2bf(tile[tc][p]);
        }
        return;
    }
    const int s1 = 64 * 9 * 64, s2 = 64 * 9 * 128;
    const int s3 = 32 * 9 * 64, s4 = 32 * 9 * 128;
    int t = (blockIdx.x - 512) * 256 + threadIdx.x;
    if (t < s1) {
        int oc = t / (9 * 64); int r = t - oc * (9 * 64);
        int n = r / 64, c = r - n * 64;
        wtp1[t] = f2bf(wc1[((size_t)oc * 64 + c) * 9 + n]);
        return;
    }
    t -= s1;
    if (t < s2) {
        int oc = t / (9 * 128); int r = t - oc * (9 * 128);
        int n = r / 128, c = r - n * 128;
        wtp2[t] = f2bf(wc2[((size_t)oc * 128 + c) * 9 + n]);
        return;
    }
    t -= s2;
    if (t < s3) {
        int oc = t / (9 * 64); int r = t - oc * (9 * 64);
        int n = r / 64, c = r - n * 64;
        float v = 0.f;
        if (oc < 18)      v = wp1[((size_t)oc * 64 + c) * 9 + n];
        else if (oc < 27) v = wm1[((size_t)(oc - 18) * 64 + c) * 9 + n];
        wop1[t] = f2bf(v);
        return;
    }
    t -= s3;
    if (t < s4) {
        int oc = t / (9 * 128); int r = t - oc * (9 * 128);
        int n = r / 128, c = r - n * 128;
        float v = 0.f;
        if (oc < 18)      v = wp2[((size_t)oc * 128 + c) * 9 + n];
        else if (oc < 27) v = wm2[((size_t)(oc - 18) * 128 + c) * 9 + n];
        wop2[t] = f2bf(v);
    }
}

// ---------------------------------------------------------------------------
// Fused DSA stage: per block of 64 pixels x full oc:
//   phase 1: offset/mask conv (MFMA, 32-oc rows) -> offsets into LDS
//   phase 2: bilinear meta from LDS offsets
//   phase 3: deformable sample + main conv (MFMA, 64 oc) -> out [B][64][HW]
// Chunk = 64 channels of one tap (CCH=64). Structures identical to the
// R10/R11-verified kernels; offb global round-trip eliminated.
// LDS: sbuf 17.4K + wbuf 17.4K + meta 9.2K + offlds 7.3K = 50.3 KB.
// ---------------------------------------------------------------------------
template<int CIN>
__global__ __launch_bounds__(512, 6) void dsa_fused(
    const unsigned short* __restrict__ xt,  // [B][HW][CIN] bf16
    const unsigned short* __restrict__ wop, // [32][9*CIN] bf16 tap-major
    const unsigned short* __restrict__ wtp, // [64][9*CIN] bf16 tap-major
    const float* __restrict__ bp,           // [18]
    const float* __restrict__ bm,           // [9]
    float* __restrict__ out)                // [B][64][HW]
{
    constexpr int HPC  = CIN / 64;
    constexpr int NCH  = 9 * HPC;
    constexpr int SROW = 68;
    __shared__ __align__(16) unsigned short sbuf[2][64][SROW];
    __shared__ __align__(16) unsigned short wbuf[2][64][SROW]; // conv: rows 0..31
    __shared__ __align__(16) unsigned short meta[9][64][8];
    __shared__ float offlds[27][68];

    int tid  = threadIdx.x;
    int pix0 = blockIdx.x * 64;
    int b    = pix0 >> 14;
    int base = pix0 & (HW - 1);
    int i    = base >> 7;
    int j0   = base & 127;

    const unsigned short* xtb = xt + (size_t)b * HW * CIN;
    const u16x8 zero8 = {0,0,0,0,0,0,0,0};

    int lane = tid & 63, wv = tid >> 6;
    int lr = lane & 15, lg = lane >> 4;

    // ================= phase 1: offset/mask conv =================
    {
        auto sample = [&](int cc, int bi) {
            int n = cc / HPC, h = cc - n * HPC;
            int di = n / 3 - 1, dj = n - (n / 3) * 3 - 1;
            int ii = i + di;
            bool rowok = (ii >= 0 && ii < H);
            int p = tid >> 3, cl = tid & 7;
            int jj = j0 + p + dj;
            bool v = rowok && (jj >= 0 && jj < W);
            u16x8 val = v ? *reinterpret_cast<const u16x8*>(
                                xtb + (size_t)(ii * W + jj) * CIN + h * 64 + cl * 8)
                          : zero8;
            *reinterpret_cast<u16x8*>(&sbuf[bi][p][cl * 8]) = val;
        };
        auto stage_w = [&](int cc, int bi) {
            if (tid < 256) {
                int n = cc / HPC, h = cc - n * HPC;
                int row = tid >> 3, seg = tid & 7;
                u16x8 v = *reinterpret_cast<const u16x8*>(
                    wop + (size_t)row * (9 * CIN) + n * CIN + h * 64 + seg * 8);
                *reinterpret_cast<u16x8*>(&wbuf[bi][row][seg * 8]) = v;
            }
        };

        sample(0, 0);
        stage_w(0, 0);
        __syncthreads();

        int mt = wv & 1, nt = wv >> 1;      // oc-half, pix-quarter
        int srow = nt * 16 + lr;
        int wrow = mt * 16 + lr;
        f32x4 acc = {0.f, 0.f, 0.f, 0.f};

        for (int cc = 0; cc < NCH; cc++) {
            int cur = cc & 1;
            #pragma unroll
            for (int ks = 0; ks < 2; ks++) {
                bf16x8 bfr = *reinterpret_cast<const bf16x8*>(&sbuf[cur][srow][ks * 32 + lg * 8]);
                bf16x8 a   = *reinterpret_cast<const bf16x8*>(&wbuf[cur][wrow][ks * 32 + lg * 8]);
                acc = __builtin_amdgcn_mfma_f32_16x16x32_bf16(a, bfr, acc, 0, 0, 0);
            }
            if (cc + 1 < NCH) {
                sample(cc + 1, cur ^ 1);
                stage_w(cc + 1, cur ^ 1);
            }
            __syncthreads();
        }

        // epilogue -> LDS offsets (fp32, same values as the old offb path)
        int plocal = nt * 16 + lr;
        #pragma unroll
        for (int r = 0; r < 4; r++) {
            int oc = mt * 16 + lg * 4 + r;
            if (oc < 27) {
                float v = acc[r];
                v = (oc < 18) ? (v + bp[oc]) : sigmoidf_(v + bm[oc - 18]);
                offlds[oc][plocal] = v;
            }
        }
    }
    __syncthreads();

    // ================= phase 2: bilinear meta =================
    for (int task = tid; task < 576; task += 512) {
        int p = task & 63, n = task >> 6;
        int j = j0 + p;
        float px = offlds[n][p]      + (float)(n / 3 - 1) + (float)(i + 1);
        float py = offlds[9 + n][p]  + (float)(n % 3 - 1) + (float)(j + 1);
        float mk = offlds[18 + n][p];
        float fx = floorf(px), fy = floorf(py);
        const float lim = 129.0f;            // Hp-1 = Wp-1
        int qltx = (int)fminf(fmaxf(fx, 0.f), lim);
        int qlty = (int)fminf(fmaxf(fy, 0.f), lim);
        int qrbx = (int)fminf(fmaxf(fx + 1.f, 0.f), lim);
        int qrby = (int)fminf(fmaxf(fy + 1.f, 0.f), lim);
        float pxc = fminf(fmaxf(px, 0.f), lim);
        float pyc = fminf(fmaxf(py, 0.f), lim);
        float gxl = 1.f + ((float)qltx - pxc);
        float gxr = 1.f - ((float)qrbx - pxc);
        float gyl = 1.f + ((float)qlty - pyc);
        float gyr = 1.f - ((float)qrby - pyc);
        int   xs[4] = {qltx, qrbx, qltx, qrbx};
        int   ys[4] = {qlty, qrby, qrby, qlty};
        float gs[4] = {gxl * gyl, gxr * gyr, gxl * gyr, gxr * gyl};
        u16x8 m;
        #pragma unroll
        for (int q = 0; q < 4; q++) {
            int qx = xs[q], qy = ys[q];
            bool valid = (qx >= 1 && qx <= H && qy >= 1 && qy <= W);
            m[q]     = valid ? (unsigned short)((qx - 1) * W + (qy - 1)) : (unsigned short)0;
            m[4 + q] = f2bf(valid ? gs[q] * mk : 0.f);
        }
        *reinterpret_cast<u16x8*>(&meta[n][p][0]) = m;
    }
    __syncthreads();

    // ================= phase 3: deformable conv =================
    {
        auto sample = [&](int cc, int bi) {
            int n = cc / HPC, h = cc - n * HPC;
            int p = tid >> 3, cl = tid & 7;
            u16x8 m = *reinterpret_cast<const u16x8*>(&meta[n][p][0]);
            float vac[8];
            #pragma unroll
            for (int e = 0; e < 8; e++) vac[e] = 0.f;
            #pragma unroll
            for (int q = 0; q < 4; q++) {
                const unsigned short* sp = xtb + (size_t)m[q] * CIN + h * 64 + cl * 8;
                u16x8 v = *reinterpret_cast<const u16x8*>(sp);
                float wq = bf2f(m[4 + q]);
                const unsigned* vd = reinterpret_cast<const unsigned*>(&v);
                #pragma unroll
                for (int d = 0; d < 4; d++) {
                    vac[2 * d]     = fmaf(bflo(vd[d]), wq, vac[2 * d]);
                    vac[2 * d + 1] = fmaf(bfhi(vd[d]), wq, vac[2 * d + 1]);
                }
            }
            u16x8 o;
            #pragma unroll
            for (int e = 0; e < 8; e++) o[e] = f2bf(vac[e]);
            *reinterpret_cast<u16x8*>(&sbuf[bi][p][cl * 8]) = o;
        };
        auto stage_w = [&](int cc, int bi) {
            int n = cc / HPC, h = cc - n * HPC;
            int row = tid >> 3, seg = tid & 7;
            u16x8 v = *reinterpret_cast<const u16x8*>(
                wtp + (size_t)row * (9 * CIN) + n * CIN + h * 64 + seg * 8);
            *reinterpret_cast<u16x8*>(&wbuf[bi][row][seg * 8]) = v;
        };

        sample(0, 0);
        stage_w(0, 0);
        __syncthreads();

        int ocq = wv & 1, pq = wv >> 1;
        int srow = pq * 16 + lr;
        int wrow = ocq * 32 + lr;

        f32x4 acc0 = {0.f, 0.f, 0.f, 0.f};
        f32x4 acc1 = {0.f, 0.f, 0.f, 0.f};

        for (int cc = 0; cc < NCH; cc++) {
            int cur = cc & 1;
            #pragma unroll
            for (int ks = 0; ks < 2; ks++) {
                bf16x8 bfr = *reinterpret_cast<const bf16x8*>(&sbuf[cur][srow][ks * 32 + lg * 8]);
                bf16x8 a0  = *reinterpret_cast<const bf16x8*>(&wbuf[cur][wrow][ks * 32 + lg * 8]);
                bf16x8 a1  = *reinterpret_cast<const bf16x8*>(&wbuf[cur][wrow + 16][ks * 32 + lg * 8]);
                acc0 = __builtin_amdgcn_mfma_f32_16x16x32_bf16(a0, bfr, acc0, 0, 0, 0);
                acc1 = __builtin_amdgcn_mfma_f32_16x16x32_bf16(a1, bfr, acc1, 0, 0, 0);
            }
            if (cc + 1 < NCH) {
                sample(cc + 1, cur ^ 1);
                stage_w(cc + 1, cur ^ 1);
            }
            __syncthreads();
        }

        int pixo = base + pq * 16 + lr;
        float* ob0 = out + ((size_t)b * 64 + ocq * 32 + lg * 4) * HW + pixo;
        #pragma unroll
        for (int r = 0; r < 4; r++) ob0[(size_t)r * HW] = acc0[r];
        float* ob1 = out + ((size_t)b * 64 + ocq * 32 + 16 + lg * 4) * HW + pixo;
        #pragma unroll
        for (int r = 0; r < 4; r++) ob1[(size_t)r * HW] = acc1[r];
    }
}

// ---------------------------------------------------------------------------
// Group-norm statistics. One block per (b, group).
// ---------------------------------------------------------------------------
__global__ __launch_bounds__(256) void gn_stats(
    const float* __restrict__ buf, float* __restrict__ stats)
{
    int bg = blockIdx.x;
    const float4* v = reinterpret_cast<const float4*>(buf + (size_t)bg * 4 * HW);
    float sum = 0.f, ssq = 0.f;
    for (int idx = threadIdx.x; idx < 4 * HW / 4; idx += 256) {
        float4 x = v[idx];
        sum += x.x + x.y + x.z + x.w;
        ssq += x.x * x.x + x.y * x.y + x.z * x.z + x.w * x.w;
    }
    #pragma unroll
    for (int d = 32; d > 0; d >>= 1) {
        sum += __shfl_down(sum, d);
        ssq += __shfl_down(ssq, d);
    }
    __shared__ float ws1[4], ws2[4];
    int wid = threadIdx.x >> 6;
    if ((threadIdx.x & 63) == 0) { ws1[wid] = sum; ws2[wid] = ssq; }
    __syncthreads();
    if (threadIdx.x == 0) {
        float S = ws1[0] + ws1[1] + ws1[2] + ws1[3];
        float Q = ws2[0] + ws2[1] + ws2[2] + ws2[3];
        float mean = S * (1.0f / (4.0f * HW));
        float var  = Q * (1.0f / (4.0f * HW)) - mean * mean;
        stats[bg]      = mean;
        stats[32 + bg] = rsqrtf(var + 1e-5f);
    }
}

// ---------------------------------------------------------------------------
// GN(+relu) on the fly -> channel mean & max maps only.
// ---------------------------------------------------------------------------
__global__ __launch_bounds__(256) void gn_meanmax(
    const float* __restrict__ dc, const float* __restrict__ stats,
    const float* __restrict__ gamma, const float* __restrict__ beta,
    float* __restrict__ cm, float* __restrict__ cx)
{
    int t = blockIdx.x * 256 + threadIdx.x;
    if (t >= BATCH * HW) return;
    int b = t >> 14;
    int pix = t & (HW - 1);
    float msum = 0.f, mmax = -INFINITY;
    #pragma unroll 8
    for (int c = 0; c < 64; c++) {
        int g = c >> 2;
        float mean = stats[b * 16 + g];
        float rstd = stats[32 + b * 16 + g];
        size_t idx = ((size_t)b * 64 + c) * HW + pix;
        float v = (dc[idx] - mean) * rstd * gamma[c] + beta[c];
        v = fmaxf(v, 0.f);
        msum += v;
        mmax = fmaxf(mmax, v);
    }
    cm[t] = msum * (1.0f / 64.0f);
    cx[t] = mmax;
}

// ---------------------------------------------------------------------------
// Fused: spatial-attention sigmoids (inline 1-ch 3x3 convs over cm/cx) +
// GN+relu + scale + concat + transpose -> bf16 catt [B][HW][128]
// ---------------------------------------------------------------------------
__global__ __launch_bounds__(256) void attn_cat_t(
    const float* __restrict__ dc, const float* __restrict__ stats,
    const float* __restrict__ gamma, const float* __restrict__ beta,
    const float* __restrict__ cm, const float* __restrict__ cx,
    const float* __restrict__ wa, const float* __restrict__ ba,
    const float* __restrict__ wb, const float* __restrict__ bb,
    unsigned short* __restrict__ catt)
{
    __shared__ float tile[64][65];
    __shared__ float avs[64], mvs[64];
    int blk = blockIdx.x;               // 512
    int b  = blk >> 8;
    int p0 = (blk & 255) * 64;
    int tr = threadIdx.x >> 6;
    int tc = threadIdx.x & 63;
    if (threadIdx.x < 64) {
        int pix = p0 + threadIdx.x;
        int i = pix >> 7, j = pix & (W - 1);
        float sa = ba[0], sb = bb[0];
        #pragma unroll
        for (int di = 0; di < 3; di++) {
            int ii = i + di - 1;
            if (ii < 0 || ii >= H) continue;
            #pragma unroll
            for (int dj = 0; dj < 3; dj++) {
                int jj = j + dj - 1;
                if (jj < 0 || jj >= W) continue;
                int q = (b << 14) + (ii << 7) + jj;
                sa = fmaf(cm[q], wa[di * 3 + dj], sa);
                sb = fmaf(cx[q], wb[di * 3 + dj], sb);
            }
        }
        avs[threadIdx.x] = sigmoidf_(sa);
        mvs[threadIdx.x] = sigmoidf_(sb);
    }
    #pragma unroll
    for (int r = 0; r < 16; r++) {
        int c = r * 4 + tr;
        float mean = stats[b * 16 + (c >> 2)];
        float rstd = stats[32 + b * 16 + (c >> 2)];
        float v = dc[((size_t)b * 64 + c) * HW + p0 + tc];
        tile[c][tc] = fmaxf((v - mean) * rstd * gamma[c] + beta[c], 0.f);
    }
    __syncthreads();
    #pragma unroll
    for (int r = 0; r < 16; r++) {
        int p = r * 4 + tr;
        float v = tile[tc][p];
        unsigned short* cr = catt + ((size_t)b * HW + p0 + p) * 128;
        cr[tc]      = f2bf(avs[p] * v);
        cr[64 + tc] = f2bf(mvs[p] * v);
    }
}

// ---------------------------------------------------------------------------
// Final GN + relu -> d_out
// ---------------------------------------------------------------------------
__global__ __launch_bounds__(256) void gn_final(
    const float* __restrict__ dc, const float* __restrict__ stats,
    const float* __restrict__ gamma, const float* __restrict__ beta,
    float* __restrict__ out)
{
    int t = blockIdx.x * 256 + threadIdx.x;
    if (t >= BATCH * 64 * HW) return;
    int c = (t >> 14) & 63;
    int b = t >> 20;
    int g = c >> 2;
    float mean = stats[b * 16 + g];
    float rstd = stats[32 + b * 16 + g];
    float v = (dc[t] - mean) * rstd * gamma[c] + beta[c];
    out[t] = fmaxf(v, 0.f);
}

// ---------------------------------------------------------------------------
extern "C" void kernel_launch(void* const* d_in, const int* in_sizes, int n_in,
                              void* d_out, int out_size, void* d_ws, size_t ws_size,
                              hipStream_t stream) {
    (void)in_sizes; (void)n_in; (void)out_size; (void)ws_size;
    const float* x   = (const float*)d_in[0];
    const float* wp1 = (const float*)d_in[1];
    const float* bp1 = (const float*)d_in[2];
    const float* wm1 = (const float*)d_in[3];
    const float* bm1 = (const float*)d_in[4];
    const float* wc1 = (const float*)d_in[5];
    const float* g1  = (const float*)d_in[6];
    const float* be1 = (const float*)d_in[7];
    const float* wa  = (const float*)d_in[8];
    const float* ba  = (const float*)d_in[9];
    const float* wb  = (const float*)d_in[10];
    const float* bb  = (const float*)d_in[11];
    const float* wp2 = (const float*)d_in[12];
    const float* bp2 = (const float*)d_in[13];
    const float* wm2 = (const float*)d_in[14];
    const float* bm2 = (const float*)d_in[15];
    const float* wc2 = (const float*)d_in[16];
    const float* g2  = (const float*)d_in[17];
    const float* be2 = (const float*)d_in[18];
    float* out = (float*)d_out;

    // ---- workspace layout ----
    float* ws   = (float*)d_ws;
    float* dcb  = ws;                              // 2097152 f
    float* cmb  = dcb + 2 * 64 * HW;               //   32768 f
    float* cxb  = cmb + 2 * HW;                    //   32768 f
    unsigned short* catt = (unsigned short*)(cxb + 2 * HW);  // 2*HW*128 u16
    float* stb  = (float*)(catt + (size_t)2 * 128 * HW);     //      64 f
    unsigned short* wtp1 = (unsigned short*)(stb + 64);      // 64*576
    unsigned short* wtp2 = wtp1 + 64 * 576;                  // 64*1152
    unsigned short* wop1 = wtp2 + 64 * 1152;                 // 32*576
    unsigned short* wop2 = wop1 + 32 * 576;                  // 32*1152
    // x transposed [B][HW][64] bf16 in d_out scratch (rewritten by gn_final)
    unsigned short* xt1 = (unsigned short*)out;

    const int NPIXB = (BATCH * HW + 255) / 256;      // 128
    const int NDEF  = BATCH * HW / 64;               // 512
    const int NPREP = 512 + (64 * 576 + 64 * 1152 + 32 * 576 + 32 * 1152 + 255) / 256;

    prep_all<<<NPREP, 256, 0, stream>>>(x, wc1, wc2, wp1, wm1, wp2, wm2,
                                        xt1, wtp1, wtp2, wop1, wop2);

    // ---- stage 1 ----
    dsa_fused<64><<<NDEF, 512, 0, stream>>>(xt1, wop1, wtp1, bp1, bm1, dcb);
    gn_stats<<<32, 256, 0, stream>>>(dcb, stb);
    gn_meanmax<<<NPIXB, 256, 0, stream>>>(dcb, stb, g1, be1, cmb, cxb);
    attn_cat_t<<<512, 256, 0, stream>>>(dcb, stb, g1, be1, cmb, cxb,
                                        wa, ba, wb, bb, catt);

    // ---- stage 2 ----
    dsa_fused<128><<<NDEF, 512, 0, stream>>>(catt, wop2, wtp2, bp2, bm2, dcb);
    gn_stats<<<32, 256, 0, stream>>>(dcb, stb);
    gn_final<<<(BATCH * 64 * HW + 255) / 256, 256, 0, stream>>>(dcb, stb, g2, be2, out);
}

// Round 14
// 95.246 us; speedup vs baseline: 4.5110x; 1.3064x over previous
//
#include <hip/hip_runtime.h>
#include <hip/hip_bf16.h>
#include <math.h>

#define H 128
#define W 128
#define HW (H*W)
#define BATCH 2

typedef __attribute__((ext_vector_type(8))) short          bf16x8;
typedef __attribute__((ext_vector_type(4))) float          f32x4;
typedef __attribute__((ext_vector_type(8))) unsigned short u16x8;

__device__ __forceinline__ float sigmoidf_(float x){ return 1.0f/(1.0f + expf(-x)); }

__device__ __forceinline__ unsigned short f2bf(float f) {
    __hip_bfloat16 h = __float2bfloat16(f);          // RTNE
    return __builtin_bit_cast(unsigned short, h);
}
__device__ __forceinline__ float bf2f(unsigned short b) {
    return __uint_as_float(((unsigned)b) << 16);
}
__device__ __forceinline__ float bflo(unsigned u){ return __uint_as_float(u << 16); }
__device__ __forceinline__ float bfhi(unsigned u){ return __uint_as_float(u & 0xFFFF0000u); }

// ---------------------------------------------------------------------------
// prep_all: block 0 additionally zeroes the GN-stat accumulators.
// blocks 0..511: transpose x [B][64][HW] f32 -> xt [B][HW][64] bf16;
// blocks 512+ : tap-major bf16 weight layouts.
// ---------------------------------------------------------------------------
__global__ __launch_bounds__(256) void prep_all(
    const float* __restrict__ x,
    const float* __restrict__ wc1, const float* __restrict__ wc2,
    const float* __restrict__ wp1, const float* __restrict__ wm1,
    const float* __restrict__ wp2, const float* __restrict__ wm2,
    unsigned short* __restrict__ xt,
    unsigned short* __restrict__ wtp1, unsigned short* __restrict__ wtp2,
    unsigned short* __restrict__ wop1, unsigned short* __restrict__ wop2,
    float* __restrict__ stats1, float* __restrict__ stats2)
{
    __shared__ float tile[64][65];
    if (blockIdx.x < 512) {
        if (blockIdx.x == 0 && threadIdx.x < 128) {
            if (threadIdx.x < 64) stats1[threadIdx.x] = 0.f;
            else                  stats2[threadIdx.x - 64] = 0.f;
        }
        int blk = blockIdx.x;
        int b  = blk >> 8;
        int p0 = (blk & 255) * 64;
        int tr = threadIdx.x >> 6;
        int tc = threadIdx.x & 63;
        #pragma unroll
        for (int r = 0; r < 16; r++) {
            int c = r * 4 + tr;
            tile[c][tc] = x[((size_t)b * 64 + c) * HW + p0 + tc];
        }
        __syncthreads();
        #pragma unroll
        for (int r = 0; r < 16; r++) {
            int p = r * 4 + tr;
            xt[((size_t)b * HW + p0 + p) * 64 + tc] = f2bf(tile[tc][p]);
        }
        return;
    }
    const int s1 = 64 * 9 * 64, s2 = 64 * 9 * 128;
    const int s3 = 32 * 9 * 64, s4 = 32 * 9 * 128;
    int t = (blockIdx.x - 512) * 256 + threadIdx.x;
    if (t < s1) {
        int oc = t / (9 * 64); int r = t - oc * (9 * 64);
        int n = r / 64, c = r - n * 64;
        wtp1[t] = f2bf(wc1[((size_t)oc * 64 + c) * 9 + n]);
        return;
    }
    t -= s1;
    if (t < s2) {
        int oc = t / (9 * 128); int r = t - oc * (9 * 128);
        int n = r / 128, c = r - n * 128;
        wtp2[t] = f2bf(wc2[((size_t)oc * 128 + c) * 9 + n]);
        return;
    }
    t -= s2;
    if (t < s3) {
        int oc = t / (9 * 64); int r = t - oc * (9 * 64);
        int n = r / 64, c = r - n * 64;
        float v = 0.f;
        if (oc < 18)      v = wp1[((size_t)oc * 64 + c) * 9 + n];
        else if (oc < 27) v = wm1[((size_t)(oc - 18) * 64 + c) * 9 + n];
        wop1[t] = f2bf(v);
        return;
    }
    t -= s3;
    if (t < s4) {
        int oc = t / (9 * 128); int r = t - oc * (9 * 128);
        int n = r / 128, c = r - n * 128;
        float v = 0.f;
        if (oc < 18)      v = wp2[((size_t)oc * 128 + c) * 9 + n];
        else if (oc < 27) v = wm2[((size_t)(oc - 18) * 128 + c) * 9 + n];
        wop2[t] = f2bf(v);
    }
}

// ---------------------------------------------------------------------------
// Fused DSA stage (R12 structure) + GN-stat accumulation epilogue + XCD
// swizzle. stats layout: [0..31] sum(b*16+g), [32..63] sumsq.
// ---------------------------------------------------------------------------
template<int CIN>
__global__ __launch_bounds__(512, 6) void dsa_fused(
    const unsigned short* __restrict__ xt,  // [B][HW][CIN] bf16
    const unsigned short* __restrict__ wop, // [32][9*CIN] bf16 tap-major
    const unsigned short* __restrict__ wtp, // [64][9*CIN] bf16 tap-major
    const float* __restrict__ bp,           // [18]
    const float* __restrict__ bm,           // [9]
    float* __restrict__ out,                // [B][64][HW]
    float* __restrict__ stats)              // [64] sums
{
    constexpr int HPC  = CIN / 64;
    constexpr int NCH  = 9 * HPC;
    constexpr int SROW = 68;
    __shared__ __align__(16) unsigned short sbuf[2][64][SROW];
    __shared__ __align__(16) unsigned short wbuf[2][64][SROW];
    __shared__ __align__(16) unsigned short meta[9][64][8];
    __shared__ float offlds[27][68];
    __shared__ float wsp[8][8][2];

    int tid  = threadIdx.x;
    int bid  = blockIdx.x;                  // 512 blocks, XCD-bijective swizzle
    int wgid = (bid & 7) * 64 + (bid >> 3);
    int pix0 = wgid * 64;
    int b    = pix0 >> 14;
    int base = pix0 & (HW - 1);
    int i    = base >> 7;
    int j0   = base & 127;

    const unsigned short* xtb = xt + (size_t)b * HW * CIN;
    const u16x8 zero8 = {0,0,0,0,0,0,0,0};

    int lane = tid & 63, wv = tid >> 6;
    int lr = lane & 15, lg = lane >> 4;

    // ================= phase 1: offset/mask conv =================
    {
        auto sample = [&](int cc, int bi) {
            int n = cc / HPC, h = cc - n * HPC;
            int di = n / 3 - 1, dj = n - (n / 3) * 3 - 1;
            int ii = i + di;
            bool rowok = (ii >= 0 && ii < H);
            int p = tid >> 3, cl = tid & 7;
            int jj = j0 + p + dj;
            bool v = rowok && (jj >= 0 && jj < W);
            u16x8 val = v ? *reinterpret_cast<const u16x8*>(
                                xtb + (size_t)(ii * W + jj) * CIN + h * 64 + cl * 8)
                          : zero8;
            *reinterpret_cast<u16x8*>(&sbuf[bi][p][cl * 8]) = val;
        };
        auto stage_w = [&](int cc, int bi) {
            if (tid < 256) {
                int n = cc / HPC, h = cc - n * HPC;
                int row = tid >> 3, seg = tid & 7;
                u16x8 v = *reinterpret_cast<const u16x8*>(
                    wop + (size_t)row * (9 * CIN) + n * CIN + h * 64 + seg * 8);
                *reinterpret_cast<u16x8*>(&wbuf[bi][row][seg * 8]) = v;
            }
        };

        sample(0, 0);
        stage_w(0, 0);
        __syncthreads();

        int mt = wv & 1, nt = wv >> 1;
        int srow = nt * 16 + lr;
        int wrow = mt * 16 + lr;
        f32x4 acc = {0.f, 0.f, 0.f, 0.f};

        for (int cc = 0; cc < NCH; cc++) {
            int cur = cc & 1;
            #pragma unroll
            for (int ks = 0; ks < 2; ks++) {
                bf16x8 bfr = *reinterpret_cast<const bf16x8*>(&sbuf[cur][srow][ks * 32 + lg * 8]);
                bf16x8 a   = *reinterpret_cast<const bf16x8*>(&wbuf[cur][wrow][ks * 32 + lg * 8]);
                acc = __builtin_amdgcn_mfma_f32_16x16x32_bf16(a, bfr, acc, 0, 0, 0);
            }
            if (cc + 1 < NCH) {
                sample(cc + 1, cur ^ 1);
                stage_w(cc + 1, cur ^ 1);
            }
            __syncthreads();
        }

        int plocal = nt * 16 + lr;
        #pragma unroll
        for (int r = 0; r < 4; r++) {
            int oc = mt * 16 + lg * 4 + r;
            if (oc < 27) {
                float v = acc[r];
                v = (oc < 18) ? (v + bp[oc]) : sigmoidf_(v + bm[oc - 18]);
                offlds[oc][plocal] = v;
            }
        }
    }
    __syncthreads();

    // ================= phase 2: bilinear meta =================
    for (int task = tid; task < 576; task += 512) {
        int p = task & 63, n = task >> 6;
        int j = j0 + p;
        float px = offlds[n][p]      + (float)(n / 3 - 1) + (float)(i + 1);
        float py = offlds[9 + n][p]  + (float)(n % 3 - 1) + (float)(j + 1);
        float mk = offlds[18 + n][p];
        float fx = floorf(px), fy = floorf(py);
        const float lim = 129.0f;
        int qltx = (int)fminf(fmaxf(fx, 0.f), lim);
        int qlty = (int)fminf(fmaxf(fy, 0.f), lim);
        int qrbx = (int)fminf(fmaxf(fx + 1.f, 0.f), lim);
        int qrby = (int)fminf(fmaxf(fy + 1.f, 0.f), lim);
        float pxc = fminf(fmaxf(px, 0.f), lim);
        float pyc = fminf(fmaxf(py, 0.f), lim);
        float gxl = 1.f + ((float)qltx - pxc);
        float gxr = 1.f - ((float)qrbx - pxc);
        float gyl = 1.f + ((float)qlty - pyc);
        float gyr = 1.f - ((float)qrby - pyc);
        int   xs[4] = {qltx, qrbx, qltx, qrbx};
        int   ys[4] = {qlty, qrby, qrby, qlty};
        float gs[4] = {gxl * gyl, gxr * gyr, gxl * gyr, gxr * gyl};
        u16x8 m;
        #pragma unroll
        for (int q = 0; q < 4; q++) {
            int qx = xs[q], qy = ys[q];
            bool valid = (qx >= 1 && qx <= H && qy >= 1 && qy <= W);
            m[q]     = valid ? (unsigned short)((qx - 1) * W + (qy - 1)) : (unsigned short)0;
            m[4 + q] = f2bf(valid ? gs[q] * mk : 0.f);
        }
        *reinterpret_cast<u16x8*>(&meta[n][p][0]) = m;
    }
    __syncthreads();

    // ================= phase 3: deformable conv =================
    {
        auto sample = [&](int cc, int bi) {
            int n = cc / HPC, h = cc - n * HPC;
            int p = tid >> 3, cl = tid & 7;
            u16x8 m = *reinterpret_cast<const u16x8*>(&meta[n][p][0]);
            float vac[8];
            #pragma unroll
            for (int e = 0; e < 8; e++) vac[e] = 0.f;
            #pragma unroll
            for (int q = 0; q < 4; q++) {
                const unsigned short* sp = xtb + (size_t)m[q] * CIN + h * 64 + cl * 8;
                u16x8 v = *reinterpret_cast<const u16x8*>(sp);
                float wq = bf2f(m[4 + q]);
                const unsigned* vd = reinterpret_cast<const unsigned*>(&v);
                #pragma unroll
                for (int d = 0; d < 4; d++) {
                    vac[2 * d]     = fmaf(bflo(vd[d]), wq, vac[2 * d]);
                    vac[2 * d + 1] = fmaf(bfhi(vd[d]), wq, vac[2 * d + 1]);
                }
            }
            u16x8 o;
            #pragma unroll
            for (int e = 0; e < 8; e++) o[e] = f2bf(vac[e]);
            *reinterpret_cast<u16x8*>(&sbuf[bi][p][cl * 8]) = o;
        };
        auto stage_w = [&](int cc, int bi) {
            int n = cc / HPC, h = cc - n * HPC;
            int row = tid >> 3, seg = tid & 7;
            u16x8 v = *reinterpret_cast<const u16x8*>(
                wtp + (size_t)row * (9 * CIN) + n * CIN + h * 64 + seg * 8);
            *reinterpret_cast<u16x8*>(&wbuf[bi][row][seg * 8]) = v;
        };

        sample(0, 0);
        stage_w(0, 0);
        __syncthreads();

        int ocq = wv & 1, pq = wv >> 1;
        int srow = pq * 16 + lr;
        int wrow = ocq * 32 + lr;

        f32x4 acc0 = {0.f, 0.f, 0.f, 0.f};
        f32x4 acc1 = {0.f, 0.f, 0.f, 0.f};

        for (int cc = 0; cc < NCH; cc++) {
            int cur = cc & 1;
            #pragma unroll
            for (int ks = 0; ks < 2; ks++) {
                bf16x8 bfr = *reinterpret_cast<const bf16x8*>(&sbuf[cur][srow][ks * 32 + lg * 8]);
                bf16x8 a0  = *reinterpret_cast<const bf16x8*>(&wbuf[cur][wrow][ks * 32 + lg * 8]);
                bf16x8 a1  = *reinterpret_cast<const bf16x8*>(&wbuf[cur][wrow + 16][ks * 32 + lg * 8]);
                acc0 = __builtin_amdgcn_mfma_f32_16x16x32_bf16(a0, bfr, acc0, 0, 0, 0);
                acc1 = __builtin_amdgcn_mfma_f32_16x16x32_bf16(a1, bfr, acc1, 0, 0, 0);
            }
            if (cc + 1 < NCH) {
                sample(cc + 1, cur ^ 1);
                stage_w(cc + 1, cur ^ 1);
            }
            __syncthreads();
        }

        int pixo = base + pq * 16 + lr;
        float* ob0 = out + ((size_t)b * 64 + ocq * 32 + lg * 4) * HW + pixo;
        #pragma unroll
        for (int r = 0; r < 4; r++) ob0[(size_t)r * HW] = acc0[r];
        float* ob1 = out + ((size_t)b * 64 + ocq * 32 + 16 + lg * 4) * HW + pixo;
        #pragma unroll
        for (int r = 0; r < 4; r++) ob1[(size_t)r * HW] = acc1[r];

        // ---- GN-stat accumulation: acc0 -> group ocq*8+lg, acc1 -> +4 ----
        float s0 = 0.f, q0 = 0.f, s1 = 0.f, q1 = 0.f;
        #pragma unroll
        for (int r = 0; r < 4; r++) {
            s0 += acc0[r]; q0 += acc0[r] * acc0[r];
            s1 += acc1[r]; q1 += acc1[r] * acc1[r];
        }
        #pragma unroll
        for (int d = 1; d < 16; d <<= 1) {
            s0 += __shfl_xor(s0, d); q0 += __shfl_xor(q0, d);
            s1 += __shfl_xor(s1, d); q1 += __shfl_xor(q1, d);
        }
        if (lr == 0) {
            wsp[wv][lg][0]     = s0; wsp[wv][lg][1]     = q0;
            wsp[wv][4 + lg][0] = s1; wsp[wv][4 + lg][1] = q1;
        }
        __syncthreads();
        if (tid < 16) {
            int g = tid, par = g >> 3, e = g & 7;
            float ss = 0.f, qq = 0.f;
            #pragma unroll
            for (int w = 0; w < 4; w++) {
                ss += wsp[par + 2 * w][e][0];
                qq += wsp[par + 2 * w][e][1];
            }
            atomicAdd(&stats[b * 16 + g], ss);
            atomicAdd(&stats[32 + b * 16 + g], qq);
        }
    }
}

// ---------------------------------------------------------------------------
// Fused: GN finalize (from sums) + halo channel-mean/max + 3x3 sigmoid conv
// + GN+relu + scale + concat + transpose -> bf16 catt [B][HW][128]
// ---------------------------------------------------------------------------
__global__ __launch_bounds__(256) void attn_cat_t(
    const float* __restrict__ dc, const float* __restrict__ stats,
    const float* __restrict__ gamma, const float* __restrict__ beta,
    const float* __restrict__ wa, const float* __restrict__ ba,
    const float* __restrict__ wb, const float* __restrict__ bb,
    unsigned short* __restrict__ catt)
{
    __shared__ float tile[64][65];
    __shared__ float cm_l[3][66], cx_l[3][66];
    __shared__ float avs[64], mvs[64];
    __shared__ float mg[16], rg[16], gam[64], bet[64];
    int blk = blockIdx.x;               // 512
    int b  = blk >> 8;
    int p0 = (blk & 255) * 64;
    int i  = p0 >> 7;
    int j0 = p0 & 127;
    int tx = threadIdx.x;

    if (tx < 16) {
        float s = stats[b * 16 + tx], q = stats[32 + b * 16 + tx];
        float mean = s * (1.0f / (4.0f * HW));
        float var  = q * (1.0f / (4.0f * HW)) - mean * mean;
        mg[tx] = mean; rg[tx] = rsqrtf(var + 1e-5f);
    }
    if (tx < 64) { gam[tx] = gamma[tx]; bet[tx] = beta[tx]; }
    __syncthreads();

    // halo cm/cx: rows i-1..i+1, cols j0-1..j0+64  (198 tasks)
    if (tx < 198) {
        int hr = tx / 66, hc = tx - hr * 66;
        int ii = i + hr - 1, jj = j0 + hc - 1;
        float msum = 0.f, mmax = 0.f;
        if (ii >= 0 && ii < H && jj >= 0 && jj < W) {
            int pixg = ii * W + jj;
            for (int c = 0; c < 64; c++) {
                float v = dc[((size_t)b * 64 + c) * HW + pixg];
                int g = c >> 2;
                v = fmaxf((v - mg[g]) * rg[g] * gam[c] + bet[c], 0.f);
                msum += v;
                mmax = fmaxf(mmax, v);
            }
            cm_l[hr][hc] = msum * (1.0f / 64.0f);
            cx_l[hr][hc] = mmax;
        } else {
            cm_l[hr][hc] = 0.f;          // zero-pad conv semantics
            cx_l[hr][hc] = 0.f;
        }
    }
    // main tile (all 256 threads)
    {
        int tr = tx >> 6, tc = tx & 63;
        #pragma unroll
        for (int r = 0; r < 16; r++) {
            int c = r * 4 + tr;
            float v = dc[((size_t)b * 64 + c) * HW + p0 + tc];
            tile[c][tc] = fmaxf((v - mg[c >> 2]) * rg[c >> 2] * gam[c] + bet[c], 0.f);
        }
    }
    __syncthreads();

    if (tx < 64) {
        int p = tx;
        float sa = ba[0], sb = bb[0];
        #pragma unroll
        for (int di = 0; di < 3; di++) {
            #pragma unroll
            for (int dj = 0; dj < 3; dj++) {
                sa = fmaf(cm_l[di][p + dj], wa[di * 3 + dj], sa);
                sb = fmaf(cx_l[di][p + dj], wb[di * 3 + dj], sb);
            }
        }
        avs[p] = sigmoidf_(sa);
        mvs[p] = sigmoidf_(sb);
    }
    __syncthreads();

    {
        int tr = tx >> 6, tc = tx & 63;
        #pragma unroll
        for (int r = 0; r < 16; r++) {
            int p = r * 4 + tr;
            float v = tile[tc][p];
            unsigned short* cr = catt + ((size_t)b * HW + p0 + p) * 128;
            cr[tc]      = f2bf(avs[p] * v);
            cr[64 + tc] = f2bf(mvs[p] * v);
        }
    }
}

// ---------------------------------------------------------------------------
// Final GN + relu -> d_out (finalize from sums inline)
// ---------------------------------------------------------------------------
__global__ __launch_bounds__(256) void gn_final(
    const float* __restrict__ dc, const float* __restrict__ stats,
    const float* __restrict__ gamma, const float* __restrict__ beta,
    float* __restrict__ out)
{
    int t = blockIdx.x * 256 + threadIdx.x;
    if (t >= BATCH * 64 * HW) return;
    int c = (t >> 14) & 63;
    int b = t >> 20;
    int g = c >> 2;
    float s = stats[b * 16 + g], q = stats[32 + b * 16 + g];
    float mean = s * (1.0f / (4.0f * HW));
    float var  = q * (1.0f / (4.0f * HW)) - mean * mean;
    float rstd = rsqrtf(var + 1e-5f);
    float v = (dc[t] - mean) * rstd * gamma[c] + beta[c];
    out[t] = fmaxf(v, 0.f);
}

// ---------------------------------------------------------------------------
extern "C" void kernel_launch(void* const* d_in, const int* in_sizes, int n_in,
                              void* d_out, int out_size, void* d_ws, size_t ws_size,
                              hipStream_t stream) {
    (void)in_sizes; (void)n_in; (void)out_size; (void)ws_size;
    const float* x   = (const float*)d_in[0];
    const float* wp1 = (const float*)d_in[1];
    const float* bp1 = (const float*)d_in[2];
    const float* wm1 = (const float*)d_in[3];
    const float* bm1 = (const float*)d_in[4];
    const float* wc1 = (const float*)d_in[5];
    const float* g1  = (const float*)d_in[6];
    const float* be1 = (const float*)d_in[7];
    const float* wa  = (const float*)d_in[8];
    const float* ba  = (const float*)d_in[9];
    const float* wb  = (const float*)d_in[10];
    const float* bb  = (const float*)d_in[11];
    const float* wp2 = (const float*)d_in[12];
    const float* bp2 = (const float*)d_in[13];
    const float* wm2 = (const float*)d_in[14];
    const float* bm2 = (const float*)d_in[15];
    const float* wc2 = (const float*)d_in[16];
    const float* g2  = (const float*)d_in[17];
    const float* be2 = (const float*)d_in[18];
    float* out = (float*)d_out;

    // ---- workspace layout ----
    float* ws   = (float*)d_ws;
    float* dcb  = ws;                              // 2097152 f
    unsigned short* catt = (unsigned short*)(dcb + 2 * 64 * HW); // 2*HW*128 u16
    float* st1  = (float*)(catt + (size_t)2 * 128 * HW);         // 64 f (sums)
    float* st2  = st1 + 64;                                      // 64 f (sums)
    unsigned short* wtp1 = (unsigned short*)(st2 + 64);          // 64*576
    unsigned short* wtp2 = wtp1 + 64 * 576;                      // 64*1152
    unsigned short* wop1 = wtp2 + 64 * 1152;                     // 32*576
    unsigned short* wop2 = wop1 + 32 * 576;                      // 32*1152
    // x transposed [B][HW][64] bf16 in d_out scratch (rewritten by gn_final)
    unsigned short* xt1 = (unsigned short*)out;

    const int NDEF  = BATCH * HW / 64;               // 512
    const int NPREP = 512 + (64 * 576 + 64 * 1152 + 32 * 576 + 32 * 1152 + 255) / 256;

    prep_all<<<NPREP, 256, 0, stream>>>(x, wc1, wc2, wp1, wm1, wp2, wm2,
                                        xt1, wtp1, wtp2, wop1, wop2, st1, st2);

    // ---- stage 1 ----
    dsa_fused<64><<<NDEF, 512, 0, stream>>>(xt1, wop1, wtp1, bp1, bm1, dcb, st1);
    attn_cat_t<<<512, 256, 0, stream>>>(dcb, st1, g1, be1,
                                        wa, ba, wb, bb, catt);

    // ---- stage 2 ----
    dsa_fused<128><<<NDEF, 512, 0, stream>>>(catt, wop2, wtp2, bp2, bm2, dcb, st2);
    gn_final<<<(BATCH * 64 * HW + 255) / 256, 256, 0, stream>>>(dcb, st2, g2, be2, out);
}

// Round 15
// 94.420 us; speedup vs baseline: 4.5504x; 1.0087x over previous
//
#include <hip/hip_runtime.h>
#include <hip/hip_bf16.h>
#include <math.h>

#define H 128
#define W 128
#define HW (H*W)
#define BATCH 2

typedef __attribute__((ext_vector_type(8))) short          bf16x8;
typedef __attribute__((ext_vector_type(4))) float          f32x4;
typedef __attribute__((ext_vector_type(8))) unsigned short u16x8;

__device__ __forceinline__ float sigmoidf_(float x){ return 1.0f/(1.0f + expf(-x)); }

__device__ __forceinline__ unsigned short f2bf(float f) {
    __hip_bfloat16 h = __float2bfloat16(f);          // RTNE
    return __builtin_bit_cast(unsigned short, h);
}
__device__ __forceinline__ float bf2f(unsigned short b) {
    return __uint_as_float(((unsigned)b) << 16);
}
__device__ __forceinline__ float bflo(unsigned u){ return __uint_as_float(u << 16); }
__device__ __forceinline__ float bfhi(unsigned u){ return __uint_as_float(u & 0xFFFF0000u); }

// ---------------------------------------------------------------------------
// prep_all: block 0 zeroes GN-stat accumulators; blocks 0..511 transpose
// x [B][64][HW] f32 -> xt [B][HW][64] bf16; blocks 512+ weight layouts.
// ---------------------------------------------------------------------------
__global__ __launch_bounds__(256) void prep_all(
    const float* __restrict__ x,
    const float* __restrict__ wc1, const float* __restrict__ wc2,
    const float* __restrict__ wp1, const float* __restrict__ wm1,
    const float* __restrict__ wp2, const float* __restrict__ wm2,
    unsigned short* __restrict__ xt,
    unsigned short* __restrict__ wtp1, unsigned short* __restrict__ wtp2,
    unsigned short* __restrict__ wop1, unsigned short* __restrict__ wop2,
    float* __restrict__ stats1, float* __restrict__ stats2)
{
    __shared__ float tile[64][65];
    if (blockIdx.x < 512) {
        if (blockIdx.x == 0 && threadIdx.x < 128) {
            if (threadIdx.x < 64) stats1[threadIdx.x] = 0.f;
            else                  stats2[threadIdx.x - 64] = 0.f;
        }
        int blk = blockIdx.x;
        int b  = blk >> 8;
        int p0 = (blk & 255) * 64;
        int tr = threadIdx.x >> 6;
        int tc = threadIdx.x & 63;
        #pragma unroll
        for (int r = 0; r < 16; r++) {
            int c = r * 4 + tr;
            tile[c][tc] = x[((size_t)b * 64 + c) * HW + p0 + tc];
        }
        __syncthreads();
        #pragma unroll
        for (int r = 0; r < 16; r++) {
            int p = r * 4 + tr;
            xt[((size_t)b * HW + p0 + p) * 64 + tc] = f2bf(tile[tc][p]);
        }
        return;
    }
    const int s1 = 64 * 9 * 64, s2 = 64 * 9 * 128;
    const int s3 = 32 * 9 * 64, s4 = 32 * 9 * 128;
    int t = (blockIdx.x - 512) * 256 + threadIdx.x;
    if (t < s1) {
        int oc = t / (9 * 64); int r = t - oc * (9 * 64);
        int n = r / 64, c = r - n * 64;
        wtp1[t] = f2bf(wc1[((size_t)oc * 64 + c) * 9 + n]);
        return;
    }
    t -= s1;
    if (t < s2) {
        int oc = t / (9 * 128); int r = t - oc * (9 * 128);
        int n = r / 128, c = r - n * 128;
        wtp2[t] = f2bf(wc2[((size_t)oc * 128 + c) * 9 + n]);
        return;
    }
    t -= s2;
    if (t < s3) {
        int oc = t / (9 * 64); int r = t - oc * (9 * 64);
        int n = r / 64, c = r - n * 64;
        float v = 0.f;
        if (oc < 18)      v = wp1[((size_t)oc * 64 + c) * 9 + n];
        else if (oc < 27) v = wm1[((size_t)(oc - 18) * 64 + c) * 9 + n];
        wop1[t] = f2bf(v);
        return;
    }
    t -= s3;
    if (t < s4) {
        int oc = t / (9 * 128); int r = t - oc * (9 * 128);
        int n = r / 128, c = r - n * 128;
        float v = 0.f;
        if (oc < 18)      v = wp2[((size_t)oc * 128 + c) * 9 + n];
        else if (oc < 27) v = wm2[((size_t)(oc - 18) * 128 + c) * 9 + n];
        wop2[t] = f2bf(v);
    }
}

// ---------------------------------------------------------------------------
// Fused DSA stage, 32-PIXEL TILES (256 threads, 1024 blocks -> 4 blocks/CU,
// LDS ~35 KB). Same verified phase structure as R13:
//   phase 1: offset/mask conv (MFMA) -> offlds
//   phase 2: bilinear meta
//   phase 3: deform conv (MFMA) -> out + GN-stat atomics
// ---------------------------------------------------------------------------
template<int CIN>
__global__ __launch_bounds__(256, 4) void dsa_fused(
    const unsigned short* __restrict__ xt,  // [B][HW][CIN] bf16
    const unsigned short* __restrict__ wop, // [32][9*CIN] bf16 tap-major
    const unsigned short* __restrict__ wtp, // [64][9*CIN] bf16 tap-major
    const float* __restrict__ bp,           // [18]
    const float* __restrict__ bm,           // [9]
    float* __restrict__ out,                // [B][64][HW]
    float* __restrict__ stats)              // [64] sums
{
    constexpr int HPC  = CIN / 64;
    constexpr int NCH  = 9 * HPC;
    constexpr int SROW = 68;
    __shared__ __align__(16) unsigned short sbuf[2][32][SROW];
    __shared__ __align__(16) unsigned short wbuf[2][64][SROW];
    __shared__ __align__(16) unsigned short meta[9][32][8];
    __shared__ float offlds[27][36];
    __shared__ float wsp[4][8][2];

    int tid  = threadIdx.x;
    int bid  = blockIdx.x;                  // 1024 blocks, XCD-bijective swizzle
    int wgid = (bid & 7) * 128 + (bid >> 3);
    int pix0 = wgid * 32;
    int b    = pix0 >> 14;
    int base = pix0 & (HW - 1);
    int i    = base >> 7;
    int j0   = base & 127;

    const unsigned short* xtb = xt + (size_t)b * HW * CIN;
    const u16x8 zero8 = {0,0,0,0,0,0,0,0};

    int lane = tid & 63, wv = tid >> 6;     // 4 waves
    int lr = lane & 15, lg = lane >> 4;
    int sp = tid >> 3, scl = tid & 7;       // sampling task: pixel, segment

    // ================= phase 1: offset/mask conv =================
    {
        auto sample = [&](int cc, int bi) {
            int n = cc / HPC, h = cc - n * HPC;
            int di = n / 3 - 1, dj = n - (n / 3) * 3 - 1;
            int ii = i + di;
            bool rowok = (ii >= 0 && ii < H);
            int jj = j0 + sp + dj;
            bool v = rowok && (jj >= 0 && jj < W);
            u16x8 val = v ? *reinterpret_cast<const u16x8*>(
                                xtb + (size_t)(ii * W + jj) * CIN + h * 64 + scl * 8)
                          : zero8;
            *reinterpret_cast<u16x8*>(&sbuf[bi][sp][scl * 8]) = val;
        };
        auto stage_w = [&](int cc, int bi) {     // 32 rows x 8 segs = 256
            int n = cc / HPC, h = cc - n * HPC;
            u16x8 v = *reinterpret_cast<const u16x8*>(
                wop + (size_t)sp * (9 * CIN) + n * CIN + h * 64 + scl * 8);
            *reinterpret_cast<u16x8*>(&wbuf[bi][sp][scl * 8]) = v;
        };

        sample(0, 0);
        stage_w(0, 0);
        __syncthreads();

        int mt = wv & 1, nt = wv >> 1;      // oc-half, pix-half
        int srow = nt * 16 + lr;
        int wrow = mt * 16 + lr;
        f32x4 acc = {0.f, 0.f, 0.f, 0.f};

        for (int cc = 0; cc < NCH; cc++) {
            int cur = cc & 1;
            #pragma unroll
            for (int ks = 0; ks < 2; ks++) {
                bf16x8 bfr = *reinterpret_cast<const bf16x8*>(&sbuf[cur][srow][ks * 32 + lg * 8]);
                bf16x8 a   = *reinterpret_cast<const bf16x8*>(&wbuf[cur][wrow][ks * 32 + lg * 8]);
                acc = __builtin_amdgcn_mfma_f32_16x16x32_bf16(a, bfr, acc, 0, 0, 0);
            }
            if (cc + 1 < NCH) {
                sample(cc + 1, cur ^ 1);
                stage_w(cc + 1, cur ^ 1);
            }
            __syncthreads();
        }

        int plocal = nt * 16 + lr;
        #pragma unroll
        for (int r = 0; r < 4; r++) {
            int oc = mt * 16 + lg * 4 + r;
            if (oc < 27) {
                float v = acc[r];
                v = (oc < 18) ? (v + bp[oc]) : sigmoidf_(v + bm[oc - 18]);
                offlds[oc][plocal] = v;
            }
        }
    }
    __syncthreads();

    // ================= phase 2: bilinear meta (288 tasks) =================
    for (int task = tid; task < 288; task += 256) {
        int p = task & 31, n = task >> 5;
        int j = j0 + p;
        float px = offlds[n][p]      + (float)(n / 3 - 1) + (float)(i + 1);
        float py = offlds[9 + n][p]  + (float)(n % 3 - 1) + (float)(j + 1);
        float mk = offlds[18 + n][p];
        float fx = floorf(px), fy = floorf(py);
        const float lim = 129.0f;
        int qltx = (int)fminf(fmaxf(fx, 0.f), lim);
        int qlty = (int)fminf(fmaxf(fy, 0.f), lim);
        int qrbx = (int)fminf(fmaxf(fx + 1.f, 0.f), lim);
        int qrby = (int)fminf(fmaxf(fy + 1.f, 0.f), lim);
        float pxc = fminf(fmaxf(px, 0.f), lim);
        float pyc = fminf(fmaxf(py, 0.f), lim);
        float gxl = 1.f + ((float)qltx - pxc);
        float gxr = 1.f - ((float)qrbx - pxc);
        float gyl = 1.f + ((float)qlty - pyc);
        float gyr = 1.f - ((float)qrby - pyc);
        int   xs[4] = {qltx, qrbx, qltx, qrbx};
        int   ys[4] = {qlty, qrby, qrby, qlty};
        float gs[4] = {gxl * gyl, gxr * gyr, gxl * gyr, gxr * gyl};
        u16x8 m;
        #pragma unroll
        for (int q = 0; q < 4; q++) {
            int qx = xs[q], qy = ys[q];
            bool valid = (qx >= 1 && qx <= H && qy >= 1 && qy <= W);
            m[q]     = valid ? (unsigned short)((qx - 1) * W + (qy - 1)) : (unsigned short)0;
            m[4 + q] = f2bf(valid ? gs[q] * mk : 0.f);
        }
        *reinterpret_cast<u16x8*>(&meta[n][p][0]) = m;
    }
    __syncthreads();

    // ================= phase 3: deformable conv =================
    {
        auto sample = [&](int cc, int bi) {
            int n = cc / HPC, h = cc - n * HPC;
            u16x8 m = *reinterpret_cast<const u16x8*>(&meta[n][sp][0]);
            float vac[8];
            #pragma unroll
            for (int e = 0; e < 8; e++) vac[e] = 0.f;
            #pragma unroll
            for (int q = 0; q < 4; q++) {
                const unsigned short* spp = xtb + (size_t)m[q] * CIN + h * 64 + scl * 8;
                u16x8 v = *reinterpret_cast<const u16x8*>(spp);
                float wq = bf2f(m[4 + q]);
                const unsigned* vd = reinterpret_cast<const unsigned*>(&v);
                #pragma unroll
                for (int d = 0; d < 4; d++) {
                    vac[2 * d]     = fmaf(bflo(vd[d]), wq, vac[2 * d]);
                    vac[2 * d + 1] = fmaf(bfhi(vd[d]), wq, vac[2 * d + 1]);
                }
            }
            u16x8 o;
            #pragma unroll
            for (int e = 0; e < 8; e++) o[e] = f2bf(vac[e]);
            *reinterpret_cast<u16x8*>(&sbuf[bi][sp][scl * 8]) = o;
        };
        auto stage_w = [&](int cc, int bi) {     // 64 rows x 8 segs = 512
            int n = cc / HPC, h = cc - n * HPC;
            #pragma unroll
            for (int t2 = 0; t2 < 2; t2++) {
                int idx = t2 * 256 + tid;
                int row = idx >> 3, seg = idx & 7;
                u16x8 v = *reinterpret_cast<const u16x8*>(
                    wtp + (size_t)row * (9 * CIN) + n * CIN + h * 64 + seg * 8);
                *reinterpret_cast<u16x8*>(&wbuf[bi][row][seg * 8]) = v;
            }
        };

        sample(0, 0);
        stage_w(0, 0);
        __syncthreads();

        int ocq = wv & 1, pq = wv >> 1;     // oc-half, pix-half
        int srow = pq * 16 + lr;
        int wrow = ocq * 32 + lr;

        f32x4 acc0 = {0.f, 0.f, 0.f, 0.f};
        f32x4 acc1 = {0.f, 0.f, 0.f, 0.f};

        for (int cc = 0; cc < NCH; cc++) {
            int cur = cc & 1;
            #pragma unroll
            for (int ks = 0; ks < 2; ks++) {
                bf16x8 bfr = *reinterpret_cast<const bf16x8*>(&sbuf[cur][srow][ks * 32 + lg * 8]);
                bf16x8 a0  = *reinterpret_cast<const bf16x8*>(&wbuf[cur][wrow][ks * 32 + lg * 8]);
                bf16x8 a1  = *reinterpret_cast<const bf16x8*>(&wbuf[cur][wrow + 16][ks * 32 + lg * 8]);
                acc0 = __builtin_amdgcn_mfma_f32_16x16x32_bf16(a0, bfr, acc0, 0, 0, 0);
                acc1 = __builtin_amdgcn_mfma_f32_16x16x32_bf16(a1, bfr, acc1, 0, 0, 0);
            }
            if (cc + 1 < NCH) {
                sample(cc + 1, cur ^ 1);
                stage_w(cc + 1, cur ^ 1);
            }
            __syncthreads();
        }

        int pixo = base + pq * 16 + lr;
        float* ob0 = out + ((size_t)b * 64 + ocq * 32 + lg * 4) * HW + pixo;
        #pragma unroll
        for (int r = 0; r < 4; r++) ob0[(size_t)r * HW] = acc0[r];
        float* ob1 = out + ((size_t)b * 64 + ocq * 32 + 16 + lg * 4) * HW + pixo;
        #pragma unroll
        for (int r = 0; r < 4; r++) ob1[(size_t)r * HW] = acc1[r];

        // ---- GN-stat accumulation: acc0 -> group ocq*8+lg, acc1 -> +4 ----
        float s0 = 0.f, q0 = 0.f, s1 = 0.f, q1 = 0.f;
        #pragma unroll
        for (int r = 0; r < 4; r++) {
            s0 += acc0[r]; q0 += acc0[r] * acc0[r];
            s1 += acc1[r]; q1 += acc1[r] * acc1[r];
        }
        #pragma unroll
        for (int d = 1; d < 16; d <<= 1) {
            s0 += __shfl_xor(s0, d); q0 += __shfl_xor(q0, d);
            s1 += __shfl_xor(s1, d); q1 += __shfl_xor(q1, d);
        }
        if (lr == 0) {
            wsp[wv][lg][0]     = s0; wsp[wv][lg][1]     = q0;
            wsp[wv][4 + lg][0] = s1; wsp[wv][4 + lg][1] = q1;
        }
        __syncthreads();
        if (tid < 16) {
            int g = tid, par = g >> 3, e = g & 7;
            float ss = wsp[par][e][0] + wsp[par + 2][e][0];
            float qq = wsp[par][e][1] + wsp[par + 2][e][1];
            atomicAdd(&stats[b * 16 + g], ss);
            atomicAdd(&stats[32 + b * 16 + g], qq);
        }
    }
}

// ---------------------------------------------------------------------------
// Fused: GN finalize + halo channel-mean/max + 3x3 sigmoid conv + GN+relu
// + scale + concat + transpose -> bf16 catt [B][HW][128]
// ---------------------------------------------------------------------------
__global__ __launch_bounds__(256) void attn_cat_t(
    const float* __restrict__ dc, const float* __restrict__ stats,
    const float* __restrict__ gamma, const float* __restrict__ beta,
    const float* __restrict__ wa, const float* __restrict__ ba,
    const float* __restrict__ wb, const float* __restrict__ bb,
    unsigned short* __restrict__ catt)
{
    __shared__ float tile[64][65];
    __shared__ float cm_l[3][66], cx_l[3][66];
    __shared__ float avs[64], mvs[64];
    __shared__ float mg[16], rg[16], gam[64], bet[64];
    int blk = blockIdx.x;               // 512
    int b  = blk >> 8;
    int p0 = (blk & 255) * 64;
    int i  = p0 >> 7;
    int j0 = p0 & 127;
    int tx = threadIdx.x;

    if (tx < 16) {
        float s = stats[b * 16 + tx], q = stats[32 + b * 16 + tx];
        float mean = s * (1.0f / (4.0f * HW));
        float var  = q * (1.0f / (4.0f * HW)) - mean * mean;
        mg[tx] = mean; rg[tx] = rsqrtf(var + 1e-5f);
    }
    if (tx < 64) { gam[tx] = gamma[tx]; bet[tx] = beta[tx]; }
    __syncthreads();

    if (tx < 198) {
        int hr = tx / 66, hc = tx - hr * 66;
        int ii = i + hr - 1, jj = j0 + hc - 1;
        float msum = 0.f, mmax = 0.f;
        if (ii >= 0 && ii < H && jj >= 0 && jj < W) {
            int pixg = ii * W + jj;
            for (int c = 0; c < 64; c++) {
                float v = dc[((size_t)b * 64 + c) * HW + pixg];
                int g = c >> 2;
                v = fmaxf((v - mg[g]) * rg[g] * gam[c] + bet[c], 0.f);
                msum += v;
                mmax = fmaxf(mmax, v);
            }
            cm_l[hr][hc] = msum * (1.0f / 64.0f);
            cx_l[hr][hc] = mmax;
        } else {
            cm_l[hr][hc] = 0.f;
            cx_l[hr][hc] = 0.f;
        }
    }
    {
        int tr = tx >> 6, tc = tx & 63;
        #pragma unroll
        for (int r = 0; r < 16; r++) {
            int c = r * 4 + tr;
            float v = dc[((size_t)b * 64 + c) * HW + p0 + tc];
            tile[c][tc] = fmaxf((v - mg[c >> 2]) * rg[c >> 2] * gam[c] + bet[c], 0.f);
        }
    }
    __syncthreads();

    if (tx < 64) {
        int p = tx;
        float sa = ba[0], sb = bb[0];
        #pragma unroll
        for (int di = 0; di < 3; di++) {
            #pragma unroll
            for (int dj = 0; dj < 3; dj++) {
                sa = fmaf(cm_l[di][p + dj], wa[di * 3 + dj], sa);
                sb = fmaf(cx_l[di][p + dj], wb[di * 3 + dj], sb);
            }
        }
        avs[p] = sigmoidf_(sa);
        mvs[p] = sigmoidf_(sb);
    }
    __syncthreads();

    {
        int tr = tx >> 6, tc = tx & 63;
        #pragma unroll
        for (int r = 0; r < 16; r++) {
            int p = r * 4 + tr;
            float v = tile[tc][p];
            unsigned short* cr = catt + ((size_t)b * HW + p0 + p) * 128;
            cr[tc]      = f2bf(avs[p] * v);
            cr[64 + tc] = f2bf(mvs[p] * v);
        }
    }
}

// ---------------------------------------------------------------------------
// Final GN + relu -> d_out (finalize from sums inline)
// ---------------------------------------------------------------------------
__global__ __launch_bounds__(256) void gn_final(
    const float* __restrict__ dc, const float* __restrict__ stats,
    const float* __restrict__ gamma, const float* __restrict__ beta,
    float* __restrict__ out)
{
    int t = blockIdx.x * 256 + threadIdx.x;
    if (t >= BATCH * 64 * HW) return;
    int c = (t >> 14) & 63;
    int b = t >> 20;
    int g = c >> 2;
    float s = stats[b * 16 + g], q = stats[32 + b * 16 + g];
    float mean = s * (1.0f / (4.0f * HW));
    float var  = q * (1.0f / (4.0f * HW)) - mean * mean;
    float rstd = rsqrtf(var + 1e-5f);
    float v = (dc[t] - mean) * rstd * gamma[c] + beta[c];
    out[t] = fmaxf(v, 0.f);
}

// ---------------------------------------------------------------------------
extern "C" void kernel_launch(void* const* d_in, const int* in_sizes, int n_in,
                              void* d_out, int out_size, void* d_ws, size_t ws_size,
                              hipStream_t stream) {
    (void)in_sizes; (void)n_in; (void)out_size; (void)ws_size;
    const float* x   = (const float*)d_in[0];
    const float* wp1 = (const float*)d_in[1];
    const float* bp1 = (const float*)d_in[2];
    const float* wm1 = (const float*)d_in[3];
    const float* bm1 = (const float*)d_in[4];
    const float* wc1 = (const float*)d_in[5];
    const float* g1  = (const float*)d_in[6];
    const float* be1 = (const float*)d_in[7];
    const float* wa  = (const float*)d_in[8];
    const float* ba  = (const float*)d_in[9];
    const float* wb  = (const float*)d_in[10];
    const float* bb  = (const float*)d_in[11];
    const float* wp2 = (const float*)d_in[12];
    const float* bp2 = (const float*)d_in[13];
    const float* wm2 = (const float*)d_in[14];
    const float* bm2 = (const float*)d_in[15];
    const float* wc2 = (const float*)d_in[16];
    const float* g2  = (const float*)d_in[17];
    const float* be2 = (const float*)d_in[18];
    float* out = (float*)d_out;

    // ---- workspace layout ----
    float* ws   = (float*)d_ws;
    float* dcb  = ws;                              // 2097152 f
    unsigned short* catt = (unsigned short*)(dcb + 2 * 64 * HW); // 2*HW*128 u16
    float* st1  = (float*)(catt + (size_t)2 * 128 * HW);         // 64 f (sums)
    float* st2  = st1 + 64;                                      // 64 f (sums)
    unsigned short* wtp1 = (unsigned short*)(st2 + 64);          // 64*576
    unsigned short* wtp2 = wtp1 + 64 * 576;                      // 64*1152
    unsigned short* wop1 = wtp2 + 64 * 1152;                     // 32*576
    unsigned short* wop2 = wop1 + 32 * 576;                      // 32*1152
    // x transposed [B][HW][64] bf16 in d_out scratch (rewritten by gn_final)
    unsigned short* xt1 = (unsigned short*)out;

    const int NDEF  = BATCH * HW / 32;               // 1024
    const int NPREP = 512 + (64 * 576 + 64 * 1152 + 32 * 576 + 32 * 1152 + 255) / 256;

    prep_all<<<NPREP, 256, 0, stream>>>(x, wc1, wc2, wp1, wm1, wp2, wm2,
                                        xt1, wtp1, wtp2, wop1, wop2, st1, st2);

    // ---- stage 1 ----
    dsa_fused<64><<<NDEF, 256, 0, stream>>>(xt1, wop1, wtp1, bp1, bm1, dcb, st1);
    attn_cat_t<<<512, 256, 0, stream>>>(dcb, st1, g1, be1,
                                        wa, ba, wb, bb, catt);

    // ---- stage 2 ----
    dsa_fused<128><<<NDEF, 256, 0, stream>>>(catt, wop2, wtp2, bp2, bm2, dcb, st2);
    gn_final<<<(BATCH * 64 * HW + 255) / 256, 256, 0, stream>>>(dcb, st2, g2, be2, out);
}

// Round 16
// 92.813 us; speedup vs baseline: 4.6292x; 1.0173x over previous
//
#include <hip/hip_runtime.h>
#include <hip/hip_bf16.h>
#include <math.h>

#define H 128
#define W 128
#define HW (H*W)
#define BATCH 2

typedef __attribute__((ext_vector_type(8))) short          bf16x8;
typedef __attribute__((ext_vector_type(4))) float          f32x4;
typedef __attribute__((ext_vector_type(8))) unsigned short u16x8;

__device__ __forceinline__ float sigmoidf_(float x){ return 1.0f/(1.0f + expf(-x)); }

__device__ __forceinline__ unsigned short f2bf(float f) {
    __hip_bfloat16 h = __float2bfloat16(f);          // RTNE
    return __builtin_bit_cast(unsigned short, h);
}
__device__ __forceinline__ float bf2f(unsigned short b) {
    return __uint_as_float(((unsigned)b) << 16);
}
__device__ __forceinline__ float bflo(unsigned u){ return __uint_as_float(u << 16); }
__device__ __forceinline__ float bfhi(unsigned u){ return __uint_as_float(u & 0xFFFF0000u); }

// ---------------------------------------------------------------------------
// prep_all: block 0 zeroes GN-stat accumulators; blocks 0..511 transpose
// x [B][64][HW] f32 -> xt [B][HW][64] bf16; blocks 512+ weight layouts.
// ---------------------------------------------------------------------------
__global__ __launch_bounds__(256) void prep_all(
    const float* __restrict__ x,
    const float* __restrict__ wc1, const float* __restrict__ wc2,
    const float* __restrict__ wp1, const float* __restrict__ wm1,
    const float* __restrict__ wp2, const float* __restrict__ wm2,
    unsigned short* __restrict__ xt,
    unsigned short* __restrict__ wtp1, unsigned short* __restrict__ wtp2,
    unsigned short* __restrict__ wop1, unsigned short* __restrict__ wop2,
    float* __restrict__ stats1, float* __restrict__ stats2)
{
    __shared__ float tile[64][65];
    if (blockIdx.x < 512) {
        if (blockIdx.x == 0 && threadIdx.x < 128) {
            if (threadIdx.x < 64) stats1[threadIdx.x] = 0.f;
            else                  stats2[threadIdx.x - 64] = 0.f;
        }
        int blk = blockIdx.x;
        int b  = blk >> 8;
        int p0 = (blk & 255) * 64;
        int tr = threadIdx.x >> 6;
        int tc = threadIdx.x & 63;
        #pragma unroll
        for (int r = 0; r < 16; r++) {
            int c = r * 4 + tr;
            tile[c][tc] = x[((size_t)b * 64 + c) * HW + p0 + tc];
        }
        __syncthreads();
        #pragma unroll
        for (int r = 0; r < 16; r++) {
            int p = r * 4 + tr;
            xt[((size_t)b * HW + p0 + p) * 64 + tc] = f2bf(tile[tc][p]);
        }
        return;
    }
    const int s1 = 64 * 9 * 64, s2 = 64 * 9 * 128;
    const int s3 = 32 * 9 * 64, s4 = 32 * 9 * 128;
    int t = (blockIdx.x - 512) * 256 + threadIdx.x;
    if (t < s1) {
        int oc = t / (9 * 64); int r = t - oc * (9 * 64);
        int n = r / 64, c = r - n * 64;
        wtp1[t] = f2bf(wc1[((size_t)oc * 64 + c) * 9 + n]);
        return;
    }
    t -= s1;
    if (t < s2) {
        int oc = t / (9 * 128); int r = t - oc * (9 * 128);
        int n = r / 128, c = r - n * 128;
        wtp2[t] = f2bf(wc2[((size_t)oc * 128 + c) * 9 + n]);
        return;
    }
    t -= s2;
    if (t < s3) {
        int oc = t / (9 * 64); int r = t - oc * (9 * 64);
        int n = r / 64, c = r - n * 64;
        float v = 0.f;
        if (oc < 18)      v = wp1[((size_t)oc * 64 + c) * 9 + n];
        else if (oc < 27) v = wm1[((size_t)(oc - 18) * 64 + c) * 9 + n];
        wop1[t] = f2bf(v);
        return;
    }
    t -= s3;
    if (t < s4) {
        int oc = t / (9 * 128); int r = t - oc * (9 * 128);
        int n = r / 128, c = r - n * 128;
        float v = 0.f;
        if (oc < 18)      v = wp2[((size_t)oc * 128 + c) * 9 + n];
        else if (oc < 27) v = wm2[((size_t)(oc - 18) * 128 + c) * 9 + n];
        wop2[t] = f2bf(v);
    }
}

// ---------------------------------------------------------------------------
// Fused DSA stage, 32-pixel tiles, 256 threads, 1024 blocks.
// R14 structure + T14 async-STAGE split: raw global loads for chunk k+1 are
// ISSUED before the MFMA of chunk k; FMA-combine + LDS-commit happen after.
// Held state is raw u16x8 loads only (no computed values) -> no spill at
// the 128-VGPR budget of launch_bounds(256,4).
// ---------------------------------------------------------------------------
template<int CIN>
__global__ __launch_bounds__(256, 4) void dsa_fused(
    const unsigned short* __restrict__ xt,  // [B][HW][CIN] bf16
    const unsigned short* __restrict__ wop, // [32][9*CIN] bf16 tap-major
    const unsigned short* __restrict__ wtp, // [64][9*CIN] bf16 tap-major
    const float* __restrict__ bp,           // [18]
    const float* __restrict__ bm,           // [9]
    float* __restrict__ out,                // [B][64][HW]
    float* __restrict__ stats)              // [64] sums
{
    constexpr int HPC  = CIN / 64;
    constexpr int NCH  = 9 * HPC;
    constexpr int SROW = 68;
    __shared__ __align__(16) unsigned short sbuf[2][32][SROW];
    __shared__ __align__(16) unsigned short wbuf[2][64][SROW];
    __shared__ __align__(16) unsigned short meta[9][32][8];
    __shared__ float offlds[27][36];
    __shared__ float wsp[4][8][2];

    int tid  = threadIdx.x;
    int bid  = blockIdx.x;                  // 1024 blocks, XCD-bijective swizzle
    int wgid = (bid & 7) * 128 + (bid >> 3);
    int pix0 = wgid * 32;
    int b    = pix0 >> 14;
    int base = pix0 & (HW - 1);
    int i    = base >> 7;
    int j0   = base & 127;

    const unsigned short* xtb = xt + (size_t)b * HW * CIN;
    const u16x8 zero8 = {0,0,0,0,0,0,0,0};

    int lane = tid & 63, wv = tid >> 6;     // 4 waves
    int lr = lane & 15, lg = lane >> 4;
    int sp = tid >> 3, scl = tid & 7;       // sampling task: pixel, segment

    // ================= phase 1: offset/mask conv =================
    {
        u16x8 sv, wvr;
        auto sload = [&](int cc) {
            int n = cc / HPC, h = cc - n * HPC;
            int di = n / 3 - 1, dj = n - (n / 3) * 3 - 1;
            int ii = i + di;
            int jj = j0 + sp + dj;
            bool ok = (ii >= 0 && ii < H) && (jj >= 0 && jj < W);
            sv = ok ? *reinterpret_cast<const u16x8*>(
                          xtb + (size_t)(ii * W + jj) * CIN + h * 64 + scl * 8)
                    : zero8;
        };
        auto scommit = [&](int bi) {
            *reinterpret_cast<u16x8*>(&sbuf[bi][sp][scl * 8]) = sv;
        };
        auto wload = [&](int cc) {          // 32 rows x 8 segs = 256 slots
            int n = cc / HPC, h = cc - n * HPC;
            wvr = *reinterpret_cast<const u16x8*>(
                wop + (size_t)sp * (9 * CIN) + n * CIN + h * 64 + scl * 8);
        };
        auto wcommit = [&](int bi) {
            *reinterpret_cast<u16x8*>(&wbuf[bi][sp][scl * 8]) = wvr;
        };

        sload(0); wload(0);
        scommit(0); wcommit(0);
        __syncthreads();

        int mt = wv & 1, nt = wv >> 1;      // oc-half, pix-half
        int srow = nt * 16 + lr;
        int wrow = mt * 16 + lr;
        f32x4 acc = {0.f, 0.f, 0.f, 0.f};

        for (int cc = 0; cc < NCH; cc++) {
            int cur = cc & 1;
            if (cc + 1 < NCH) { sload(cc + 1); wload(cc + 1); }  // issue early
            #pragma unroll
            for (int ks = 0; ks < 2; ks++) {
                bf16x8 bfr = *reinterpret_cast<const bf16x8*>(&sbuf[cur][srow][ks * 32 + lg * 8]);
                bf16x8 a   = *reinterpret_cast<const bf16x8*>(&wbuf[cur][wrow][ks * 32 + lg * 8]);
                acc = __builtin_amdgcn_mfma_f32_16x16x32_bf16(a, bfr, acc, 0, 0, 0);
            }
            if (cc + 1 < NCH) { scommit(cur ^ 1); wcommit(cur ^ 1); }
            __syncthreads();
        }

        int plocal = nt * 16 + lr;
        #pragma unroll
        for (int r = 0; r < 4; r++) {
            int oc = mt * 16 + lg * 4 + r;
            if (oc < 27) {
                float v = acc[r];
                v = (oc < 18) ? (v + bp[oc]) : sigmoidf_(v + bm[oc - 18]);
                offlds[oc][plocal] = v;
            }
        }
    }
    __syncthreads();

    // ================= phase 2: bilinear meta (288 tasks) =================
    for (int task = tid; task < 288; task += 256) {
        int p = task & 31, n = task >> 5;
        int j = j0 + p;
        float px = offlds[n][p]      + (float)(n / 3 - 1) + (float)(i + 1);
        float py = offlds[9 + n][p]  + (float)(n % 3 - 1) + (float)(j + 1);
        float mk = offlds[18 + n][p];
        float fx = floorf(px), fy = floorf(py);
        const float lim = 129.0f;
        int qltx = (int)fminf(fmaxf(fx, 0.f), lim);
        int qlty = (int)fminf(fmaxf(fy, 0.f), lim);
        int qrbx = (int)fminf(fmaxf(fx + 1.f, 0.f), lim);
        int qrby = (int)fminf(fmaxf(fy + 1.f, 0.f), lim);
        float pxc = fminf(fmaxf(px, 0.f), lim);
        float pyc = fminf(fmaxf(py, 0.f), lim);
        float gxl = 1.f + ((float)qltx - pxc);
        float gxr = 1.f - ((float)qrbx - pxc);
        float gyl = 1.f + ((float)qlty - pyc);
        float gyr = 1.f - ((float)qrby - pyc);
        int   xs[4] = {qltx, qrbx, qltx, qrbx};
        int   ys[4] = {qlty, qrby, qrby, qlty};
        float gs[4] = {gxl * gyl, gxr * gyr, gxl * gyr, gxr * gyl};
        u16x8 m;
        #pragma unroll
        for (int q = 0; q < 4; q++) {
            int qx = xs[q], qy = ys[q];
            bool valid = (qx >= 1 && qx <= H && qy >= 1 && qy <= W);
            m[q]     = valid ? (unsigned short)((qx - 1) * W + (qy - 1)) : (unsigned short)0;
            m[4 + q] = f2bf(valid ? gs[q] * mk : 0.f);
        }
        *reinterpret_cast<u16x8*>(&meta[n][p][0]) = m;
    }
    __syncthreads();

    // ================= phase 3: deformable conv =================
    {
        u16x8 gv0, gv1, gv2, gv3, gm;
        u16x8 pw0, pw1;
        auto gload = [&](int cc) {
            int n = cc / HPC, h = cc - n * HPC;
            gm = *reinterpret_cast<const u16x8*>(&meta[n][sp][0]);
            const unsigned short* cb = xtb + h * 64 + scl * 8;
            gv0 = *reinterpret_cast<const u16x8*>(cb + (size_t)gm[0] * CIN);
            gv1 = *reinterpret_cast<const u16x8*>(cb + (size_t)gm[1] * CIN);
            gv2 = *reinterpret_cast<const u16x8*>(cb + (size_t)gm[2] * CIN);
            gv3 = *reinterpret_cast<const u16x8*>(cb + (size_t)gm[3] * CIN);
        };
        auto gcommit = [&](int bi) {
            float vac[8];
            #pragma unroll
            for (int e = 0; e < 8; e++) vac[e] = 0.f;
            const u16x8* gvs[4] = {&gv0, &gv1, &gv2, &gv3};
            #pragma unroll
            for (int q = 0; q < 4; q++) {
                float wq = bf2f(gm[4 + q]);
                const unsigned* vd = reinterpret_cast<const unsigned*>(gvs[q]);
                #pragma unroll
                for (int d = 0; d < 4; d++) {
                    vac[2 * d]     = fmaf(bflo(vd[d]), wq, vac[2 * d]);
                    vac[2 * d + 1] = fmaf(bfhi(vd[d]), wq, vac[2 * d + 1]);
                }
            }
            u16x8 o;
            #pragma unroll
            for (int e = 0; e < 8; e++) o[e] = f2bf(vac[e]);
            *reinterpret_cast<u16x8*>(&sbuf[bi][sp][scl * 8]) = o;
        };
        auto wload = [&](int cc) {          // 64 rows x 8 segs = 512 slots
            int n = cc / HPC, h = cc - n * HPC;
            const unsigned short* wb = wtp + n * CIN + h * 64;
            pw0 = *reinterpret_cast<const u16x8*>(wb + (size_t)(tid >> 3) * (9 * CIN) + (tid & 7) * 8);
            int idx = 256 + tid;
            pw1 = *reinterpret_cast<const u16x8*>(wb + (size_t)(idx >> 3) * (9 * CIN) + (idx & 7) * 8);
        };
        auto wcommit = [&](int bi) {
            *reinterpret_cast<u16x8*>(&wbuf[bi][tid >> 3][(tid & 7) * 8]) = pw0;
            int idx = 256 + tid;
            *reinterpret_cast<u16x8*>(&wbuf[bi][idx >> 3][(idx & 7) * 8]) = pw1;
        };

        gload(0); wload(0);
        gcommit(0); wcommit(0);
        __syncthreads();

        int ocq = wv & 1, pq = wv >> 1;     // oc-half, pix-half
        int srow = pq * 16 + lr;
        int wrow = ocq * 32 + lr;

        f32x4 acc0 = {0.f, 0.f, 0.f, 0.f};
        f32x4 acc1 = {0.f, 0.f, 0.f, 0.f};

        for (int cc = 0; cc < NCH; cc++) {
            int cur = cc & 1;
            if (cc + 1 < NCH) { gload(cc + 1); wload(cc + 1); }  // issue early
            #pragma unroll
            for (int ks = 0; ks < 2; ks++) {
                bf16x8 bfr = *reinterpret_cast<const bf16x8*>(&sbuf[cur][srow][ks * 32 + lg * 8]);
                bf16x8 a0  = *reinterpret_cast<const bf16x8*>(&wbuf[cur][wrow][ks * 32 + lg * 8]);
                bf16x8 a1  = *reinterpret_cast<const bf16x8*>(&wbuf[cur][wrow + 16][ks * 32 + lg * 8]);
                acc0 = __builtin_amdgcn_mfma_f32_16x16x32_bf16(a0, bfr, acc0, 0, 0, 0);
                acc1 = __builtin_amdgcn_mfma_f32_16x16x32_bf16(a1, bfr, acc1, 0, 0, 0);
            }
            if (cc + 1 < NCH) { gcommit(cur ^ 1); wcommit(cur ^ 1); }
            __syncthreads();
        }

        int pixo = base + pq * 16 + lr;
        float* ob0 = out + ((size_t)b * 64 + ocq * 32 + lg * 4) * HW + pixo;
        #pragma unroll
        for (int r = 0; r < 4; r++) ob0[(size_t)r * HW] = acc0[r];
        float* ob1 = out + ((size_t)b * 64 + ocq * 32 + 16 + lg * 4) * HW + pixo;
        #pragma unroll
        for (int r = 0; r < 4; r++) ob1[(size_t)r * HW] = acc1[r];

        // ---- GN-stat accumulation: acc0 -> group ocq*8+lg, acc1 -> +4 ----
        float s0 = 0.f, q0 = 0.f, s1 = 0.f, q1 = 0.f;
        #pragma unroll
        for (int r = 0; r < 4; r++) {
            s0 += acc0[r]; q0 += acc0[r] * acc0[r];
            s1 += acc1[r]; q1 += acc1[r] * acc1[r];
        }
        #pragma unroll
        for (int d = 1; d < 16; d <<= 1) {
            s0 += __shfl_xor(s0, d); q0 += __shfl_xor(q0, d);
            s1 += __shfl_xor(s1, d); q1 += __shfl_xor(q1, d);
        }
        if (lr == 0) {
            wsp[wv][lg][0]     = s0; wsp[wv][lg][1]     = q0;
            wsp[wv][4 + lg][0] = s1; wsp[wv][4 + lg][1] = q1;
        }
        __syncthreads();
        if (tid < 16) {
            int g = tid, par = g >> 3, e = g & 7;
            float ss = wsp[par][e][0] + wsp[par + 2][e][0];
            float qq = wsp[par][e][1] + wsp[par + 2][e][1];
            atomicAdd(&stats[b * 16 + g], ss);
            atomicAdd(&stats[32 + b * 16 + g], qq);
        }
    }
}

// ---------------------------------------------------------------------------
// Fused: GN finalize + halo channel-mean/max + 3x3 sigmoid conv + GN+relu
// + scale + concat + transpose -> bf16 catt [B][HW][128]
// ---------------------------------------------------------------------------
__global__ __launch_bounds__(256) void attn_cat_t(
    const float* __restrict__ dc, const float* __restrict__ stats,
    const float* __restrict__ gamma, const float* __restrict__ beta,
    const float* __restrict__ wa, const float* __restrict__ ba,
    const float* __restrict__ wb, const float* __restrict__ bb,
    unsigned short* __restrict__ catt)
{
    __shared__ float tile[64][65];
    __shared__ float cm_l[3][66], cx_l[3][66];
    __shared__ float avs[64], mvs[64];
    __shared__ float mg[16], rg[16], gam[64], bet[64];
    int blk = blockIdx.x;               // 512
    int b  = blk >> 8;
    int p0 = (blk & 255) * 64;
    int i  = p0 >> 7;
    int j0 = p0 & 127;
    int tx = threadIdx.x;

    if (tx < 16) {
        float s = stats[b * 16 + tx], q = stats[32 + b * 16 + tx];
        float mean = s * (1.0f / (4.0f * HW));
        float var  = q * (1.0f / (4.0f * HW)) - mean * mean;
        mg[tx] = mean; rg[tx] = rsqrtf(var + 1e-5f);
    }
    if (tx < 64) { gam[tx] = gamma[tx]; bet[tx] = beta[tx]; }
    __syncthreads();

    if (tx < 198) {
        int hr = tx / 66, hc = tx - hr * 66;
        int ii = i + hr - 1, jj = j0 + hc - 1;
        float msum = 0.f, mmax = 0.f;
        if (ii >= 0 && ii < H && jj >= 0 && jj < W) {
            int pixg = ii * W + jj;
            for (int c = 0; c < 64; c++) {
                float v = dc[((size_t)b * 64 + c) * HW + pixg];
                int g = c >> 2;
                v = fmaxf((v - mg[g]) * rg[g] * gam[c] + bet[c], 0.f);
                msum += v;
                mmax = fmaxf(mmax, v);
            }
            cm_l[hr][hc] = msum * (1.0f / 64.0f);
            cx_l[hr][hc] = mmax;
        } else {
            cm_l[hr][hc] = 0.f;
            cx_l[hr][hc] = 0.f;
        }
    }
    {
        int tr = tx >> 6, tc = tx & 63;
        #pragma unroll
        for (int r = 0; r < 16; r++) {
            int c = r * 4 + tr;
            float v = dc[((size_t)b * 64 + c) * HW + p0 + tc];
            tile[c][tc] = fmaxf((v - mg[c >> 2]) * rg[c >> 2] * gam[c] + bet[c], 0.f);
        }
    }
    __syncthreads();

    if (tx < 64) {
        int p = tx;
        float sa = ba[0], sb = bb[0];
        #pragma unroll
        for (int di = 0; di < 3; di++) {
            #pragma unroll
            for (int dj = 0; dj < 3; dj++) {
                sa = fmaf(cm_l[di][p + dj], wa[di * 3 + dj], sa);
                sb = fmaf(cx_l[di][p + dj], wb[di * 3 + dj], sb);
            }
        }
        avs[p] = sigmoidf_(sa);
        mvs[p] = sigmoidf_(sb);
    }
    __syncthreads();

    {
        int tr = tx >> 6, tc = tx & 63;
        #pragma unroll
        for (int r = 0; r < 16; r++) {
            int p = r * 4 + tr;
            float v = tile[tc][p];
            unsigned short* cr = catt + ((size_t)b * HW + p0 + p) * 128;
            cr[tc]      = f2bf(avs[p] * v);
            cr[64 + tc] = f2bf(mvs[p] * v);
        }
    }
}

// ---------------------------------------------------------------------------
// Final GN + relu -> d_out (finalize from sums inline)
// ---------------------------------------------------------------------------
__global__ __launch_bounds__(256) void gn_final(
    const float* __restrict__ dc, const float* __restrict__ stats,
    const float* __restrict__ gamma, const float* __restrict__ beta,
    float* __restrict__ out)
{
    int t = blockIdx.x * 256 + threadIdx.x;
    if (t >= BATCH * 64 * HW) return;
    int c = (t >> 14) & 63;
    int b = t >> 20;
    int g = c >> 2;
    float s = stats[b * 16 + g], q = stats[32 + b * 16 + g];
    float mean = s * (1.0f / (4.0f * HW));
    float var  = q * (1.0f / (4.0f * HW)) - mean * mean;
    float rstd = rsqrtf(var + 1e-5f);
    float v = (dc[t] - mean) * rstd * gamma[c] + beta[c];
    out[t] = fmaxf(v, 0.f);
}

// ---------------------------------------------------------------------------
extern "C" void kernel_launch(void* const* d_in, const int* in_sizes, int n_in,
                              void* d_out, int out_size, void* d_ws, size_t ws_size,
                              hipStream_t stream) {
    (void)in_sizes; (void)n_in; (void)out_size; (void)ws_size;
    const float* x   = (const float*)d_in[0];
    const float* wp1 = (const float*)d_in[1];
    const float* bp1 = (const float*)d_in[2];
    const float* wm1 = (const float*)d_in[3];
    const float* bm1 = (const float*)d_in[4];
    const float* wc1 = (const float*)d_in[5];
    const float* g1  = (const float*)d_in[6];
    const float* be1 = (const float*)d_in[7];
    const float* wa  = (const float*)d_in[8];
    const float* ba  = (const float*)d_in[9];
    const float* wb  = (const float*)d_in[10];
    const float* bb  = (const float*)d_in[11];
    const float* wp2 = (const float*)d_in[12];
    const float* bp2 = (const float*)d_in[13];
    const float* wm2 = (const float*)d_in[14];
    const float* bm2 = (const float*)d_in[15];
    const float* wc2 = (const float*)d_in[16];
    const float* g2  = (const float*)d_in[17];
    const float* be2 = (const float*)d_in[18];
    float* out = (float*)d_out;

    // ---- workspace layout ----
    float* ws   = (float*)d_ws;
    float* dcb  = ws;                              // 2097152 f
    unsigned short* catt = (unsigned short*)(dcb + 2 * 64 * HW); // 2*HW*128 u16
    float* st1  = (float*)(catt + (size_t)2 * 128 * HW);         // 64 f (sums)
    float* st2  = st1 + 64;                                      // 64 f (sums)
    unsigned short* wtp1 = (unsigned short*)(st2 + 64);          // 64*576
    unsigned short* wtp2 = wtp1 + 64 * 576;                      // 64*1152
    unsigned short* wop1 = wtp2 + 64 * 1152;                     // 32*576
    unsigned short* wop2 = wop1 + 32 * 576;                      // 32*1152
    // x transposed [B][HW][64] bf16 in d_out scratch (rewritten by gn_final)
    unsigned short* xt1 = (unsigned short*)out;

    const int NDEF  = BATCH * HW / 32;               // 1024
    const int NPREP = 512 + (64 * 576 + 64 * 1152 + 32 * 576 + 32 * 1152 + 255) / 256;

    prep_all<<<NPREP, 256, 0, stream>>>(x, wc1, wc2, wp1, wm1, wp2, wm2,
                                        xt1, wtp1, wtp2, wop1, wop2, st1, st2);

    // ---- stage 1 ----
    dsa_fused<64><<<NDEF, 256, 0, stream>>>(xt1, wop1, wtp1, bp1, bm1, dcb, st1);
    attn_cat_t<<<512, 256, 0, stream>>>(dcb, st1, g1, be1,
                                        wa, ba, wb, bb, catt);

    // ---- stage 2 ----
    dsa_fused<128><<<NDEF, 256, 0, stream>>>(catt, wop2, wtp2, bp2, bm2, dcb, st2);
    gn_final<<<(BATCH * 64 * HW + 255) / 256, 256, 0, stream>>>(dcb, st2, g2, be2, out);
}